// Round 7
// baseline (691.348 us; speedup 1.0000x reference)
//
#include <hip/hip_runtime.h>
#include <hip/hip_cooperative_groups.h>
#include <math.h>

namespace cg = cooperative_groups;

#define NB    64
#define NPG   2048      // nodes per graph
#define EPG   16384     // edges per graph
#define HID   128
#define K1V   512
#define K2V   128
#define N1    32768     // NB*K1V
#define SCAP  2048      // per-graph surviving-edge capacity
#define MSK   (NPG - 1)
#define NQ    8         // edge segments per graph
#define ESEG  (EPG / NQ)   // 2048
#define QCAP  256       // per-segment survivor capacity (E~128)
#define GRID  512
#define TPB   256

typedef unsigned int u32;

static __device__ __forceinline__ float frelu(float v) { return v > 0.f ? v : 0.f; }

static __device__ __forceinline__ u32 f2key(float f) {
    u32 u = __float_as_uint(f);
    return u ^ ((u >> 31) ? 0xFFFFFFFFu : 0x80000000u);
}

static __device__ __forceinline__ u32 wave_iscan(u32 v, int lane) {
    #pragma unroll
    for (int off = 1; off < 64; off <<= 1) {
        u32 t = __shfl_up(v, off);
        if (lane >= off) v += t;
    }
    return v;
}

// Radix-select the K-th largest key among N LDS keys (T threads).
template <int N, int T>
static __device__ __forceinline__ void radix_top(const u32* __restrict__ key, int K,
                                                 u32* hist, u32* misc,
                                                 u32& tau, int& R) {
    const int tid = threadIdx.x;
    if (tid == 0) { misc[0] = 0u; misc[1] = (u32)K; }
    __syncthreads();
    #pragma unroll
    for (int p = 0; p < 4; p++) {
        const int shift = 24 - 8 * p;
        for (int i = tid; i < 256; i += T) hist[i] = 0u;
        __syncthreads();
        const u32 prefix = misc[0];
        const u32 need   = misc[1];
        for (int i = tid; i < N; i += T) {
            u32 k = key[i];
            bool ok = (p == 0) || ((k >> (shift + 8)) == prefix);
            if (ok) atomicAdd(&hist[(k >> shift) & 255u], 1u);
        }
        __syncthreads();
        if (tid < 64) {
            const int lane = tid;
            u32 c0 = hist[4 * lane + 0], c1 = hist[4 * lane + 1];
            u32 c2 = hist[4 * lane + 2], c3 = hist[4 * lane + 3];
            u32 local = c0 + c1 + c2 + c3;
            u32 inc = local;
            #pragma unroll
            for (int off = 1; off < 64; off <<= 1) {
                u32 v = __shfl_down(inc, off);
                if (lane + off < 64) inc += v;
            }
            u32 excl = inc - local;
            u32 ge3 = excl + c3, ge2 = ge3 + c2, ge1 = ge2 + c1, ge0 = ge1 + c0;
            int selb = -1; u32 gt = 0;
            if      (ge3 >= need && excl < need) { selb = 4 * lane + 3; gt = excl; }
            else if (ge2 >= need && ge3  < need) { selb = 4 * lane + 2; gt = ge3; }
            else if (ge1 >= need && ge2  < need) { selb = 4 * lane + 1; gt = ge2; }
            else if (ge0 >= need && ge1  < need) { selb = 4 * lane + 0; gt = ge1; }
            if (selb >= 0) { misc[0] = (prefix << 8) | (u32)selb; misc[1] = need - gt; }
        }
        __syncthreads();
    }
    tau = misc[0];
    R = (int)misc[1];
}

union SMem {
    struct { int cnt[NPG]; } deg;                                   // 8KB
    struct { float lv[NPG]; float acc[NPG]; } fs;                   // 16KB
    struct { float lw[HID], lbb[HID], lsw[HID]; } nb;               // 1.5KB
    struct {
        float lsc[NPG]; u32 lkey[NPG]; int ln[NPG];
        float ul[K1V], tgl[K1V]; int sellist[K1V];
        u32 hist[256], misc[2], wsum[4]; int scnt;
        float rp[256], rp2[256];
    } sel;                                                          // ~34.3KB
    struct { int lnm[NPG]; int pbuf[QCAP]; int lda[K1V]; int lcnt; } cp; // ~11KB
    struct { int cur[K1V]; u32 wsum[4]; } csr;                      // ~2KB
    struct { float lhT[HID * 64]; float lu[64], lg[64]; } mm;       // ~32.8KB
    struct {
        float sv[K1V]; u32 skey[K1V];
        u32 hist[256], misc[2], wsum[4]; int scnt;
        int plist[K2V]; float tl[K2V];
        float rmx[HID], rsm[HID];
        float z[266], z1[HID], z2[64], z3[32], red[2];
    } tk;                                                           // ~13KB
};

struct KArgs {
    const float* x; const int* esrc; const int* edst;
    const float* gi;
    const float* W1;  const float* b1;  const float* sW1; const float* sb1;
    const float* W2;  const float* b2;  const float* sW2; const float* sb2;
    const float* l1W; const float* l1b; const float* l2W; const float* l2b;
    const float* l3W; const float* l3b;
    float* out;
    int* degp; float* df_g; float* di_g; float* dx_g; float* tp;
    float* u_g; float* ds01_g; float* sci_g; float* scp; int* nmap_g;
    float* ulist; float* tg1; float* x1b;
    int* epair; int* eqcnt; int* ldegp;
    int* srcs2; int* rs2; int* ic2; float* dfull2; float* dinv2;
    float* hw; float* h2; float* ds02; float* sc2i;
};

__global__ __launch_bounds__(TPB, 2) void k_mega(KArgs a) {
    cg::grid_group grid = cg::this_grid();
    __shared__ SMem sm;
    const int bid = blockIdx.x, tid = threadIdx.x;
    const int lane = tid & 63, wv = tid >> 6;

    // ================= P1: per-segment degree histogram =================
    {
        const int g = bid >> 3, q = bid & 7;
        for (int i = tid; i < NPG; i += TPB) sm.deg.cnt[i] = 0;
        __syncthreads();
        const int4* d4 = (const int4*)(a.edst + g * EPG + q * ESEG);
        for (int i = tid; i < ESEG / 4; i += TPB) {
            int4 dd = d4[i];
            atomicAdd(&sm.deg.cnt[dd.x & MSK], 1); atomicAdd(&sm.deg.cnt[dd.y & MSK], 1);
            atomicAdd(&sm.deg.cnt[dd.z & MSK], 1); atomicAdd(&sm.deg.cnt[dd.w & MSK], 1);
        }
        __syncthreads();
        int4* op = (int4*)(a.degp + (size_t)bid * NPG);
        const int4* cp4 = (const int4*)sm.deg.cnt;
        for (int i = tid; i < NPG / 4; i += TPB) op[i] = cp4[i];
    }
    grid.sync();

    // ================= P2: nodeA (deg reduce -> df, di, dx) =================
    {
        int i = bid * TPB + tid;
        int g = i >> 11, loc = i & MSK;
        int dg = 0;
        #pragma unroll
        for (int q = 0; q < NQ; q++) dg += a.degp[(size_t)(g * NQ + q) * NPG + loc];
        float df = (float)dg + 1.0f;
        float di = rsqrtf(df);
        a.df_g[i] = df; a.di_g[i] = di; a.dx_g[i] = di * a.x[i];
    }
    grid.sync();

    // ================= P3: fsweep dx -> tp =================
    {
        const int g = bid >> 3, q = bid & 7;
        for (int i = tid; i < NPG; i += TPB) { sm.fs.lv[i] = a.dx_g[(size_t)g * NPG + i]; sm.fs.acc[i] = 0.f; }
        __syncthreads();
        const int4* s4 = (const int4*)(a.esrc + g * EPG + q * ESEG);
        const int4* d4 = (const int4*)(a.edst + g * EPG + q * ESEG);
        for (int i = tid; i < ESEG / 4; i += TPB) {
            int4 ss = s4[i]; int4 dd = d4[i];
            atomicAdd(&sm.fs.acc[dd.x & MSK], sm.fs.lv[ss.x & MSK]);
            atomicAdd(&sm.fs.acc[dd.y & MSK], sm.fs.lv[ss.y & MSK]);
            atomicAdd(&sm.fs.acc[dd.z & MSK], sm.fs.lv[ss.z & MSK]);
            atomicAdd(&sm.fs.acc[dd.w & MSK], sm.fs.lv[ss.w & MSK]);
        }
        __syncthreads();
        float4* op = (float4*)(a.tp + (size_t)bid * NPG);
        const float4* ap = (const float4*)sm.fs.acc;
        for (int i = tid; i < NPG / 4; i += TPB) op[i] = ap[i];
    }
    grid.sync();

    // ================= P4: nodeB (u, MLP, ds01, sc_init) =================
    {
        if (tid < HID) { sm.nb.lw[tid] = a.W1[tid]; sm.nb.lbb[tid] = a.b1[tid]; sm.nb.lsw[tid] = a.sW1[tid]; }
        __syncthreads();
        int i = bid * TPB + tid;
        int g = i >> 11, loc = i & MSK;
        float t = 0.f;
        #pragma unroll
        for (int q = 0; q < NQ; q++) t += a.tp[(size_t)(g * NQ + q) * NPG + loc];
        float df = a.df_g[i], di = a.di_g[i];
        float u = t * di + a.x[i] / df;
        float s = 0.f;
        #pragma unroll 8
        for (int c = 0; c < HID; c++) s += frelu(fmaf(sm.nb.lw[c], u, sm.nb.lbb[c])) * sm.nb.lsw[c];
        a.u_g[i] = u;
        a.ds01_g[i] = di * s;
        a.sci_g[i] = s / df + a.sb1[0];
    }
    grid.sync();

    // ================= P5: fsweep ds01 -> scp =================
    {
        const int g = bid >> 3, q = bid & 7;
        for (int i = tid; i < NPG; i += TPB) { sm.fs.lv[i] = a.ds01_g[(size_t)g * NPG + i]; sm.fs.acc[i] = 0.f; }
        __syncthreads();
        const int4* s4 = (const int4*)(a.esrc + g * EPG + q * ESEG);
        const int4* d4 = (const int4*)(a.edst + g * EPG + q * ESEG);
        for (int i = tid; i < ESEG / 4; i += TPB) {
            int4 ss = s4[i]; int4 dd = d4[i];
            atomicAdd(&sm.fs.acc[dd.x & MSK], sm.fs.lv[ss.x & MSK]);
            atomicAdd(&sm.fs.acc[dd.y & MSK], sm.fs.lv[ss.y & MSK]);
            atomicAdd(&sm.fs.acc[dd.z & MSK], sm.fs.lv[ss.z & MSK]);
            atomicAdd(&sm.fs.acc[dd.w & MSK], sm.fs.lv[ss.w & MSK]);
        }
        __syncthreads();
        float4* op = (float4*)(a.scp + (size_t)bid * NPG);
        const float4* ap = (const float4*)sm.fs.acc;
        for (int i = tid; i < NPG / 4; i += TPB) op[i] = ap[i];
    }
    grid.sync();

    // ================= P6: select (64 blocks) =================
    if (bid < NB) {
        const int b = bid;
        for (int i = tid; i < NPG; i += TPB) {
            float acc2 = 0.f;
            #pragma unroll
            for (int q = 0; q < NQ; q++) acc2 += a.scp[(size_t)(b * NQ + q) * NPG + i];
            float sc = a.sci_g[(size_t)b * NPG + i] + a.di_g[(size_t)b * NPG + i] * acc2;
            sm.sel.lsc[i] = sc;
            sm.sel.lkey[i] = f2key(sc);
            sm.sel.ln[i] = -1;
        }
        if (tid == 0) sm.sel.scnt = 0;
        __syncthreads();

        u32 tau; int R;
        radix_top<NPG, TPB>(sm.sel.lkey, K1V, sm.sel.hist, sm.sel.misc, tau, R);

        // stable tie rank, 8 elems per thread
        {
            int base_e = tid * 8;
            u32 kk[8]; int qf[8]; int csum = 0;
            #pragma unroll
            for (int r = 0; r < 8; r++) {
                kk[r] = sm.sel.lkey[base_e + r];
                qf[r] = (kk[r] == tau) ? 1 : 0;
                csum += qf[r];
            }
            u32 inc = wave_iscan((u32)csum, lane);
            if (lane == 63) sm.sel.wsum[wv] = inc;
            __syncthreads();
            if (tid == 0) { u32 run = 0; for (int w2 = 0; w2 < 4; w2++) { u32 v = sm.sel.wsum[w2]; sm.sel.wsum[w2] = run; run += v; } }
            __syncthreads();
            u32 base = sm.sel.wsum[wv] + inc - (u32)csum;
            int run2 = 0;
            #pragma unroll
            for (int r = 0; r < 8; r++) {
                bool s = (kk[r] > tau) || (qf[r] && (base + (u32)run2) < (u32)R);
                run2 += qf[r];
                if (s) { int pos = atomicAdd(&sm.sel.scnt, 1); sm.sel.sellist[pos] = base_e + r; }
            }
            __syncthreads();
        }

        for (int t2 = tid; t2 < K1V; t2 += TPB) {
            int node = sm.sel.sellist[t2];
            float uu = a.u_g[(size_t)b * NPG + node];
            float g = tanhf(sm.sel.lsc[node]);
            sm.sel.ul[t2] = uu; sm.sel.tgl[t2] = g;
            a.ulist[b * K1V + t2] = uu;
            a.tg1[b * K1V + t2] = g;
            sm.sel.ln[node] = t2;
        }
        __syncthreads();
        for (int i = tid; i < NPG; i += TPB) a.nmap_g[(size_t)b * NPG + i] = sm.sel.ln[i];

        // readout1
        {
            int grp = tid >> 7, c = tid & 127;
            float w = a.W1[c], bb = a.b1[c];
            float mx = -INFINITY, smv = 0.f;
            for (int j = grp; j < K1V; j += 2) {
                float v = frelu(fmaf(w, sm.sel.ul[j], bb)) * sm.sel.tgl[j];
                mx = fmaxf(mx, v); smv += v;
            }
            sm.sel.rp[tid] = mx; sm.sel.rp2[tid] = smv;
            __syncthreads();
            if (tid < HID) {
                float m2 = fmaxf(sm.sel.rp[tid], sm.sel.rp[128 + tid]);
                float s2 = sm.sel.rp2[tid] + sm.sel.rp2[128 + tid];
                a.x1b[b * 256 + tid] = m2;
                a.x1b[b * 256 + HID + tid] = s2 / (float)K1V;
            }
        }
    }
    grid.sync();

    // ================= P7: per-segment edge compaction =================
    {
        const int g = bid >> 3, q = bid & 7;
        for (int i = tid; i < NPG; i += TPB) sm.cp.lnm[i] = a.nmap_g[(size_t)g * NPG + i];
        for (int i = tid; i < K1V; i += TPB) sm.cp.lda[i] = 0;
        if (tid == 0) sm.cp.lcnt = 0;
        __syncthreads();
        const int4* s4 = (const int4*)(a.esrc + g * EPG + q * ESEG);
        const int4* d4 = (const int4*)(a.edst + g * EPG + q * ESEG);
        for (int i = tid; i < ESEG / 4; i += TPB) {
            int4 ss = s4[i]; int4 dd = d4[i];
            int sa[4] = { ss.x & MSK, ss.y & MSK, ss.z & MSK, ss.w & MSK };
            int da[4] = { dd.x & MSK, dd.y & MSK, dd.z & MSK, dd.w & MSK };
            #pragma unroll
            for (int r = 0; r < 4; r++) {
                int s2 = sm.cp.lnm[sa[r]], d2 = sm.cp.lnm[da[r]];
                if (s2 >= 0 && d2 >= 0) {
                    int p = atomicAdd(&sm.cp.lcnt, 1);
                    if (p < QCAP) { sm.cp.pbuf[p] = s2 | (d2 << 16); atomicAdd(&sm.cp.lda[d2], 1); }
                }
            }
        }
        __syncthreads();
        int cnt = sm.cp.lcnt < QCAP ? sm.cp.lcnt : QCAP;
        if (tid == 0) a.eqcnt[bid] = cnt;
        for (int i = tid; i < cnt; i += TPB) a.epair[(size_t)bid * QCAP + i] = sm.cp.pbuf[i];
        for (int i = tid; i < K1V; i += TPB) a.ldegp[(size_t)bid * K1V + i] = sm.cp.lda[i];
    }
    grid.sync();

    // ================= P8: csr (64 blocks) then matmul (all blocks) =================
    if (bid < NB) {
        const int b = bid;
        int e0 = tid * 2, e1 = e0 + 1;
        int dv0 = 0, dv1 = 0;
        #pragma unroll
        for (int q = 0; q < NQ; q++) {
            dv0 += a.ldegp[(size_t)(b * NQ + q) * K1V + e0];
            dv1 += a.ldegp[(size_t)(b * NQ + q) * K1V + e1];
        }
        int pr = dv0 + dv1;
        u32 inc = wave_iscan((u32)pr, lane);
        if (lane == 63) sm.csr.wsum[wv] = inc;
        __syncthreads();
        if (tid == 0) { u32 run = 0; for (int w2 = 0; w2 < 4; w2++) { u32 v = sm.csr.wsum[w2]; sm.csr.wsum[w2] = run; run += v; } }
        __syncthreads();
        int exclp = (int)(sm.csr.wsum[wv] + inc - (u32)pr);
        {
            int n0 = b * K1V + e0;
            a.rs2[n0] = b * SCAP + exclp; a.ic2[n0] = dv0;
            float df0 = (float)dv0 + 1.0f;
            a.dfull2[n0] = df0; a.dinv2[n0] = rsqrtf(df0);
            sm.csr.cur[e0] = exclp;
            int excl1 = exclp + dv0;
            int n1 = b * K1V + e1;
            a.rs2[n1] = b * SCAP + excl1; a.ic2[n1] = dv1;
            float df1 = (float)dv1 + 1.0f;
            a.dfull2[n1] = df1; a.dinv2[n1] = rsqrtf(df1);
            sm.csr.cur[e1] = excl1;
        }
        __syncthreads();
        for (int q = 0; q < NQ; q++) {
            int cnt = a.eqcnt[b * NQ + q];
            for (int i = tid; i < cnt; i += TPB) {
                int pk = a.epair[(size_t)(b * NQ + q) * QCAP + i];
                int s2 = pk & 0xffff, d2 = pk >> 16;
                int pos = atomicAdd(&sm.csr.cur[d2], 1);
                a.srcs2[(size_t)b * SCAP + pos] = b * K1V + s2;
            }
        }
    }
    __syncthreads();
    // matmul: hw = hp @ W2 (64 rows per block; W2 streamed from cache)
    {
        const int row0 = bid * 64;
        if (tid < 64) { sm.mm.lu[tid] = a.ulist[row0 + tid]; sm.mm.lg[tid] = a.tg1[row0 + tid]; }
        __syncthreads();
        for (int idx = tid; idx < HID * 64; idx += TPB) {
            int k = idx >> 6, j = idx & 63;
            sm.mm.lhT[idx] = frelu(fmaf(a.W1[k], sm.mm.lu[j], a.b1[k])) * sm.mm.lg[j];
        }
        __syncthreads();
        const int cg2 = tid & 31, rg2 = tid >> 5;
        float acc[8][4];
        #pragma unroll
        for (int r = 0; r < 8; r++)
            #pragma unroll
            for (int c = 0; c < 4; c++) acc[r][c] = 0.f;
        const float4* lhT4 = (const float4*)sm.mm.lhT;
        #pragma unroll 4
        for (int k = 0; k < HID; k++) {
            float4 h0 = lhT4[k * 16 + rg2 * 2];
            float4 h1 = lhT4[k * 16 + rg2 * 2 + 1];
            float4 ww = *(const float4*)&a.W2[(size_t)k * HID + cg2 * 4];
            float hr[8] = { h0.x, h0.y, h0.z, h0.w, h1.x, h1.y, h1.z, h1.w };
            float wc[4] = { ww.x, ww.y, ww.z, ww.w };
            #pragma unroll
            for (int r = 0; r < 8; r++)
                #pragma unroll
                for (int c = 0; c < 4; c++)
                    acc[r][c] = fmaf(hr[r], wc[c], acc[r][c]);
        }
        #pragma unroll
        for (int r = 0; r < 8; r++) {
            float4 o; o.x = acc[r][0]; o.y = acc[r][1]; o.z = acc[r][2]; o.w = acc[r][3];
            *(float4*)&a.hw[(size_t)(row0 + rg2 * 8 + r) * HID + cg2 * 4] = o;
        }
    }
    grid.sync();

    // ================= P9: pull2 (64 nodes per block) =================
    {
        #pragma unroll 2
        for (int it = 0; it < 16; ++it) {
            int node = bid * 64 + it * 4 + wv;
            int rs = a.rs2[node], cnt = a.ic2[node];
            float a0 = 0.f, a1 = 0.f;
            for (int j = 0; j < cnt; j++) {
                int s = a.srcs2[rs + j];
                float w = a.dinv2[s];
                a0 = fmaf(w, a.hw[(size_t)s * HID + lane], a0);
                a1 = fmaf(w, a.hw[(size_t)s * HID + 64 + lane], a1);
            }
            float df = a.dfull2[node], di = a.dinv2[node];
            float h0 = frelu(a0 * di + a.hw[(size_t)node * HID + lane] / df + a.b2[lane]);
            float h1 = frelu(a1 * di + a.hw[(size_t)node * HID + 64 + lane] / df + a.b2[lane + 64]);
            a.h2[(size_t)node * HID + lane] = h0;
            a.h2[(size_t)node * HID + 64 + lane] = h1;
            float dot = h0 * a.sW2[lane] + h1 * a.sW2[lane + 64];
            #pragma unroll
            for (int o = 32; o > 0; o >>= 1) dot += __shfl_down(dot, o);
            if (lane == 0) {
                a.ds02[node] = di * dot;
                a.sc2i[node] = dot / df + a.sb2[0];
            }
        }
    }
    grid.sync();

    // ================= P10: topk2 + readout2 + head (64 blocks) =================
    if (bid < NB) {
        const int b = bid;
        if (tid == 0) sm.tk.scnt = 0;
        for (int r = tid; r < K1V; r += TPB) {
            int n = b * K1V + r;
            int rs = a.rs2[n], cnt = a.ic2[n];
            float acc = 0.f;
            for (int j = 0; j < cnt; j++) acc += a.ds02[a.srcs2[rs + j]];
            float sc = a.sc2i[n] + a.dinv2[n] * acc;
            sm.tk.sv[r] = sc; sm.tk.skey[r] = f2key(sc);
        }
        __syncthreads();
        u32 tau; int R;
        radix_top<K1V, TPB>(sm.tk.skey, K2V, sm.tk.hist, sm.tk.misc, tau, R);
        {
            int e0 = tid * 2, e1 = e0 + 1;
            u32 k0 = sm.tk.skey[e0], k1 = sm.tk.skey[e1];
            int q0 = (k0 == tau) ? 1 : 0, q1 = (k1 == tau) ? 1 : 0;
            u32 inc = wave_iscan((u32)(q0 + q1), lane);
            if (lane == 63) sm.tk.wsum[wv] = inc;
            __syncthreads();
            if (tid == 0) { u32 run = 0; for (int w2 = 0; w2 < 4; w2++) { u32 v = sm.tk.wsum[w2]; sm.tk.wsum[w2] = run; run += v; } }
            __syncthreads();
            u32 base = sm.tk.wsum[wv] + inc - (u32)(q0 + q1);
            bool sel0 = (k0 > tau) || (q0 && base < (u32)R);
            bool sel1 = (k1 > tau) || (q1 && (base + (u32)q0) < (u32)R);
            if (sel0) { int pos = atomicAdd(&sm.tk.scnt, 1); sm.tk.plist[pos] = b * K1V + e0; sm.tk.tl[pos] = tanhf(sm.tk.sv[e0]); }
            if (sel1) { int pos = atomicAdd(&sm.tk.scnt, 1); sm.tk.plist[pos] = b * K1V + e1; sm.tk.tl[pos] = tanhf(sm.tk.sv[e1]); }
            __syncthreads();
        }
        int c = tid & 127, h = tid >> 7;
        float mx = -INFINITY, smv = 0.f;
        for (int j = h; j < K2V; j += 2) {
            float v = a.h2[(size_t)sm.tk.plist[j] * HID + c] * sm.tk.tl[j];
            mx = fmaxf(mx, v); smv += v;
        }
        if (h == 1) { sm.tk.rmx[c] = mx; sm.tk.rsm[c] = smv; }
        __syncthreads();
        if (h == 0) {
            float fmx = fmaxf(mx, sm.tk.rmx[c]);
            float fsm = smv + sm.tk.rsm[c];
            sm.tk.z[c] = a.x1b[b * 256 + c] + fmx;
            sm.tk.z[128 + c] = a.x1b[b * 256 + 128 + c] + fsm / (float)K2V;
        }
        if (tid < 10) sm.tk.z[256 + tid] = a.gi[b * 10 + tid];
        __syncthreads();
        int t = tid;
        if (t < 128) {
            float acc = a.l1b[t];
            for (int k = 0; k < 266; k++) acc = fmaf(sm.tk.z[k], a.l1W[k * 128 + t], acc);
            sm.tk.z1[t] = frelu(acc);
        }
        __syncthreads();
        if (t < 64) {
            float a2 = a.l2b[t];
            for (int k = 0; k < 128; k++) a2 = fmaf(sm.tk.z1[k], a.l2W[k * 64 + t], a2);
            sm.tk.z2[t] = frelu(a2);
        }
        __syncthreads();
        if (t < 32) {
            float a3 = a.l3b[t];
            for (int k = 0; k < 64; k++) a3 = fmaf(sm.tk.z2[k], a.l3W[k * 32 + t], a3);
            sm.tk.z3[t] = a3;
        }
        __syncthreads();
        if (t == 0) {
            float m = -INFINITY;
            for (int c2 = 0; c2 < 32; c2++) m = fmaxf(m, sm.tk.z3[c2]);
            float s = 0.f;
            for (int c2 = 0; c2 < 32; c2++) s += expf(sm.tk.z3[c2] - m);
            sm.tk.red[0] = m; sm.tk.red[1] = logf(s);
        }
        __syncthreads();
        if (t < 32) a.out[b * 32 + t] = sm.tk.z3[t] - sm.tk.red[0] - sm.tk.red[1];
    }
}

// ============ launch ============
extern "C" void kernel_launch(void* const* d_in, const int* in_sizes, int n_in,
                              void* d_out, int out_size, void* d_ws, size_t ws_size,
                              hipStream_t stream) {
    char* p = (char*)d_ws;
    auto alloc = [&](size_t bytes) {
        char* r = p;
        p += (bytes + 255) & ~size_t(255);
        return (void*)r;
    };

    KArgs a;
    a.x    = (const float*)d_in[0];
    a.esrc = (const int*)d_in[1];
    a.edst = (const int*)d_in[2];
    a.gi   = (const float*)d_in[3];
    a.W1   = (const float*)d_in[4];
    a.b1   = (const float*)d_in[5];
    a.sW1  = (const float*)d_in[6];
    a.sb1  = (const float*)d_in[7];
    a.W2   = (const float*)d_in[8];
    a.b2   = (const float*)d_in[9];
    a.sW2  = (const float*)d_in[10];
    a.sb2  = (const float*)d_in[11];
    a.l1W  = (const float*)d_in[12];
    a.l1b  = (const float*)d_in[13];
    a.l2W  = (const float*)d_in[14];
    a.l2b  = (const float*)d_in[15];
    a.l3W  = (const float*)d_in[16];
    a.l3b  = (const float*)d_in[17];
    a.out  = (float*)d_out;

    a.degp   = (int*)alloc((size_t)NB * NQ * NPG * 4);
    a.df_g   = (float*)alloc((size_t)NB * NPG * 4);
    a.di_g   = (float*)alloc((size_t)NB * NPG * 4);
    a.dx_g   = (float*)alloc((size_t)NB * NPG * 4);
    a.tp     = (float*)alloc((size_t)NB * NQ * NPG * 4);
    a.u_g    = (float*)alloc((size_t)NB * NPG * 4);
    a.ds01_g = (float*)alloc((size_t)NB * NPG * 4);
    a.sci_g  = (float*)alloc((size_t)NB * NPG * 4);
    a.scp    = (float*)alloc((size_t)NB * NQ * NPG * 4);
    a.nmap_g = (int*)alloc((size_t)NB * NPG * 4);
    a.ulist  = (float*)alloc((size_t)N1 * 4);
    a.tg1    = (float*)alloc((size_t)N1 * 4);
    a.x1b    = (float*)alloc((size_t)NB * 256 * 4);
    a.epair  = (int*)alloc((size_t)NB * NQ * QCAP * 4);
    a.eqcnt  = (int*)alloc((size_t)NB * NQ * 4);
    a.ldegp  = (int*)alloc((size_t)NB * NQ * K1V * 4);
    a.srcs2  = (int*)alloc((size_t)NB * SCAP * 4);
    a.rs2    = (int*)alloc((size_t)N1 * 4);
    a.ic2    = (int*)alloc((size_t)N1 * 4);
    a.dfull2 = (float*)alloc((size_t)N1 * 4);
    a.dinv2  = (float*)alloc((size_t)N1 * 4);
    a.hw     = (float*)alloc((size_t)N1 * HID * 4);
    a.h2     = (float*)alloc((size_t)N1 * HID * 4);
    a.ds02   = (float*)alloc((size_t)N1 * 4);
    a.sc2i   = (float*)alloc((size_t)N1 * 4);

    void* kargs[] = { (void*)&a };
    hipLaunchCooperativeKernel((const void*)k_mega, dim3(GRID), dim3(TPB),
                               kargs, 0, stream);
}

// Round 8
// 147.327 us; speedup vs baseline: 4.6926x; 4.6926x over previous
//
#include <hip/hip_runtime.h>
#include <math.h>

#define NB    64
#define NPG   2048      // nodes per graph
#define EPG   16384     // edges per graph
#define HID   128
#define K1V   512
#define K2V   128
#define N1    32768     // NB*K1V
#define SCAP  2048      // per-graph surviving-edge capacity
#define MSK   (NPG - 1)
#define NQ    8         // edge segments per graph
#define ESEG  (EPG / NQ)   // 2048
#define QCAP  256       // per-segment survivor capacity (E~128)

typedef unsigned int u32;

static __device__ __forceinline__ float frelu(float v) { return v > 0.f ? v : 0.f; }

static __device__ __forceinline__ u32 f2key(float f) {
    u32 u = __float_as_uint(f);
    return u ^ ((u >> 31) ? 0xFFFFFFFFu : 0x80000000u);
}

static __device__ __forceinline__ u32 wave_iscan(u32 v, int lane) {
    #pragma unroll
    for (int off = 1; off < 64; off <<= 1) {
        u32 t = __shfl_up(v, off);
        if (lane >= off) v += t;
    }
    return v;
}

// Radix-select the K-th largest key among N LDS keys (T threads).
template <int N, int T>
static __device__ __forceinline__ void radix_top(const u32* __restrict__ key, int K,
                                                 u32* hist, u32* misc,
                                                 u32& tau, int& R) {
    const int tid = threadIdx.x;
    if (tid == 0) { misc[0] = 0u; misc[1] = (u32)K; }
    __syncthreads();
    #pragma unroll
    for (int p = 0; p < 4; p++) {
        const int shift = 24 - 8 * p;
        for (int i = tid; i < 256; i += T) hist[i] = 0u;
        __syncthreads();
        const u32 prefix = misc[0];
        const u32 need   = misc[1];
        for (int i = tid; i < N; i += T) {
            u32 k = key[i];
            bool ok = (p == 0) || ((k >> (shift + 8)) == prefix);
            if (ok) atomicAdd(&hist[(k >> shift) & 255u], 1u);
        }
        __syncthreads();
        if (tid < 64) {
            const int lane = tid;
            u32 c0 = hist[4 * lane + 0], c1 = hist[4 * lane + 1];
            u32 c2 = hist[4 * lane + 2], c3 = hist[4 * lane + 3];
            u32 local = c0 + c1 + c2 + c3;
            u32 inc = local;
            #pragma unroll
            for (int off = 1; off < 64; off <<= 1) {
                u32 v = __shfl_down(inc, off);
                if (lane + off < 64) inc += v;
            }
            u32 excl = inc - local;
            u32 ge3 = excl + c3, ge2 = ge3 + c2, ge1 = ge2 + c1, ge0 = ge1 + c0;
            int selb = -1; u32 gt = 0;
            if      (ge3 >= need && excl < need) { selb = 4 * lane + 3; gt = excl; }
            else if (ge2 >= need && ge3  < need) { selb = 4 * lane + 2; gt = ge3; }
            else if (ge1 >= need && ge2  < need) { selb = 4 * lane + 1; gt = ge2; }
            else if (ge0 >= need && ge1  < need) { selb = 4 * lane + 0; gt = ge1; }
            if (selb >= 0) { misc[0] = (prefix << 8) | (u32)selb; misc[1] = need - gt; }
        }
        __syncthreads();
    }
    tau = misc[0];
    R = (int)misc[1];
}

// ===== K1: per-segment degree histogram =====
__global__ __launch_bounds__(256) void k_deg8(const int* __restrict__ edst,
                                              int* __restrict__ degp) {
    __shared__ int cnt[NPG];
    const int bid = blockIdx.x, tid = threadIdx.x;
    const int g = bid >> 3, q = bid & 7;
    for (int i = tid; i < NPG; i += 256) cnt[i] = 0;
    __syncthreads();
    const int4* d4 = (const int4*)(edst + g * EPG + q * ESEG);
    for (int i = tid; i < ESEG / 4; i += 256) {
        int4 dd = d4[i];
        atomicAdd(&cnt[dd.x & MSK], 1); atomicAdd(&cnt[dd.y & MSK], 1);
        atomicAdd(&cnt[dd.z & MSK], 1); atomicAdd(&cnt[dd.w & MSK], 1);
    }
    __syncthreads();
    int4* op = (int4*)(degp + (size_t)bid * NPG);
    const int4* cp4 = (const int4*)cnt;
    for (int i = tid; i < NPG / 4; i += 256) op[i] = cp4[i];
}

// ===== K2: fused nodeA + t-sweep =====
// deg-reduce -> di -> dx (in LDS), then t[d] += dx[s]; q==0 writes df/di.
__global__ __launch_bounds__(256) void k_sweepA(const float* __restrict__ x,
                                                const int* __restrict__ esrc,
                                                const int* __restrict__ edst,
                                                const int* __restrict__ degp,
                                                float* __restrict__ df_g,
                                                float* __restrict__ di_g,
                                                float* __restrict__ tp) {
    __shared__ float lv[NPG];
    __shared__ float acc[NPG];
    const int bid = blockIdx.x, tid = threadIdx.x;
    const int g = bid >> 3, q = bid & 7;
    for (int i = tid; i < NPG; i += 256) {
        int dg = 0;
        #pragma unroll
        for (int q2 = 0; q2 < NQ; q2++) dg += degp[(size_t)(g * NQ + q2) * NPG + i];
        float df = (float)dg + 1.0f;
        float di = rsqrtf(df);
        lv[i] = di * x[(size_t)g * NPG + i];
        acc[i] = 0.f;
        if (q == 0) { df_g[(size_t)g * NPG + i] = df; di_g[(size_t)g * NPG + i] = di; }
    }
    __syncthreads();
    const int4* s4 = (const int4*)(esrc + g * EPG + q * ESEG);
    const int4* d4 = (const int4*)(edst + g * EPG + q * ESEG);
    for (int i = tid; i < ESEG / 4; i += 256) {
        int4 ss = s4[i]; int4 dd = d4[i];
        atomicAdd(&acc[dd.x & MSK], lv[ss.x & MSK]);
        atomicAdd(&acc[dd.y & MSK], lv[ss.y & MSK]);
        atomicAdd(&acc[dd.z & MSK], lv[ss.z & MSK]);
        atomicAdd(&acc[dd.w & MSK], lv[ss.w & MSK]);
    }
    __syncthreads();
    float4* op = (float4*)(tp + (size_t)bid * NPG);
    const float4* ap = (const float4*)acc;
    for (int i = tid; i < NPG / 4; i += 256) op[i] = ap[i];
}

// ===== K3: fused nodeB + score-sweep =====
// t-reduce -> u -> MLP -> ds01 (LDS), then raw[d] += ds01[s]; q==0 writes u/sci.
__global__ __launch_bounds__(256) void k_sweepB(const float* __restrict__ x,
                                                const int* __restrict__ esrc,
                                                const int* __restrict__ edst,
                                                const float* __restrict__ tp,
                                                const float* __restrict__ df_g,
                                                const float* __restrict__ di_g,
                                                const float* __restrict__ W1,
                                                const float* __restrict__ b1,
                                                const float* __restrict__ sW1,
                                                const float* __restrict__ sb1,
                                                float* __restrict__ u_g,
                                                float* __restrict__ sci_g,
                                                float* __restrict__ scp) {
    __shared__ float lv[NPG];
    __shared__ float acc[NPG];
    __shared__ float lw[HID], lbb[HID], lsw[HID];
    const int bid = blockIdx.x, tid = threadIdx.x;
    const int g = bid >> 3, q = bid & 7;
    if (tid < HID) { lw[tid] = W1[tid]; lbb[tid] = b1[tid]; lsw[tid] = sW1[tid]; }
    __syncthreads();
    const float sb1v = sb1[0];
    for (int i = tid; i < NPG; i += 256) {
        float t = 0.f;
        #pragma unroll
        for (int q2 = 0; q2 < NQ; q2++) t += tp[(size_t)(g * NQ + q2) * NPG + i];
        float df = df_g[(size_t)g * NPG + i];
        float di = di_g[(size_t)g * NPG + i];
        float u = t * di + x[(size_t)g * NPG + i] / df;
        float s = 0.f;
        #pragma unroll 8
        for (int c = 0; c < HID; c++) s += frelu(fmaf(lw[c], u, lbb[c])) * lsw[c];
        lv[i] = di * s;
        acc[i] = 0.f;
        if (q == 0) {
            u_g[(size_t)g * NPG + i] = u;
            sci_g[(size_t)g * NPG + i] = s / df + sb1v;
        }
    }
    __syncthreads();
    const int4* s4 = (const int4*)(esrc + g * EPG + q * ESEG);
    const int4* d4 = (const int4*)(edst + g * EPG + q * ESEG);
    for (int i = tid; i < ESEG / 4; i += 256) {
        int4 ss = s4[i]; int4 dd = d4[i];
        atomicAdd(&acc[dd.x & MSK], lv[ss.x & MSK]);
        atomicAdd(&acc[dd.y & MSK], lv[ss.y & MSK]);
        atomicAdd(&acc[dd.z & MSK], lv[ss.z & MSK]);
        atomicAdd(&acc[dd.w & MSK], lv[ss.w & MSK]);
    }
    __syncthreads();
    float4* op = (float4*)(scp + (size_t)bid * NPG);
    const float4* ap = (const float4*)acc;
    for (int i = tid; i < NPG / 4; i += 256) op[i] = ap[i];
}

// ===== K4: per-graph score finalize, radix top-512, nmap, readout1 =====
__global__ __launch_bounds__(1024) void k_select(
    const float* __restrict__ sci_g, const float* __restrict__ di_g,
    const float* __restrict__ scp, const float* __restrict__ u_g,
    const float* __restrict__ W1, const float* __restrict__ b1,
    float* __restrict__ ulist, float* __restrict__ tg1, float* __restrict__ x1b,
    int* __restrict__ nmap_g)
{
    __shared__ float lsc[NPG];
    __shared__ u32   lkey[NPG];
    __shared__ int   ln[NPG];
    __shared__ float ul[K1V], tgl[K1V];
    __shared__ int   sellist[K1V];
    __shared__ u32   hist[256], misc[2], wsum[16];
    __shared__ int   scnt;
    __shared__ float lw[HID], lbb[HID];
    const int b = blockIdx.x, tid = threadIdx.x;
    const int lane = tid & 63, wv = tid >> 6;

    for (int i = tid; i < NPG; i += 1024) {
        float a = 0.f;
        #pragma unroll
        for (int q = 0; q < NQ; q++) a += scp[(size_t)(b * NQ + q) * NPG + i];
        float sc = sci_g[(size_t)b * NPG + i] + di_g[(size_t)b * NPG + i] * a;
        lsc[i] = sc;
        lkey[i] = f2key(sc);
        ln[i] = -1;
    }
    if (tid < HID) { lw[tid] = W1[tid]; lbb[tid] = b1[tid]; }
    if (tid == 0) scnt = 0;
    __syncthreads();

    u32 tau; int R;
    radix_top<NPG, 1024>(lkey, K1V, hist, misc, tau, R);

    // stable tie rank (lowest index first)
    {
        int e0 = tid * 2, e1 = e0 + 1;
        u32 k0 = lkey[e0], k1 = lkey[e1];
        int q0 = (k0 == tau) ? 1 : 0, q1 = (k1 == tau) ? 1 : 0;
        u32 inc = wave_iscan((u32)(q0 + q1), lane);
        if (lane == 63) wsum[wv] = inc;
        __syncthreads();
        if (tid == 0) { u32 run = 0; for (int w2 = 0; w2 < 16; w2++) { u32 v = wsum[w2]; wsum[w2] = run; run += v; } }
        __syncthreads();
        u32 base = wsum[wv] + inc - (u32)(q0 + q1);
        bool sel0 = (k0 > tau) || (q0 && base < (u32)R);
        bool sel1 = (k1 > tau) || (q1 && (base + (u32)q0) < (u32)R);
        if (sel0) { int pos = atomicAdd(&scnt, 1); sellist[pos] = e0; }
        if (sel1) { int pos = atomicAdd(&scnt, 1); sellist[pos] = e1; }
        __syncthreads();
    }

    if (tid < K1V) {
        int node = sellist[tid];
        float uu = u_g[(size_t)b * NPG + node];
        float g = tanhf(lsc[node]);
        ul[tid] = uu; tgl[tid] = g;
        ulist[b * K1V + tid] = uu;
        tg1[b * K1V + tid] = g;
        ln[node] = tid;
    }
    __syncthreads();
    for (int i = tid; i < NPG; i += 1024) nmap_g[(size_t)b * NPG + i] = ln[i];

    // readout1: reuse lkey as two 1024-float partial arrays
    float* rp = (float*)lkey;
    {
        int grp = tid >> 7, c = tid & 127;
        float w = lw[c], bb = lbb[c];
        float mx = -INFINITY, sm = 0.f;
        for (int j = grp; j < K1V; j += 8) {
            float v = frelu(fmaf(w, ul[j], bb)) * tgl[j];
            mx = fmaxf(mx, v); sm += v;
        }
        __syncthreads();
        rp[tid] = mx; rp[1024 + tid] = sm;
        __syncthreads();
        if (tid < HID) {
            float m2 = -INFINITY, s2 = 0.f;
            #pragma unroll
            for (int g2 = 0; g2 < 8; g2++) {
                m2 = fmaxf(m2, rp[g2 * 128 + tid]);
                s2 += rp[1024 + g2 * 128 + tid];
            }
            x1b[b * 256 + tid] = m2;
            x1b[b * 256 + HID + tid] = s2 / (float)K1V;
        }
    }
}

// ===== K5: per-segment edge compaction =====
__global__ __launch_bounds__(256) void k_compact8(const int* __restrict__ esrc,
                                                  const int* __restrict__ edst,
                                                  const int* __restrict__ nmap_g,
                                                  int* __restrict__ epair,
                                                  int* __restrict__ eqcnt,
                                                  int* __restrict__ ldegp) {
    __shared__ int lnm[NPG];
    __shared__ int pbuf[QCAP];
    __shared__ int lda[K1V];
    __shared__ int lcnt;
    const int bid = blockIdx.x, tid = threadIdx.x;
    const int g = bid >> 3, q = bid & 7;
    for (int i = tid; i < NPG; i += 256) lnm[i] = nmap_g[(size_t)g * NPG + i];
    for (int i = tid; i < K1V; i += 256) lda[i] = 0;
    if (tid == 0) lcnt = 0;
    __syncthreads();
    const int4* s4 = (const int4*)(esrc + g * EPG + q * ESEG);
    const int4* d4 = (const int4*)(edst + g * EPG + q * ESEG);
    for (int i = tid; i < ESEG / 4; i += 256) {
        int4 ss = s4[i]; int4 dd = d4[i];
        int sa[4] = { ss.x & MSK, ss.y & MSK, ss.z & MSK, ss.w & MSK };
        int da[4] = { dd.x & MSK, dd.y & MSK, dd.z & MSK, dd.w & MSK };
        #pragma unroll
        for (int r = 0; r < 4; r++) {
            int s2 = lnm[sa[r]], d2 = lnm[da[r]];
            if (s2 >= 0 && d2 >= 0) {
                int p = atomicAdd(&lcnt, 1);
                if (p < QCAP) { pbuf[p] = s2 | (d2 << 16); atomicAdd(&lda[d2], 1); }
            }
        }
    }
    __syncthreads();
    int cnt = lcnt < QCAP ? lcnt : QCAP;
    if (tid == 0) eqcnt[bid] = cnt;
    for (int i = tid; i < cnt; i += 256) epair[(size_t)bid * QCAP + i] = pbuf[i];
    for (int i = tid; i < K1V; i += 256) ldegp[(size_t)bid * K1V + i] = lda[i];
}

// ===== K6: csr (blocks 0..63) || matmul (blocks 64..575) =====
__global__ __launch_bounds__(256) void k_csrmm(
    const int* __restrict__ ldegp, const int* __restrict__ eqcnt,
    const int* __restrict__ epair,
    int* __restrict__ srcs2, int* __restrict__ rs2, int* __restrict__ ic2,
    float* __restrict__ dfull2, float* __restrict__ dinv2,
    const float* __restrict__ ulist, const float* __restrict__ tg1,
    const float* __restrict__ W1, const float* __restrict__ b1,
    const float* __restrict__ W2, float* __restrict__ hw)
{
    __shared__ union {
        struct { int cur[K1V]; u32 wsum[4]; } csr;
        struct { float lhT[HID * 64]; float lu[64], lg[64]; } mm;
    } sm;
    const int bid = blockIdx.x, tid = threadIdx.x;
    const int lane = tid & 63, wv = tid >> 6;

    if (bid < NB) {
        const int b = bid;
        int e0 = tid * 2, e1 = e0 + 1;
        int dv0 = 0, dv1 = 0;
        #pragma unroll
        for (int q = 0; q < NQ; q++) {
            dv0 += ldegp[(size_t)(b * NQ + q) * K1V + e0];
            dv1 += ldegp[(size_t)(b * NQ + q) * K1V + e1];
        }
        int pr = dv0 + dv1;
        u32 inc = wave_iscan((u32)pr, lane);
        if (lane == 63) sm.csr.wsum[wv] = inc;
        __syncthreads();
        if (tid == 0) { u32 run = 0; for (int w2 = 0; w2 < 4; w2++) { u32 v = sm.csr.wsum[w2]; sm.csr.wsum[w2] = run; run += v; } }
        __syncthreads();
        int exclp = (int)(sm.csr.wsum[wv] + inc - (u32)pr);
        {
            int n0 = b * K1V + e0;
            rs2[n0] = b * SCAP + exclp; ic2[n0] = dv0;
            float df0 = (float)dv0 + 1.0f;
            dfull2[n0] = df0; dinv2[n0] = rsqrtf(df0);
            sm.csr.cur[e0] = exclp;
            int excl1 = exclp + dv0;
            int n1 = b * K1V + e1;
            rs2[n1] = b * SCAP + excl1; ic2[n1] = dv1;
            float df1 = (float)dv1 + 1.0f;
            dfull2[n1] = df1; dinv2[n1] = rsqrtf(df1);
            sm.csr.cur[e1] = excl1;
        }
        __syncthreads();
        for (int q = 0; q < NQ; q++) {
            int cnt = eqcnt[b * NQ + q];
            for (int i = tid; i < cnt; i += 256) {
                int pk = epair[(size_t)(b * NQ + q) * QCAP + i];
                int s2 = pk & 0xffff, d2 = pk >> 16;
                int pos = atomicAdd(&sm.csr.cur[d2], 1);
                srcs2[(size_t)b * SCAP + pos] = b * K1V + s2;
            }
        }
    } else {
        const int row0 = (bid - NB) * 64;
        if (tid < 64) { sm.mm.lu[tid] = ulist[row0 + tid]; sm.mm.lg[tid] = tg1[row0 + tid]; }
        __syncthreads();
        for (int idx = tid; idx < HID * 64; idx += 256) {
            int k = idx >> 6, j = idx & 63;
            sm.mm.lhT[idx] = frelu(fmaf(W1[k], sm.mm.lu[j], b1[k])) * sm.mm.lg[j];
        }
        __syncthreads();
        const int cg2 = tid & 31, rg2 = tid >> 5;
        float acc[8][4];
        #pragma unroll
        for (int r = 0; r < 8; r++)
            #pragma unroll
            for (int c = 0; c < 4; c++) acc[r][c] = 0.f;
        const float4* lhT4 = (const float4*)sm.mm.lhT;
        #pragma unroll 4
        for (int k = 0; k < HID; k++) {
            float4 h0 = lhT4[k * 16 + rg2 * 2];
            float4 h1 = lhT4[k * 16 + rg2 * 2 + 1];
            float4 ww = *(const float4*)&W2[(size_t)k * HID + cg2 * 4];
            float hr[8] = { h0.x, h0.y, h0.z, h0.w, h1.x, h1.y, h1.z, h1.w };
            float wc[4] = { ww.x, ww.y, ww.z, ww.w };
            #pragma unroll
            for (int r = 0; r < 8; r++)
                #pragma unroll
                for (int c = 0; c < 4; c++)
                    acc[r][c] = fmaf(hr[r], wc[c], acc[r][c]);
        }
        #pragma unroll
        for (int r = 0; r < 8; r++) {
            float4 o; o.x = acc[r][0]; o.y = acc[r][1]; o.z = acc[r][2]; o.w = acc[r][3];
            *(float4*)&hw[(size_t)(row0 + rg2 * 8 + r) * HID + cg2 * 4] = o;
        }
    }
}

// ===== K7: stage-2 GCN via CSR pull, fused bias/relu/score =====
__global__ __launch_bounds__(256) void k_pull2(
    const int* __restrict__ srcs2, const int* __restrict__ rs2, const int* __restrict__ ic2,
    const float* __restrict__ dfull2, const float* __restrict__ dinv2,
    const float* __restrict__ hw, const float* __restrict__ b2,
    const float* __restrict__ sW2, const float* __restrict__ sb2,
    float* __restrict__ h2, float* __restrict__ ds02, float* __restrict__ sc2i)
{
    int node = blockIdx.x * 4 + (threadIdx.x >> 6);
    int lane = threadIdx.x & 63;
    int rs = rs2[node], cnt = ic2[node];
    float a0 = 0.f, a1 = 0.f;
    for (int j = 0; j < cnt; j++) {
        int s = srcs2[rs + j];
        float w = dinv2[s];
        a0 = fmaf(w, hw[(size_t)s * HID + lane], a0);
        a1 = fmaf(w, hw[(size_t)s * HID + 64 + lane], a1);
    }
    float df = dfull2[node], di = dinv2[node];
    float h0 = frelu(a0 * di + hw[(size_t)node * HID + lane] / df + b2[lane]);
    float h1 = frelu(a1 * di + hw[(size_t)node * HID + 64 + lane] / df + b2[lane + 64]);
    h2[(size_t)node * HID + lane] = h0;
    h2[(size_t)node * HID + 64 + lane] = h1;
    float dot = h0 * sW2[lane] + h1 * sW2[lane + 64];
    #pragma unroll
    for (int o = 32; o > 0; o >>= 1) dot += __shfl_down(dot, o);
    if (lane == 0) {
        ds02[node] = di * dot;
        sc2i[node] = dot / df + sb2[0];
    }
}

// ===== K8: topk2 + readout2 + head =====
__global__ __launch_bounds__(256) void k_tkhead(
    const int* __restrict__ srcs2, const int* __restrict__ rs2, const int* __restrict__ ic2,
    const float* __restrict__ dinv2, const float* __restrict__ ds02,
    const float* __restrict__ sc2i, const float* __restrict__ h2,
    const float* __restrict__ x1b, const float* __restrict__ gi,
    const float* __restrict__ l1W, const float* __restrict__ l1b,
    const float* __restrict__ l2W, const float* __restrict__ l2b,
    const float* __restrict__ l3W, const float* __restrict__ l3b,
    float* __restrict__ out)
{
    __shared__ float sv[K1V];
    __shared__ u32   skey[K1V];
    __shared__ u32   hist[256], misc[2], wsum[4];
    __shared__ int   plist[K2V];
    __shared__ float tl[K2V];
    __shared__ float rmx[HID], rsm[HID];
    __shared__ float z[266], z1[HID], z2[64], z3[32], red[2];
    __shared__ int   scnt;
    const int b = blockIdx.x, tid = threadIdx.x;
    const int lane = tid & 63, wv = tid >> 6;
    if (tid == 0) scnt = 0;
    for (int r = tid; r < K1V; r += 256) {
        int n = b * K1V + r;
        int rsv = rs2[n], cnt = ic2[n];
        float acc = 0.f;
        for (int j = 0; j < cnt; j++) acc += ds02[srcs2[rsv + j]];
        float sc = sc2i[n] + dinv2[n] * acc;
        sv[r] = sc; skey[r] = f2key(sc);
    }
    __syncthreads();
    u32 tau; int R;
    radix_top<K1V, 256>(skey, K2V, hist, misc, tau, R);
    {
        int e0 = tid * 2, e1 = e0 + 1;
        u32 k0 = skey[e0], k1 = skey[e1];
        int q0 = (k0 == tau) ? 1 : 0, q1 = (k1 == tau) ? 1 : 0;
        u32 inc = wave_iscan((u32)(q0 + q1), lane);
        if (lane == 63) wsum[wv] = inc;
        __syncthreads();
        if (tid == 0) { u32 run = 0; for (int w2 = 0; w2 < 4; w2++) { u32 v = wsum[w2]; wsum[w2] = run; run += v; } }
        __syncthreads();
        u32 base = wsum[wv] + inc - (u32)(q0 + q1);
        bool sel0 = (k0 > tau) || (q0 && base < (u32)R);
        bool sel1 = (k1 > tau) || (q1 && (base + (u32)q0) < (u32)R);
        if (sel0) { int pos = atomicAdd(&scnt, 1); plist[pos] = b * K1V + e0; tl[pos] = tanhf(sv[e0]); }
        if (sel1) { int pos = atomicAdd(&scnt, 1); plist[pos] = b * K1V + e1; tl[pos] = tanhf(sv[e1]); }
        __syncthreads();
    }
    int c = tid & 127, h = tid >> 7;
    float mx = -INFINITY, smv = 0.f;
    for (int j = h; j < K2V; j += 2) {
        float v = h2[(size_t)plist[j] * HID + c] * tl[j];
        mx = fmaxf(mx, v); smv += v;
    }
    if (h == 1) { rmx[c] = mx; rsm[c] = smv; }
    __syncthreads();
    if (h == 0) {
        float fmx = fmaxf(mx, rmx[c]);
        float fsm = smv + rsm[c];
        z[c] = x1b[b * 256 + c] + fmx;
        z[128 + c] = x1b[b * 256 + 128 + c] + fsm / (float)K2V;
    }
    if (tid < 10) z[256 + tid] = gi[b * 10 + tid];
    __syncthreads();
    int t = tid;
    if (t < 128) {
        float acc = l1b[t];
        for (int k = 0; k < 266; k++) acc = fmaf(z[k], l1W[k * 128 + t], acc);
        z1[t] = frelu(acc);
    }
    __syncthreads();
    if (t < 64) {
        float a2 = l2b[t];
        for (int k = 0; k < 128; k++) a2 = fmaf(z1[k], l2W[k * 64 + t], a2);
        z2[t] = frelu(a2);
    }
    __syncthreads();
    if (t < 32) {
        float a3 = l3b[t];
        for (int k = 0; k < 64; k++) a3 = fmaf(z2[k], l3W[k * 32 + t], a3);
        z3[t] = a3;
    }
    __syncthreads();
    if (t == 0) {
        float m = -INFINITY;
        for (int c2 = 0; c2 < 32; c2++) m = fmaxf(m, z3[c2]);
        float s = 0.f;
        for (int c2 = 0; c2 < 32; c2++) s += expf(z3[c2] - m);
        red[0] = m; red[1] = logf(s);
    }
    __syncthreads();
    if (t < 32) out[b * 32 + t] = z3[t] - red[0] - red[1];
}

// ============ launch ============
extern "C" void kernel_launch(void* const* d_in, const int* in_sizes, int n_in,
                              void* d_out, int out_size, void* d_ws, size_t ws_size,
                              hipStream_t stream) {
    const float* x    = (const float*)d_in[0];
    const int*   esrc = (const int*)d_in[1];
    const int*   edst = (const int*)d_in[2];
    const float* gi   = (const float*)d_in[3];
    const float* W1   = (const float*)d_in[4];
    const float* b1   = (const float*)d_in[5];
    const float* sW1  = (const float*)d_in[6];
    const float* sb1  = (const float*)d_in[7];
    const float* W2   = (const float*)d_in[8];
    const float* b2   = (const float*)d_in[9];
    const float* sW2  = (const float*)d_in[10];
    const float* sb2  = (const float*)d_in[11];
    const float* l1W  = (const float*)d_in[12];
    const float* l1b  = (const float*)d_in[13];
    const float* l2W  = (const float*)d_in[14];
    const float* l2b  = (const float*)d_in[15];
    const float* l3W  = (const float*)d_in[16];
    const float* l3b  = (const float*)d_in[17];
    float* out = (float*)d_out;

    char* p = (char*)d_ws;
    auto alloc = [&](size_t bytes) {
        char* r = p;
        p += (bytes + 255) & ~size_t(255);
        return (void*)r;
    };
    int*   degp   = (int*)alloc((size_t)NB * NQ * NPG * 4);
    float* df_g   = (float*)alloc((size_t)NB * NPG * 4);
    float* di_g   = (float*)alloc((size_t)NB * NPG * 4);
    float* tp     = (float*)alloc((size_t)NB * NQ * NPG * 4);
    float* u_g    = (float*)alloc((size_t)NB * NPG * 4);
    float* sci_g  = (float*)alloc((size_t)NB * NPG * 4);
    float* scp    = (float*)alloc((size_t)NB * NQ * NPG * 4);
    int*   nmap_g = (int*)alloc((size_t)NB * NPG * 4);
    float* ulist  = (float*)alloc((size_t)N1 * 4);
    float* tg1    = (float*)alloc((size_t)N1 * 4);
    float* x1b    = (float*)alloc((size_t)NB * 256 * 4);
    int*   epair  = (int*)alloc((size_t)NB * NQ * QCAP * 4);
    int*   eqcnt  = (int*)alloc((size_t)NB * NQ * 4);
    int*   ldegp  = (int*)alloc((size_t)NB * NQ * K1V * 4);
    int*   srcs2  = (int*)alloc((size_t)NB * SCAP * 4);
    int*   rs2    = (int*)alloc((size_t)N1 * 4);
    int*   ic2    = (int*)alloc((size_t)N1 * 4);
    float* dfull2 = (float*)alloc((size_t)N1 * 4);
    float* dinv2  = (float*)alloc((size_t)N1 * 4);
    float* hw     = (float*)alloc((size_t)N1 * HID * 4);
    float* h2     = (float*)alloc((size_t)N1 * HID * 4);
    float* ds02   = (float*)alloc((size_t)N1 * 4);
    float* sc2i   = (float*)alloc((size_t)N1 * 4);

    k_deg8<<<NB * NQ, 256, 0, stream>>>(edst, degp);
    k_sweepA<<<NB * NQ, 256, 0, stream>>>(x, esrc, edst, degp, df_g, di_g, tp);
    k_sweepB<<<NB * NQ, 256, 0, stream>>>(x, esrc, edst, tp, df_g, di_g,
                                          W1, b1, sW1, sb1, u_g, sci_g, scp);
    k_select<<<NB, 1024, 0, stream>>>(sci_g, di_g, scp, u_g, W1, b1,
                                      ulist, tg1, x1b, nmap_g);
    k_compact8<<<NB * NQ, 256, 0, stream>>>(esrc, edst, nmap_g, epair, eqcnt, ldegp);
    k_csrmm<<<NB + N1 / 64, 256, 0, stream>>>(ldegp, eqcnt, epair, srcs2, rs2, ic2,
                                              dfull2, dinv2, ulist, tg1, W1, b1, W2, hw);
    k_pull2<<<N1 / 4, 256, 0, stream>>>(srcs2, rs2, ic2, dfull2, dinv2, hw,
                                        b2, sW2, sb2, h2, ds02, sc2i);
    k_tkhead<<<NB, 256, 0, stream>>>(srcs2, rs2, ic2, dinv2, ds02, sc2i, h2,
                                     x1b, gi, l1W, l1b, l2W, l2b, l3W, l3b, out);
}

// Round 9
// 133.439 us; speedup vs baseline: 5.1810x; 1.1041x over previous
//
#include <hip/hip_runtime.h>
#include <math.h>

#define NB    64
#define NPG   2048      // nodes per graph
#define EPG   16384     // edges per graph
#define HID   128
#define K1V   512
#define K2V   128
#define N1    32768     // NB*K1V
#define SCAP  2048      // per-graph surviving-edge capacity
#define MSK   (NPG - 1)
#define NQ    8         // edge segments per graph
#define ESEG  (EPG / NQ)   // 2048
#define QCAP  256       // per-segment survivor capacity (E~128)

typedef unsigned int u32;

static __device__ __forceinline__ float frelu(float v) { return v > 0.f ? v : 0.f; }

static __device__ __forceinline__ u32 f2key(float f) {
    u32 u = __float_as_uint(f);
    return u ^ ((u >> 31) ? 0xFFFFFFFFu : 0x80000000u);
}

static __device__ __forceinline__ u32 wave_iscan(u32 v, int lane) {
    #pragma unroll
    for (int off = 1; off < 64; off <<= 1) {
        u32 t = __shfl_up(v, off);
        if (lane >= off) v += t;
    }
    return v;
}

// Radix-select the K-th largest key among N LDS keys (T threads).
template <int N, int T>
static __device__ __forceinline__ void radix_top(const u32* __restrict__ key, int K,
                                                 u32* hist, u32* misc,
                                                 u32& tau, int& R) {
    const int tid = threadIdx.x;
    if (tid == 0) { misc[0] = 0u; misc[1] = (u32)K; }
    __syncthreads();
    #pragma unroll
    for (int p = 0; p < 4; p++) {
        const int shift = 24 - 8 * p;
        for (int i = tid; i < 256; i += T) hist[i] = 0u;
        __syncthreads();
        const u32 prefix = misc[0];
        const u32 need   = misc[1];
        for (int i = tid; i < N; i += T) {
            u32 k = key[i];
            bool ok = (p == 0) || ((k >> (shift + 8)) == prefix);
            if (ok) atomicAdd(&hist[(k >> shift) & 255u], 1u);
        }
        __syncthreads();
        if (tid < 64) {
            const int lane = tid;
            u32 c0 = hist[4 * lane + 0], c1 = hist[4 * lane + 1];
            u32 c2 = hist[4 * lane + 2], c3 = hist[4 * lane + 3];
            u32 local = c0 + c1 + c2 + c3;
            u32 inc = local;
            #pragma unroll
            for (int off = 1; off < 64; off <<= 1) {
                u32 v = __shfl_down(inc, off);
                if (lane + off < 64) inc += v;
            }
            u32 excl = inc - local;
            u32 ge3 = excl + c3, ge2 = ge3 + c2, ge1 = ge2 + c1, ge0 = ge1 + c0;
            int selb = -1; u32 gt = 0;
            if      (ge3 >= need && excl < need) { selb = 4 * lane + 3; gt = excl; }
            else if (ge2 >= need && ge3  < need) { selb = 4 * lane + 2; gt = ge3; }
            else if (ge1 >= need && ge2  < need) { selb = 4 * lane + 1; gt = ge2; }
            else if (ge0 >= need && ge1  < need) { selb = 4 * lane + 0; gt = ge1; }
            if (selb >= 0) { misc[0] = (prefix << 8) | (u32)selb; misc[1] = need - gt; }
        }
        __syncthreads();
    }
    tau = misc[0];
    R = (int)misc[1];
}

// ===== K1: per-segment degree histogram =====
__global__ __launch_bounds__(256) void k_deg8(const int* __restrict__ edst,
                                              int* __restrict__ degp) {
    __shared__ int cnt[NPG];
    const int bid = blockIdx.x, tid = threadIdx.x;
    const int g = bid >> 3, q = bid & 7;
    for (int i = tid; i < NPG; i += 256) cnt[i] = 0;
    __syncthreads();
    const int4* d4 = (const int4*)(edst + g * EPG + q * ESEG);
    for (int i = tid; i < ESEG / 4; i += 256) {
        int4 dd = d4[i];
        atomicAdd(&cnt[dd.x & MSK], 1); atomicAdd(&cnt[dd.y & MSK], 1);
        atomicAdd(&cnt[dd.z & MSK], 1); atomicAdd(&cnt[dd.w & MSK], 1);
    }
    __syncthreads();
    int4* op = (int4*)(degp + (size_t)bid * NPG);
    const int4* cp4 = (const int4*)cnt;
    for (int i = tid; i < NPG / 4; i += 256) op[i] = cp4[i];
}

// ===== K2: fused nodeA + t-sweep =====
__global__ __launch_bounds__(256) void k_sweepA(const float* __restrict__ x,
                                                const int* __restrict__ esrc,
                                                const int* __restrict__ edst,
                                                const int* __restrict__ degp,
                                                float* __restrict__ df_g,
                                                float* __restrict__ di_g,
                                                float* __restrict__ tp) {
    __shared__ float lv[NPG];
    __shared__ float acc[NPG];
    const int bid = blockIdx.x, tid = threadIdx.x;
    const int g = bid >> 3, q = bid & 7;
    for (int i = tid; i < NPG; i += 256) {
        int dg = 0;
        #pragma unroll
        for (int q2 = 0; q2 < NQ; q2++) dg += degp[(size_t)(g * NQ + q2) * NPG + i];
        float df = (float)dg + 1.0f;
        float di = rsqrtf(df);
        lv[i] = di * x[(size_t)g * NPG + i];
        acc[i] = 0.f;
        if (q == 0) { df_g[(size_t)g * NPG + i] = df; di_g[(size_t)g * NPG + i] = di; }
    }
    __syncthreads();
    const int4* s4 = (const int4*)(esrc + g * EPG + q * ESEG);
    const int4* d4 = (const int4*)(edst + g * EPG + q * ESEG);
    for (int i = tid; i < ESEG / 4; i += 256) {
        int4 ss = s4[i]; int4 dd = d4[i];
        atomicAdd(&acc[dd.x & MSK], lv[ss.x & MSK]);
        atomicAdd(&acc[dd.y & MSK], lv[ss.y & MSK]);
        atomicAdd(&acc[dd.z & MSK], lv[ss.z & MSK]);
        atomicAdd(&acc[dd.w & MSK], lv[ss.w & MSK]);
    }
    __syncthreads();
    float4* op = (float4*)(tp + (size_t)bid * NPG);
    const float4* ap = (const float4*)acc;
    for (int i = tid; i < NPG / 4; i += 256) op[i] = ap[i];
}

// ===== K3: fused nodeB + score-sweep =====
__global__ __launch_bounds__(256) void k_sweepB(const float* __restrict__ x,
                                                const int* __restrict__ esrc,
                                                const int* __restrict__ edst,
                                                const float* __restrict__ tp,
                                                const float* __restrict__ df_g,
                                                const float* __restrict__ di_g,
                                                const float* __restrict__ W1,
                                                const float* __restrict__ b1,
                                                const float* __restrict__ sW1,
                                                const float* __restrict__ sb1,
                                                float* __restrict__ u_g,
                                                float* __restrict__ sci_g,
                                                float* __restrict__ scp) {
    __shared__ float lv[NPG];
    __shared__ float acc[NPG];
    __shared__ float lw[HID], lbb[HID], lsw[HID];
    const int bid = blockIdx.x, tid = threadIdx.x;
    const int g = bid >> 3, q = bid & 7;
    if (tid < HID) { lw[tid] = W1[tid]; lbb[tid] = b1[tid]; lsw[tid] = sW1[tid]; }
    __syncthreads();
    const float sb1v = sb1[0];
    for (int i = tid; i < NPG; i += 256) {
        float t = 0.f;
        #pragma unroll
        for (int q2 = 0; q2 < NQ; q2++) t += tp[(size_t)(g * NQ + q2) * NPG + i];
        float df = df_g[(size_t)g * NPG + i];
        float di = di_g[(size_t)g * NPG + i];
        float u = t * di + x[(size_t)g * NPG + i] / df;
        float s = 0.f;
        #pragma unroll 8
        for (int c = 0; c < HID; c++) s += frelu(fmaf(lw[c], u, lbb[c])) * lsw[c];
        lv[i] = di * s;
        acc[i] = 0.f;
        if (q == 0) {
            u_g[(size_t)g * NPG + i] = u;
            sci_g[(size_t)g * NPG + i] = s / df + sb1v;
        }
    }
    __syncthreads();
    const int4* s4 = (const int4*)(esrc + g * EPG + q * ESEG);
    const int4* d4 = (const int4*)(edst + g * EPG + q * ESEG);
    for (int i = tid; i < ESEG / 4; i += 256) {
        int4 ss = s4[i]; int4 dd = d4[i];
        atomicAdd(&acc[dd.x & MSK], lv[ss.x & MSK]);
        atomicAdd(&acc[dd.y & MSK], lv[ss.y & MSK]);
        atomicAdd(&acc[dd.z & MSK], lv[ss.z & MSK]);
        atomicAdd(&acc[dd.w & MSK], lv[ss.w & MSK]);
    }
    __syncthreads();
    float4* op = (float4*)(scp + (size_t)bid * NPG);
    const float4* ap = (const float4*)acc;
    for (int i = tid; i < NPG / 4; i += 256) op[i] = ap[i];
}

// ===== K4: per-graph score finalize, radix top-512, nmap, readout1 =====
__global__ __launch_bounds__(1024) void k_select(
    const float* __restrict__ sci_g, const float* __restrict__ di_g,
    const float* __restrict__ scp, const float* __restrict__ u_g,
    const float* __restrict__ W1, const float* __restrict__ b1,
    float* __restrict__ ulist, float* __restrict__ tg1, float* __restrict__ x1b,
    int* __restrict__ nmap_g)
{
    __shared__ float lsc[NPG];
    __shared__ u32   lkey[NPG];
    __shared__ int   ln[NPG];
    __shared__ float ul[K1V], tgl[K1V];
    __shared__ int   sellist[K1V];
    __shared__ u32   hist[256], misc[2], wsum[16];
    __shared__ int   scnt;
    __shared__ float lw[HID], lbb[HID];
    const int b = blockIdx.x, tid = threadIdx.x;
    const int lane = tid & 63, wv = tid >> 6;

    for (int i = tid; i < NPG; i += 1024) {
        float a = 0.f;
        #pragma unroll
        for (int q = 0; q < NQ; q++) a += scp[(size_t)(b * NQ + q) * NPG + i];
        float sc = sci_g[(size_t)b * NPG + i] + di_g[(size_t)b * NPG + i] * a;
        lsc[i] = sc;
        lkey[i] = f2key(sc);
        ln[i] = -1;
    }
    if (tid < HID) { lw[tid] = W1[tid]; lbb[tid] = b1[tid]; }
    if (tid == 0) scnt = 0;
    __syncthreads();

    u32 tau; int R;
    radix_top<NPG, 1024>(lkey, K1V, hist, misc, tau, R);

    // stable tie rank (lowest index first)
    {
        int e0 = tid * 2, e1 = e0 + 1;
        u32 k0 = lkey[e0], k1 = lkey[e1];
        int q0 = (k0 == tau) ? 1 : 0, q1 = (k1 == tau) ? 1 : 0;
        u32 inc = wave_iscan((u32)(q0 + q1), lane);
        if (lane == 63) wsum[wv] = inc;
        __syncthreads();
        if (tid == 0) { u32 run = 0; for (int w2 = 0; w2 < 16; w2++) { u32 v = wsum[w2]; wsum[w2] = run; run += v; } }
        __syncthreads();
        u32 base = wsum[wv] + inc - (u32)(q0 + q1);
        bool sel0 = (k0 > tau) || (q0 && base < (u32)R);
        bool sel1 = (k1 > tau) || (q1 && (base + (u32)q0) < (u32)R);
        if (sel0) { int pos = atomicAdd(&scnt, 1); sellist[pos] = e0; }
        if (sel1) { int pos = atomicAdd(&scnt, 1); sellist[pos] = e1; }
        __syncthreads();
    }

    if (tid < K1V) {
        int node = sellist[tid];
        float uu = u_g[(size_t)b * NPG + node];
        float g = tanhf(lsc[node]);
        ul[tid] = uu; tgl[tid] = g;
        ulist[b * K1V + tid] = uu;
        tg1[b * K1V + tid] = g;
        ln[node] = tid;
    }
    __syncthreads();
    for (int i = tid; i < NPG; i += 1024) nmap_g[(size_t)b * NPG + i] = ln[i];

    // readout1: reuse lkey as two 1024-float partial arrays
    float* rp = (float*)lkey;
    {
        int grp = tid >> 7, c = tid & 127;
        float w = lw[c], bb = lbb[c];
        float mx = -INFINITY, sm = 0.f;
        for (int j = grp; j < K1V; j += 8) {
            float v = frelu(fmaf(w, ul[j], bb)) * tgl[j];
            mx = fmaxf(mx, v); sm += v;
        }
        __syncthreads();
        rp[tid] = mx; rp[1024 + tid] = sm;
        __syncthreads();
        if (tid < HID) {
            float m2 = -INFINITY, s2 = 0.f;
            #pragma unroll
            for (int g2 = 0; g2 < 8; g2++) {
                m2 = fmaxf(m2, rp[g2 * 128 + tid]);
                s2 += rp[1024 + g2 * 128 + tid];
            }
            x1b[b * 256 + tid] = m2;
            x1b[b * 256 + HID + tid] = s2 / (float)K1V;
        }
    }
}

// ===== K5: per-segment edge compaction =====
__global__ __launch_bounds__(256) void k_compact8(const int* __restrict__ esrc,
                                                  const int* __restrict__ edst,
                                                  const int* __restrict__ nmap_g,
                                                  int* __restrict__ epair,
                                                  int* __restrict__ eqcnt,
                                                  int* __restrict__ ldegp) {
    __shared__ int lnm[NPG];
    __shared__ int pbuf[QCAP];
    __shared__ int lda[K1V];
    __shared__ int lcnt;
    const int bid = blockIdx.x, tid = threadIdx.x;
    const int g = bid >> 3, q = bid & 7;
    for (int i = tid; i < NPG; i += 256) lnm[i] = nmap_g[(size_t)g * NPG + i];
    for (int i = tid; i < K1V; i += 256) lda[i] = 0;
    if (tid == 0) lcnt = 0;
    __syncthreads();
    const int4* s4 = (const int4*)(esrc + g * EPG + q * ESEG);
    const int4* d4 = (const int4*)(edst + g * EPG + q * ESEG);
    for (int i = tid; i < ESEG / 4; i += 256) {
        int4 ss = s4[i]; int4 dd = d4[i];
        int sa[4] = { ss.x & MSK, ss.y & MSK, ss.z & MSK, ss.w & MSK };
        int da[4] = { dd.x & MSK, dd.y & MSK, dd.z & MSK, dd.w & MSK };
        #pragma unroll
        for (int r = 0; r < 4; r++) {
            int s2 = lnm[sa[r]], d2 = lnm[da[r]];
            if (s2 >= 0 && d2 >= 0) {
                int p = atomicAdd(&lcnt, 1);
                if (p < QCAP) { pbuf[p] = s2 | (d2 << 16); atomicAdd(&lda[d2], 1); }
            }
        }
    }
    __syncthreads();
    int cnt = lcnt < QCAP ? lcnt : QCAP;
    if (tid == 0) eqcnt[bid] = cnt;
    for (int i = tid; i < cnt; i += 256) epair[(size_t)bid * QCAP + i] = pbuf[i];
    for (int i = tid; i < K1V; i += 256) ldegp[(size_t)bid * K1V + i] = lda[i];
}

// ===== K6: csr (blocks 0..63) || matmul (blocks 64..575) =====
__global__ __launch_bounds__(256) void k_csrmm(
    const int* __restrict__ ldegp, const int* __restrict__ eqcnt,
    const int* __restrict__ epair,
    int* __restrict__ srcs2, int* __restrict__ rs2, int* __restrict__ ic2,
    float* __restrict__ dfull2, float* __restrict__ dinv2,
    const float* __restrict__ ulist, const float* __restrict__ tg1,
    const float* __restrict__ W1, const float* __restrict__ b1,
    const float* __restrict__ W2, float* __restrict__ hw)
{
    __shared__ union {
        struct { int cur[K1V]; u32 wsum[4]; } csr;
        struct { float lhT[HID * 64]; float lu[64], lg[64]; } mm;
    } sm;
    const int bid = blockIdx.x, tid = threadIdx.x;
    const int lane = tid & 63, wv = tid >> 6;

    if (bid < NB) {
        const int b = bid;
        int e0 = tid * 2, e1 = e0 + 1;
        int dv0 = 0, dv1 = 0;
        #pragma unroll
        for (int q = 0; q < NQ; q++) {
            dv0 += ldegp[(size_t)(b * NQ + q) * K1V + e0];
            dv1 += ldegp[(size_t)(b * NQ + q) * K1V + e1];
        }
        int pr = dv0 + dv1;
        u32 inc = wave_iscan((u32)pr, lane);
        if (lane == 63) sm.csr.wsum[wv] = inc;
        __syncthreads();
        if (tid == 0) { u32 run = 0; for (int w2 = 0; w2 < 4; w2++) { u32 v = sm.csr.wsum[w2]; sm.csr.wsum[w2] = run; run += v; } }
        __syncthreads();
        int exclp = (int)(sm.csr.wsum[wv] + inc - (u32)pr);
        {
            int n0 = b * K1V + e0;
            rs2[n0] = b * SCAP + exclp; ic2[n0] = dv0;
            float df0 = (float)dv0 + 1.0f;
            dfull2[n0] = df0; dinv2[n0] = rsqrtf(df0);
            sm.csr.cur[e0] = exclp;
            int excl1 = exclp + dv0;
            int n1 = b * K1V + e1;
            rs2[n1] = b * SCAP + excl1; ic2[n1] = dv1;
            float df1 = (float)dv1 + 1.0f;
            dfull2[n1] = df1; dinv2[n1] = rsqrtf(df1);
            sm.csr.cur[e1] = excl1;
        }
        __syncthreads();
        for (int q = 0; q < NQ; q++) {
            int cnt = eqcnt[b * NQ + q];
            for (int i = tid; i < cnt; i += 256) {
                int pk = epair[(size_t)(b * NQ + q) * QCAP + i];
                int s2 = pk & 0xffff, d2 = pk >> 16;
                int pos = atomicAdd(&sm.csr.cur[d2], 1);
                srcs2[(size_t)b * SCAP + pos] = b * K1V + s2;
            }
        }
    } else {
        const int row0 = (bid - NB) * 64;
        if (tid < 64) { sm.mm.lu[tid] = ulist[row0 + tid]; sm.mm.lg[tid] = tg1[row0 + tid]; }
        __syncthreads();
        for (int idx = tid; idx < HID * 64; idx += 256) {
            int k = idx >> 6, j = idx & 63;
            sm.mm.lhT[idx] = frelu(fmaf(W1[k], sm.mm.lu[j], b1[k])) * sm.mm.lg[j];
        }
        __syncthreads();
        const int cg2 = tid & 31, rg2 = tid >> 5;
        float acc[8][4];
        #pragma unroll
        for (int r = 0; r < 8; r++)
            #pragma unroll
            for (int c = 0; c < 4; c++) acc[r][c] = 0.f;
        const float4* lhT4 = (const float4*)sm.mm.lhT;
        #pragma unroll 4
        for (int k = 0; k < HID; k++) {
            float4 h0 = lhT4[k * 16 + rg2 * 2];
            float4 h1 = lhT4[k * 16 + rg2 * 2 + 1];
            float4 ww = *(const float4*)&W2[(size_t)k * HID + cg2 * 4];
            float hr[8] = { h0.x, h0.y, h0.z, h0.w, h1.x, h1.y, h1.z, h1.w };
            float wc[4] = { ww.x, ww.y, ww.z, ww.w };
            #pragma unroll
            for (int r = 0; r < 8; r++)
                #pragma unroll
                for (int c = 0; c < 4; c++)
                    acc[r][c] = fmaf(hr[r], wc[c], acc[r][c]);
        }
        #pragma unroll
        for (int r = 0; r < 8; r++) {
            float4 o; o.x = acc[r][0]; o.y = acc[r][1]; o.z = acc[r][2]; o.w = acc[r][3];
            *(float4*)&hw[(size_t)(row0 + rg2 * 8 + r) * HID + cg2 * 4] = o;
        }
    }
}

// ===== K7: stage-2 GCN via CSR pull, fused bias/relu/score =====
__global__ __launch_bounds__(256) void k_pull2(
    const int* __restrict__ srcs2, const int* __restrict__ rs2, const int* __restrict__ ic2,
    const float* __restrict__ dfull2, const float* __restrict__ dinv2,
    const float* __restrict__ hw, const float* __restrict__ b2,
    const float* __restrict__ sW2, const float* __restrict__ sb2,
    float* __restrict__ h2, float* __restrict__ ds02, float* __restrict__ sc2i)
{
    int node = blockIdx.x * 4 + (threadIdx.x >> 6);
    int lane = threadIdx.x & 63;
    int rs = rs2[node], cnt = ic2[node];
    float a0 = 0.f, a1 = 0.f;
    for (int j = 0; j < cnt; j++) {
        int s = srcs2[rs + j];
        float w = dinv2[s];
        a0 = fmaf(w, hw[(size_t)s * HID + lane], a0);
        a1 = fmaf(w, hw[(size_t)s * HID + 64 + lane], a1);
    }
    float df = dfull2[node], di = dinv2[node];
    float h0 = frelu(a0 * di + hw[(size_t)node * HID + lane] / df + b2[lane]);
    float h1 = frelu(a1 * di + hw[(size_t)node * HID + 64 + lane] / df + b2[lane + 64]);
    h2[(size_t)node * HID + lane] = h0;
    h2[(size_t)node * HID + 64 + lane] = h1;
    float dot = h0 * sW2[lane] + h1 * sW2[lane + 64];
    #pragma unroll
    for (int o = 32; o > 0; o >>= 1) dot += __shfl_down(dot, o);
    if (lane == 0) {
        ds02[node] = di * dot;
        sc2i[node] = dot / df + sb2[0];
    }
}

// ===== K8: topk2 + readout2 + head (1024 threads, latency-parallelized) =====
__global__ __launch_bounds__(1024) void k_tkhead(
    const int* __restrict__ srcs2, const int* __restrict__ rs2, const int* __restrict__ ic2,
    const float* __restrict__ dinv2, const float* __restrict__ ds02,
    const float* __restrict__ sc2i, const float* __restrict__ h2,
    const float* __restrict__ x1b, const float* __restrict__ gi,
    const float* __restrict__ l1W, const float* __restrict__ l1b,
    const float* __restrict__ l2W, const float* __restrict__ l2b,
    const float* __restrict__ l3W, const float* __restrict__ l3b,
    float* __restrict__ out)
{
    __shared__ float sv[K1V];
    __shared__ u32   skey[K1V];
    __shared__ u32   hist[256], misc[2], wsum[16];
    __shared__ int   plist[K2V];
    __shared__ float tl[K2V];
    __shared__ float rp[1024], rp2[1024];
    __shared__ float z[272];
    __shared__ float zp[8][128];
    __shared__ float z1[HID], z2[64], z3[32], red[2];
    __shared__ int   scnt;
    const int b = blockIdx.x, tid = threadIdx.x;
    const int lane = tid & 63, wv = tid >> 6;
    if (tid == 0) scnt = 0;

    // score finalize (one node per thread, tid<512)
    if (tid < K1V) {
        int n = b * K1V + tid;
        int rsv = rs2[n], cnt = ic2[n];
        float acc = 0.f;
        for (int j = 0; j < cnt; j++) acc += ds02[srcs2[rsv + j]];
        float sc = sc2i[n] + dinv2[n] * acc;
        sv[tid] = sc; skey[tid] = f2key(sc);
    }
    __syncthreads();
    u32 tau; int R;
    radix_top<K1V, 1024>(skey, K2V, hist, misc, tau, R);

    // tie rank: one element per thread
    {
        u32 k0 = skey[tid < K1V ? tid : 0];
        int q0 = (tid < K1V && k0 == tau) ? 1 : 0;
        u32 inc = wave_iscan((u32)q0, lane);
        if (lane == 63) wsum[wv] = inc;
        __syncthreads();
        if (tid == 0) { u32 run = 0; for (int w2 = 0; w2 < 16; w2++) { u32 v = wsum[w2]; wsum[w2] = run; run += v; } }
        __syncthreads();
        u32 base = wsum[wv] + inc - (u32)q0;
        bool sel = (tid < K1V) && ((k0 > tau) || (q0 && base < (u32)R));
        if (sel) { int pos = atomicAdd(&scnt, 1); plist[pos] = b * K1V + tid; tl[pos] = tanhf(sv[tid]); }
        __syncthreads();
    }

    // readout2: 8 groups x 128 channels (8 gathers in flight per channel)
    {
        int grp = tid >> 7, c = tid & 127;
        float mx = -INFINITY, smv = 0.f;
        for (int j = grp; j < K2V; j += 8) {
            float v = h2[(size_t)plist[j] * HID + c] * tl[j];
            mx = fmaxf(mx, v); smv += v;
        }
        rp[tid] = mx; rp2[tid] = smv;
        __syncthreads();
        if (tid < 256) {
            int c2 = tid & 127, half = tid >> 7;
            if (half == 0) {
                float m = rp[c2];
                #pragma unroll
                for (int g2 = 1; g2 < 8; g2++) m = fmaxf(m, rp[g2 * 128 + c2]);
                z[c2] = x1b[b * 256 + c2] + m;
            } else {
                float s = rp2[c2];
                #pragma unroll
                for (int g2 = 1; g2 < 8; g2++) s += rp2[g2 * 128 + c2];
                z[128 + c2] = x1b[b * 256 + 128 + c2] + s / (float)K2V;
            }
        }
        if (tid < 10) z[256 + tid] = gi[b * 10 + tid];
        __syncthreads();
    }

    // head layer 1: 8 k-groups x 128 outputs, LDS reduce (k-chain 266 -> 34)
    {
        int grp = tid >> 7, c = tid & 127;
        int k0 = grp * 34;
        int k1 = k0 + 34; if (k1 > 266) k1 = 266;
        float acc = 0.f;
        for (int k = k0; k < k1; k++) acc = fmaf(z[k], l1W[k * 128 + c], acc);
        zp[grp][c] = acc;
        __syncthreads();
        if (tid < 128) {
            float s = l1b[tid];
            #pragma unroll
            for (int g2 = 0; g2 < 8; g2++) s += zp[g2][tid];
            z1[tid] = frelu(s);
        }
        __syncthreads();
    }

    // head layer 2: 8 k-groups x 64 outputs (tid<512), LDS reduce
    {
        if (tid < 512) {
            int grp = tid >> 6, c = tid & 63;
            int k0 = grp * 16;
            float acc = 0.f;
            #pragma unroll
            for (int k = k0; k < k0 + 16; k++) acc = fmaf(z1[k], l2W[k * 64 + c], acc);
            zp[grp][c] = acc;
        }
        __syncthreads();
        if (tid < 64) {
            float s = l2b[tid];
            #pragma unroll
            for (int g2 = 0; g2 < 8; g2++) s += zp[g2][tid];
            z2[tid] = frelu(s);
        }
        __syncthreads();
    }

    // head layer 3 + log_softmax
    if (tid < 32) {
        float a3 = l3b[tid];
        for (int k = 0; k < 64; k++) a3 = fmaf(z2[k], l3W[k * 32 + tid], a3);
        z3[tid] = a3;
    }
    __syncthreads();
    if (tid == 0) {
        float m = -INFINITY;
        for (int c2 = 0; c2 < 32; c2++) m = fmaxf(m, z3[c2]);
        float s = 0.f;
        for (int c2 = 0; c2 < 32; c2++) s += expf(z3[c2] - m);
        red[0] = m; red[1] = logf(s);
    }
    __syncthreads();
    if (tid < 32) out[b * 32 + tid] = z3[tid] - red[0] - red[1];
}

// ============ launch ============
extern "C" void kernel_launch(void* const* d_in, const int* in_sizes, int n_in,
                              void* d_out, int out_size, void* d_ws, size_t ws_size,
                              hipStream_t stream) {
    const float* x    = (const float*)d_in[0];
    const int*   esrc = (const int*)d_in[1];
    const int*   edst = (const int*)d_in[2];
    const float* gi   = (const float*)d_in[3];
    const float* W1   = (const float*)d_in[4];
    const float* b1   = (const float*)d_in[5];
    const float* sW1  = (const float*)d_in[6];
    const float* sb1  = (const float*)d_in[7];
    const float* W2   = (const float*)d_in[8];
    const float* b2   = (const float*)d_in[9];
    const float* sW2  = (const float*)d_in[10];
    const float* sb2  = (const float*)d_in[11];
    const float* l1W  = (const float*)d_in[12];
    const float* l1b  = (const float*)d_in[13];
    const float* l2W  = (const float*)d_in[14];
    const float* l2b  = (const float*)d_in[15];
    const float* l3W  = (const float*)d_in[16];
    const float* l3b  = (const float*)d_in[17];
    float* out = (float*)d_out;

    char* p = (char*)d_ws;
    auto alloc = [&](size_t bytes) {
        char* r = p;
        p += (bytes + 255) & ~size_t(255);
        return (void*)r;
    };
    int*   degp   = (int*)alloc((size_t)NB * NQ * NPG * 4);
    float* df_g   = (float*)alloc((size_t)NB * NPG * 4);
    float* di_g   = (float*)alloc((size_t)NB * NPG * 4);
    float* tp     = (float*)alloc((size_t)NB * NQ * NPG * 4);
    float* u_g    = (float*)alloc((size_t)NB * NPG * 4);
    float* sci_g  = (float*)alloc((size_t)NB * NPG * 4);
    float* scp    = (float*)alloc((size_t)NB * NQ * NPG * 4);
    int*   nmap_g = (int*)alloc((size_t)NB * NPG * 4);
    float* ulist  = (float*)alloc((size_t)N1 * 4);
    float* tg1    = (float*)alloc((size_t)N1 * 4);
    float* x1b    = (float*)alloc((size_t)NB * 256 * 4);
    int*   epair  = (int*)alloc((size_t)NB * NQ * QCAP * 4);
    int*   eqcnt  = (int*)alloc((size_t)NB * NQ * 4);
    int*   ldegp  = (int*)alloc((size_t)NB * NQ * K1V * 4);
    int*   srcs2  = (int*)alloc((size_t)NB * SCAP * 4);
    int*   rs2    = (int*)alloc((size_t)N1 * 4);
    int*   ic2    = (int*)alloc((size_t)N1 * 4);
    float* dfull2 = (float*)alloc((size_t)N1 * 4);
    float* dinv2  = (float*)alloc((size_t)N1 * 4);
    float* hw     = (float*)alloc((size_t)N1 * HID * 4);
    float* h2     = (float*)alloc((size_t)N1 * HID * 4);
    float* ds02   = (float*)alloc((size_t)N1 * 4);
    float* sc2i   = (float*)alloc((size_t)N1 * 4);

    k_deg8<<<NB * NQ, 256, 0, stream>>>(edst, degp);
    k_sweepA<<<NB * NQ, 256, 0, stream>>>(x, esrc, edst, degp, df_g, di_g, tp);
    k_sweepB<<<NB * NQ, 256, 0, stream>>>(x, esrc, edst, tp, df_g, di_g,
                                          W1, b1, sW1, sb1, u_g, sci_g, scp);
    k_select<<<NB, 1024, 0, stream>>>(sci_g, di_g, scp, u_g, W1, b1,
                                      ulist, tg1, x1b, nmap_g);
    k_compact8<<<NB * NQ, 256, 0, stream>>>(esrc, edst, nmap_g, epair, eqcnt, ldegp);
    k_csrmm<<<NB + N1 / 64, 256, 0, stream>>>(ldegp, eqcnt, epair, srcs2, rs2, ic2,
                                              dfull2, dinv2, ulist, tg1, W1, b1, W2, hw);
    k_pull2<<<N1 / 4, 256, 0, stream>>>(srcs2, rs2, ic2, dfull2, dinv2, hw,
                                        b2, sW2, sb2, h2, ds02, sc2i);
    k_tkhead<<<NB, 1024, 0, stream>>>(srcs2, rs2, ic2, dinv2, ds02, sc2i, h2,
                                      x1b, gi, l1W, l1b, l2W, l2b, l3W, l3b, out);
}

// Round 10
// 131.945 us; speedup vs baseline: 5.2397x; 1.0113x over previous
//
#include <hip/hip_runtime.h>
#include <math.h>

#define NB    64
#define NPG   2048      // nodes per graph
#define EPG   16384     // edges per graph
#define HID   128
#define K1V   512
#define K2V   128
#define N1    32768     // NB*K1V
#define SCAP  2048      // per-graph surviving-edge capacity
#define MSK   (NPG - 1)
#define NQ    4         // edge segments per graph
#define ESEG  (EPG / NQ)   // 4096
#define QCAP  512       // per-segment survivor capacity (E~256, sigma~16)

typedef unsigned int u32;

static __device__ __forceinline__ float frelu(float v) { return v > 0.f ? v : 0.f; }

static __device__ __forceinline__ u32 f2key(float f) {
    u32 u = __float_as_uint(f);
    return u ^ ((u >> 31) ? 0xFFFFFFFFu : 0x80000000u);
}

static __device__ __forceinline__ u32 wave_iscan(u32 v, int lane) {
    #pragma unroll
    for (int off = 1; off < 64; off <<= 1) {
        u32 t = __shfl_up(v, off);
        if (lane >= off) v += t;
    }
    return v;
}

// Radix-select the K-th largest key among N LDS keys (T threads).
template <int N, int T>
static __device__ __forceinline__ void radix_top(const u32* __restrict__ key, int K,
                                                 u32* hist, u32* misc,
                                                 u32& tau, int& R) {
    const int tid = threadIdx.x;
    if (tid == 0) { misc[0] = 0u; misc[1] = (u32)K; }
    __syncthreads();
    #pragma unroll
    for (int p = 0; p < 4; p++) {
        const int shift = 24 - 8 * p;
        for (int i = tid; i < 256; i += T) hist[i] = 0u;
        __syncthreads();
        const u32 prefix = misc[0];
        const u32 need   = misc[1];
        for (int i = tid; i < N; i += T) {
            u32 k = key[i];
            bool ok = (p == 0) || ((k >> (shift + 8)) == prefix);
            if (ok) atomicAdd(&hist[(k >> shift) & 255u], 1u);
        }
        __syncthreads();
        if (tid < 64) {
            const int lane = tid;
            u32 c0 = hist[4 * lane + 0], c1 = hist[4 * lane + 1];
            u32 c2 = hist[4 * lane + 2], c3 = hist[4 * lane + 3];
            u32 local = c0 + c1 + c2 + c3;
            u32 inc = local;
            #pragma unroll
            for (int off = 1; off < 64; off <<= 1) {
                u32 v = __shfl_down(inc, off);
                if (lane + off < 64) inc += v;
            }
            u32 excl = inc - local;
            u32 ge3 = excl + c3, ge2 = ge3 + c2, ge1 = ge2 + c1, ge0 = ge1 + c0;
            int selb = -1; u32 gt = 0;
            if      (ge3 >= need && excl < need) { selb = 4 * lane + 3; gt = excl; }
            else if (ge2 >= need && ge3  < need) { selb = 4 * lane + 2; gt = ge3; }
            else if (ge1 >= need && ge2  < need) { selb = 4 * lane + 1; gt = ge2; }
            else if (ge0 >= need && ge1  < need) { selb = 4 * lane + 0; gt = ge1; }
            if (selb >= 0) { misc[0] = (prefix << 8) | (u32)selb; misc[1] = need - gt; }
        }
        __syncthreads();
    }
    tau = misc[0];
    R = (int)misc[1];
}

// ===== K1: per-segment degree histogram =====
__global__ __launch_bounds__(256) void k_deg8(const int* __restrict__ edst,
                                              int* __restrict__ degp) {
    __shared__ int cnt[NPG];
    const int bid = blockIdx.x, tid = threadIdx.x;
    const int g = bid >> 2, q = bid & 3;
    for (int i = tid; i < NPG; i += 256) cnt[i] = 0;
    __syncthreads();
    const int4* d4 = (const int4*)(edst + g * EPG + q * ESEG);
    for (int i = tid; i < ESEG / 4; i += 256) {
        int4 dd = d4[i];
        atomicAdd(&cnt[dd.x & MSK], 1); atomicAdd(&cnt[dd.y & MSK], 1);
        atomicAdd(&cnt[dd.z & MSK], 1); atomicAdd(&cnt[dd.w & MSK], 1);
    }
    __syncthreads();
    int4* op = (int4*)(degp + (size_t)bid * NPG);
    const int4* cp4 = (const int4*)cnt;
    for (int i = tid; i < NPG / 4; i += 256) op[i] = cp4[i];
}

// ===== K2: fused nodeA + t-sweep =====
__global__ __launch_bounds__(256) void k_sweepA(const float* __restrict__ x,
                                                const int* __restrict__ esrc,
                                                const int* __restrict__ edst,
                                                const int* __restrict__ degp,
                                                float* __restrict__ df_g,
                                                float* __restrict__ di_g,
                                                float* __restrict__ tp) {
    __shared__ float lv[NPG];
    __shared__ float acc[NPG];
    const int bid = blockIdx.x, tid = threadIdx.x;
    const int g = bid >> 2, q = bid & 3;
    for (int i = tid; i < NPG; i += 256) {
        int dg = 0;
        #pragma unroll
        for (int q2 = 0; q2 < NQ; q2++) dg += degp[(size_t)(g * NQ + q2) * NPG + i];
        float df = (float)dg + 1.0f;
        float di = rsqrtf(df);
        lv[i] = di * x[(size_t)g * NPG + i];
        acc[i] = 0.f;
        if (q == 0) { df_g[(size_t)g * NPG + i] = df; di_g[(size_t)g * NPG + i] = di; }
    }
    __syncthreads();
    const int4* s4 = (const int4*)(esrc + g * EPG + q * ESEG);
    const int4* d4 = (const int4*)(edst + g * EPG + q * ESEG);
    for (int i = tid; i < ESEG / 4; i += 256) {
        int4 ss = s4[i]; int4 dd = d4[i];
        atomicAdd(&acc[dd.x & MSK], lv[ss.x & MSK]);
        atomicAdd(&acc[dd.y & MSK], lv[ss.y & MSK]);
        atomicAdd(&acc[dd.z & MSK], lv[ss.z & MSK]);
        atomicAdd(&acc[dd.w & MSK], lv[ss.w & MSK]);
    }
    __syncthreads();
    float4* op = (float4*)(tp + (size_t)bid * NPG);
    const float4* ap = (const float4*)acc;
    for (int i = tid; i < NPG / 4; i += 256) op[i] = ap[i];
}

// ===== K3: fused nodeB + score-sweep =====
__global__ __launch_bounds__(256) void k_sweepB(const float* __restrict__ x,
                                                const int* __restrict__ esrc,
                                                const int* __restrict__ edst,
                                                const float* __restrict__ tp,
                                                const float* __restrict__ df_g,
                                                const float* __restrict__ di_g,
                                                const float* __restrict__ W1,
                                                const float* __restrict__ b1,
                                                const float* __restrict__ sW1,
                                                const float* __restrict__ sb1,
                                                float* __restrict__ u_g,
                                                float* __restrict__ sci_g,
                                                float* __restrict__ scp) {
    __shared__ float lv[NPG];
    __shared__ float acc[NPG];
    __shared__ float lw[HID], lbb[HID], lsw[HID];
    const int bid = blockIdx.x, tid = threadIdx.x;
    const int g = bid >> 2, q = bid & 3;
    if (tid < HID) { lw[tid] = W1[tid]; lbb[tid] = b1[tid]; lsw[tid] = sW1[tid]; }
    __syncthreads();
    const float sb1v = sb1[0];
    for (int i = tid; i < NPG; i += 256) {
        float t = 0.f;
        #pragma unroll
        for (int q2 = 0; q2 < NQ; q2++) t += tp[(size_t)(g * NQ + q2) * NPG + i];
        float df = df_g[(size_t)g * NPG + i];
        float di = di_g[(size_t)g * NPG + i];
        float u = t * di + x[(size_t)g * NPG + i] / df;
        float s = 0.f;
        #pragma unroll 8
        for (int c = 0; c < HID; c++) s += frelu(fmaf(lw[c], u, lbb[c])) * lsw[c];
        lv[i] = di * s;
        acc[i] = 0.f;
        if (q == 0) {
            u_g[(size_t)g * NPG + i] = u;
            sci_g[(size_t)g * NPG + i] = s / df + sb1v;
        }
    }
    __syncthreads();
    const int4* s4 = (const int4*)(esrc + g * EPG + q * ESEG);
    const int4* d4 = (const int4*)(edst + g * EPG + q * ESEG);
    for (int i = tid; i < ESEG / 4; i += 256) {
        int4 ss = s4[i]; int4 dd = d4[i];
        atomicAdd(&acc[dd.x & MSK], lv[ss.x & MSK]);
        atomicAdd(&acc[dd.y & MSK], lv[ss.y & MSK]);
        atomicAdd(&acc[dd.z & MSK], lv[ss.z & MSK]);
        atomicAdd(&acc[dd.w & MSK], lv[ss.w & MSK]);
    }
    __syncthreads();
    float4* op = (float4*)(scp + (size_t)bid * NPG);
    const float4* ap = (const float4*)acc;
    for (int i = tid; i < NPG / 4; i += 256) op[i] = ap[i];
}

// ===== K4: per-graph score finalize, radix top-512, nmap, readout1 =====
__global__ __launch_bounds__(1024) void k_select(
    const float* __restrict__ sci_g, const float* __restrict__ di_g,
    const float* __restrict__ scp, const float* __restrict__ u_g,
    const float* __restrict__ W1, const float* __restrict__ b1,
    float* __restrict__ ulist, float* __restrict__ tg1, float* __restrict__ x1b,
    int* __restrict__ nmap_g)
{
    __shared__ float lsc[NPG];
    __shared__ u32   lkey[NPG];
    __shared__ int   ln[NPG];
    __shared__ float ul[K1V], tgl[K1V];
    __shared__ int   sellist[K1V];
    __shared__ u32   hist[256], misc[2], wsum[16];
    __shared__ int   scnt;
    __shared__ float lw[HID], lbb[HID];
    const int b = blockIdx.x, tid = threadIdx.x;
    const int lane = tid & 63, wv = tid >> 6;

    for (int i = tid; i < NPG; i += 1024) {
        float a = 0.f;
        #pragma unroll
        for (int q = 0; q < NQ; q++) a += scp[(size_t)(b * NQ + q) * NPG + i];
        float sc = sci_g[(size_t)b * NPG + i] + di_g[(size_t)b * NPG + i] * a;
        lsc[i] = sc;
        lkey[i] = f2key(sc);
        ln[i] = -1;
    }
    if (tid < HID) { lw[tid] = W1[tid]; lbb[tid] = b1[tid]; }
    if (tid == 0) scnt = 0;
    __syncthreads();

    u32 tau; int R;
    radix_top<NPG, 1024>(lkey, K1V, hist, misc, tau, R);

    // stable tie rank (lowest index first)
    {
        int e0 = tid * 2, e1 = e0 + 1;
        u32 k0 = lkey[e0], k1 = lkey[e1];
        int q0 = (k0 == tau) ? 1 : 0, q1 = (k1 == tau) ? 1 : 0;
        u32 inc = wave_iscan((u32)(q0 + q1), lane);
        if (lane == 63) wsum[wv] = inc;
        __syncthreads();
        if (tid == 0) { u32 run = 0; for (int w2 = 0; w2 < 16; w2++) { u32 v = wsum[w2]; wsum[w2] = run; run += v; } }
        __syncthreads();
        u32 base = wsum[wv] + inc - (u32)(q0 + q1);
        bool sel0 = (k0 > tau) || (q0 && base < (u32)R);
        bool sel1 = (k1 > tau) || (q1 && (base + (u32)q0) < (u32)R);
        if (sel0) { int pos = atomicAdd(&scnt, 1); sellist[pos] = e0; }
        if (sel1) { int pos = atomicAdd(&scnt, 1); sellist[pos] = e1; }
        __syncthreads();
    }

    if (tid < K1V) {
        int node = sellist[tid];
        float uu = u_g[(size_t)b * NPG + node];
        float g = tanhf(lsc[node]);
        ul[tid] = uu; tgl[tid] = g;
        ulist[b * K1V + tid] = uu;
        tg1[b * K1V + tid] = g;
        ln[node] = tid;
    }
    __syncthreads();
    for (int i = tid; i < NPG; i += 1024) nmap_g[(size_t)b * NPG + i] = ln[i];

    // readout1: reuse lkey as two 1024-float partial arrays
    float* rp = (float*)lkey;
    {
        int grp = tid >> 7, c = tid & 127;
        float w = lw[c], bb = lbb[c];
        float mx = -INFINITY, sm = 0.f;
        for (int j = grp; j < K1V; j += 8) {
            float v = frelu(fmaf(w, ul[j], bb)) * tgl[j];
            mx = fmaxf(mx, v); sm += v;
        }
        __syncthreads();
        rp[tid] = mx; rp[1024 + tid] = sm;
        __syncthreads();
        if (tid < HID) {
            float m2 = -INFINITY, s2 = 0.f;
            #pragma unroll
            for (int g2 = 0; g2 < 8; g2++) {
                m2 = fmaxf(m2, rp[g2 * 128 + tid]);
                s2 += rp[1024 + g2 * 128 + tid];
            }
            x1b[b * 256 + tid] = m2;
            x1b[b * 256 + HID + tid] = s2 / (float)K1V;
        }
    }
}

// ===== K5: per-segment edge compaction =====
__global__ __launch_bounds__(256) void k_compact8(const int* __restrict__ esrc,
                                                  const int* __restrict__ edst,
                                                  const int* __restrict__ nmap_g,
                                                  int* __restrict__ epair,
                                                  int* __restrict__ eqcnt,
                                                  int* __restrict__ ldegp) {
    __shared__ int lnm[NPG];
    __shared__ int pbuf[QCAP];
    __shared__ int lda[K1V];
    __shared__ int lcnt;
    const int bid = blockIdx.x, tid = threadIdx.x;
    const int g = bid >> 2, q = bid & 3;
    for (int i = tid; i < NPG; i += 256) lnm[i] = nmap_g[(size_t)g * NPG + i];
    for (int i = tid; i < K1V; i += 256) lda[i] = 0;
    if (tid == 0) lcnt = 0;
    __syncthreads();
    const int4* s4 = (const int4*)(esrc + g * EPG + q * ESEG);
    const int4* d4 = (const int4*)(edst + g * EPG + q * ESEG);
    for (int i = tid; i < ESEG / 4; i += 256) {
        int4 ss = s4[i]; int4 dd = d4[i];
        int sa[4] = { ss.x & MSK, ss.y & MSK, ss.z & MSK, ss.w & MSK };
        int da[4] = { dd.x & MSK, dd.y & MSK, dd.z & MSK, dd.w & MSK };
        #pragma unroll
        for (int r = 0; r < 4; r++) {
            int s2 = lnm[sa[r]], d2 = lnm[da[r]];
            if (s2 >= 0 && d2 >= 0) {
                int p = atomicAdd(&lcnt, 1);
                if (p < QCAP) { pbuf[p] = s2 | (d2 << 16); atomicAdd(&lda[d2], 1); }
            }
        }
    }
    __syncthreads();
    int cnt = lcnt < QCAP ? lcnt : QCAP;
    if (tid == 0) eqcnt[bid] = cnt;
    for (int i = tid; i < cnt; i += 256) epair[(size_t)bid * QCAP + i] = pbuf[i];
    for (int i = tid; i < K1V; i += 256) ldegp[(size_t)bid * K1V + i] = lda[i];
}

// ===== K6: csr (blocks 0..63) || matmul (blocks 64..575) =====
__global__ __launch_bounds__(256) void k_csrmm(
    const int* __restrict__ ldegp, const int* __restrict__ eqcnt,
    const int* __restrict__ epair,
    int* __restrict__ srcs2, int* __restrict__ rs2, int* __restrict__ ic2,
    float* __restrict__ dfull2, float* __restrict__ dinv2,
    const float* __restrict__ ulist, const float* __restrict__ tg1,
    const float* __restrict__ W1, const float* __restrict__ b1,
    const float* __restrict__ W2, float* __restrict__ hw)
{
    __shared__ union {
        struct { int cur[K1V]; u32 wsum[4]; } csr;
        struct { float lhT[HID * 64]; float lu[64], lg[64]; } mm;
    } sm;
    const int bid = blockIdx.x, tid = threadIdx.x;
    const int lane = tid & 63, wv = tid >> 6;

    if (bid < NB) {
        const int b = bid;
        int e0 = tid * 2, e1 = e0 + 1;
        int dv0 = 0, dv1 = 0;
        #pragma unroll
        for (int q = 0; q < NQ; q++) {
            dv0 += ldegp[(size_t)(b * NQ + q) * K1V + e0];
            dv1 += ldegp[(size_t)(b * NQ + q) * K1V + e1];
        }
        int pr = dv0 + dv1;
        u32 inc = wave_iscan((u32)pr, lane);
        if (lane == 63) sm.csr.wsum[wv] = inc;
        __syncthreads();
        if (tid == 0) { u32 run = 0; for (int w2 = 0; w2 < 4; w2++) { u32 v = sm.csr.wsum[w2]; sm.csr.wsum[w2] = run; run += v; } }
        __syncthreads();
        int exclp = (int)(sm.csr.wsum[wv] + inc - (u32)pr);
        {
            int n0 = b * K1V + e0;
            rs2[n0] = b * SCAP + exclp; ic2[n0] = dv0;
            float df0 = (float)dv0 + 1.0f;
            dfull2[n0] = df0; dinv2[n0] = rsqrtf(df0);
            sm.csr.cur[e0] = exclp;
            int excl1 = exclp + dv0;
            int n1 = b * K1V + e1;
            rs2[n1] = b * SCAP + excl1; ic2[n1] = dv1;
            float df1 = (float)dv1 + 1.0f;
            dfull2[n1] = df1; dinv2[n1] = rsqrtf(df1);
            sm.csr.cur[e1] = excl1;
        }
        __syncthreads();
        for (int q = 0; q < NQ; q++) {
            int cnt = eqcnt[b * NQ + q];
            for (int i = tid; i < cnt; i += 256) {
                int pk = epair[(size_t)(b * NQ + q) * QCAP + i];
                int s2 = pk & 0xffff, d2 = pk >> 16;
                int pos = atomicAdd(&sm.csr.cur[d2], 1);
                srcs2[(size_t)b * SCAP + pos] = b * K1V + s2;
            }
        }
    } else {
        const int row0 = (bid - NB) * 64;
        if (tid < 64) { sm.mm.lu[tid] = ulist[row0 + tid]; sm.mm.lg[tid] = tg1[row0 + tid]; }
        __syncthreads();
        for (int idx = tid; idx < HID * 64; idx += 256) {
            int k = idx >> 6, j = idx & 63;
            sm.mm.lhT[idx] = frelu(fmaf(W1[k], sm.mm.lu[j], b1[k])) * sm.mm.lg[j];
        }
        __syncthreads();
        const int cg2 = tid & 31, rg2 = tid >> 5;
        float acc[8][4];
        #pragma unroll
        for (int r = 0; r < 8; r++)
            #pragma unroll
            for (int c = 0; c < 4; c++) acc[r][c] = 0.f;
        const float4* lhT4 = (const float4*)sm.mm.lhT;
        #pragma unroll 4
        for (int k = 0; k < HID; k++) {
            float4 h0 = lhT4[k * 16 + rg2 * 2];
            float4 h1 = lhT4[k * 16 + rg2 * 2 + 1];
            float4 ww = *(const float4*)&W2[(size_t)k * HID + cg2 * 4];
            float hr[8] = { h0.x, h0.y, h0.z, h0.w, h1.x, h1.y, h1.z, h1.w };
            float wc[4] = { ww.x, ww.y, ww.z, ww.w };
            #pragma unroll
            for (int r = 0; r < 8; r++)
                #pragma unroll
                for (int c = 0; c < 4; c++)
                    acc[r][c] = fmaf(hr[r], wc[c], acc[r][c]);
        }
        #pragma unroll
        for (int r = 0; r < 8; r++) {
            float4 o; o.x = acc[r][0]; o.y = acc[r][1]; o.z = acc[r][2]; o.w = acc[r][3];
            *(float4*)&hw[(size_t)(row0 + rg2 * 8 + r) * HID + cg2 * 4] = o;
        }
    }
}

// ===== K7: stage-2 GCN via CSR pull, fused bias/relu/score =====
__global__ __launch_bounds__(256) void k_pull2(
    const int* __restrict__ srcs2, const int* __restrict__ rs2, const int* __restrict__ ic2,
    const float* __restrict__ dfull2, const float* __restrict__ dinv2,
    const float* __restrict__ hw, const float* __restrict__ b2,
    const float* __restrict__ sW2, const float* __restrict__ sb2,
    float* __restrict__ h2, float* __restrict__ ds02, float* __restrict__ sc2i)
{
    int node = blockIdx.x * 4 + (threadIdx.x >> 6);
    int lane = threadIdx.x & 63;
    int rs = rs2[node], cnt = ic2[node];
    float a0 = 0.f, a1 = 0.f;
    for (int j = 0; j < cnt; j++) {
        int s = srcs2[rs + j];
        float w = dinv2[s];
        a0 = fmaf(w, hw[(size_t)s * HID + lane], a0);
        a1 = fmaf(w, hw[(size_t)s * HID + 64 + lane], a1);
    }
    float df = dfull2[node], di = dinv2[node];
    float h0 = frelu(a0 * di + hw[(size_t)node * HID + lane] / df + b2[lane]);
    float h1 = frelu(a1 * di + hw[(size_t)node * HID + 64 + lane] / df + b2[lane + 64]);
    h2[(size_t)node * HID + lane] = h0;
    h2[(size_t)node * HID + 64 + lane] = h1;
    float dot = h0 * sW2[lane] + h1 * sW2[lane + 64];
    #pragma unroll
    for (int o = 32; o > 0; o >>= 1) dot += __shfl_down(dot, o);
    if (lane == 0) {
        ds02[node] = di * dot;
        sc2i[node] = dot / df + sb2[0];
    }
}

// ===== K8: topk2 + readout2 + head (1024 threads, latency-parallelized) =====
__global__ __launch_bounds__(1024) void k_tkhead(
    const int* __restrict__ srcs2, const int* __restrict__ rs2, const int* __restrict__ ic2,
    const float* __restrict__ dinv2, const float* __restrict__ ds02,
    const float* __restrict__ sc2i, const float* __restrict__ h2,
    const float* __restrict__ x1b, const float* __restrict__ gi,
    const float* __restrict__ l1W, const float* __restrict__ l1b,
    const float* __restrict__ l2W, const float* __restrict__ l2b,
    const float* __restrict__ l3W, const float* __restrict__ l3b,
    float* __restrict__ out)
{
    __shared__ float sv[K1V];
    __shared__ u32   skey[K1V];
    __shared__ u32   hist[256], misc[2], wsum[16];
    __shared__ int   plist[K2V];
    __shared__ float tl[K2V];
    __shared__ float rp[1024], rp2[1024];
    __shared__ float z[272];
    __shared__ float zp[8][128];
    __shared__ float z1[HID], z2[64], z3[32], red[2];
    __shared__ int   scnt;
    const int b = blockIdx.x, tid = threadIdx.x;
    const int lane = tid & 63, wv = tid >> 6;
    if (tid == 0) scnt = 0;

    // score finalize (one node per thread, tid<512)
    if (tid < K1V) {
        int n = b * K1V + tid;
        int rsv = rs2[n], cnt = ic2[n];
        float acc = 0.f;
        for (int j = 0; j < cnt; j++) acc += ds02[srcs2[rsv + j]];
        float sc = sc2i[n] + dinv2[n] * acc;
        sv[tid] = sc; skey[tid] = f2key(sc);
    }
    __syncthreads();
    u32 tau; int R;
    radix_top<K1V, 1024>(skey, K2V, hist, misc, tau, R);

    // tie rank: one element per thread
    {
        u32 k0 = skey[tid < K1V ? tid : 0];
        int q0 = (tid < K1V && k0 == tau) ? 1 : 0;
        u32 inc = wave_iscan((u32)q0, lane);
        if (lane == 63) wsum[wv] = inc;
        __syncthreads();
        if (tid == 0) { u32 run = 0; for (int w2 = 0; w2 < 16; w2++) { u32 v = wsum[w2]; wsum[w2] = run; run += v; } }
        __syncthreads();
        u32 base = wsum[wv] + inc - (u32)q0;
        bool sel = (tid < K1V) && ((k0 > tau) || (q0 && base < (u32)R));
        if (sel) { int pos = atomicAdd(&scnt, 1); plist[pos] = b * K1V + tid; tl[pos] = tanhf(sv[tid]); }
        __syncthreads();
    }

    // readout2: 8 groups x 128 channels (8 gathers in flight per channel)
    {
        int grp = tid >> 7, c = tid & 127;
        float mx = -INFINITY, smv = 0.f;
        for (int j = grp; j < K2V; j += 8) {
            float v = h2[(size_t)plist[j] * HID + c] * tl[j];
            mx = fmaxf(mx, v); smv += v;
        }
        rp[tid] = mx; rp2[tid] = smv;
        __syncthreads();
        if (tid < 256) {
            int c2 = tid & 127, half = tid >> 7;
            if (half == 0) {
                float m = rp[c2];
                #pragma unroll
                for (int g2 = 1; g2 < 8; g2++) m = fmaxf(m, rp[g2 * 128 + c2]);
                z[c2] = x1b[b * 256 + c2] + m;
            } else {
                float s = rp2[c2];
                #pragma unroll
                for (int g2 = 1; g2 < 8; g2++) s += rp2[g2 * 128 + c2];
                z[128 + c2] = x1b[b * 256 + 128 + c2] + s / (float)K2V;
            }
        }
        if (tid < 10) z[256 + tid] = gi[b * 10 + tid];
        __syncthreads();
    }

    // head layer 1: 8 k-groups x 128 outputs, LDS reduce (k-chain 266 -> 34)
    {
        int grp = tid >> 7, c = tid & 127;
        int k0 = grp * 34;
        int k1 = k0 + 34; if (k1 > 266) k1 = 266;
        float acc = 0.f;
        for (int k = k0; k < k1; k++) acc = fmaf(z[k], l1W[k * 128 + c], acc);
        zp[grp][c] = acc;
        __syncthreads();
        if (tid < 128) {
            float s = l1b[tid];
            #pragma unroll
            for (int g2 = 0; g2 < 8; g2++) s += zp[g2][tid];
            z1[tid] = frelu(s);
        }
        __syncthreads();
    }

    // head layer 2: 8 k-groups x 64 outputs (tid<512), LDS reduce
    {
        if (tid < 512) {
            int grp = tid >> 6, c = tid & 63;
            int k0 = grp * 16;
            float acc = 0.f;
            #pragma unroll
            for (int k = k0; k < k0 + 16; k++) acc = fmaf(z1[k], l2W[k * 64 + c], acc);
            zp[grp][c] = acc;
        }
        __syncthreads();
        if (tid < 64) {
            float s = l2b[tid];
            #pragma unroll
            for (int g2 = 0; g2 < 8; g2++) s += zp[g2][tid];
            z2[tid] = frelu(s);
        }
        __syncthreads();
    }

    // head layer 3 + log_softmax
    if (tid < 32) {
        float a3 = l3b[tid];
        for (int k = 0; k < 64; k++) a3 = fmaf(z2[k], l3W[k * 32 + tid], a3);
        z3[tid] = a3;
    }
    __syncthreads();
    if (tid == 0) {
        float m = -INFINITY;
        for (int c2 = 0; c2 < 32; c2++) m = fmaxf(m, z3[c2]);
        float s = 0.f;
        for (int c2 = 0; c2 < 32; c2++) s += expf(z3[c2] - m);
        red[0] = m; red[1] = logf(s);
    }
    __syncthreads();
    if (tid < 32) out[b * 32 + tid] = z3[tid] - red[0] - red[1];
}

// ============ launch ============
extern "C" void kernel_launch(void* const* d_in, const int* in_sizes, int n_in,
                              void* d_out, int out_size, void* d_ws, size_t ws_size,
                              hipStream_t stream) {
    const float* x    = (const float*)d_in[0];
    const int*   esrc = (const int*)d_in[1];
    const int*   edst = (const int*)d_in[2];
    const float* gi   = (const float*)d_in[3];
    const float* W1   = (const float*)d_in[4];
    const float* b1   = (const float*)d_in[5];
    const float* sW1  = (const float*)d_in[6];
    const float* sb1  = (const float*)d_in[7];
    const float* W2   = (const float*)d_in[8];
    const float* b2   = (const float*)d_in[9];
    const float* sW2  = (const float*)d_in[10];
    const float* sb2  = (const float*)d_in[11];
    const float* l1W  = (const float*)d_in[12];
    const float* l1b  = (const float*)d_in[13];
    const float* l2W  = (const float*)d_in[14];
    const float* l2b  = (const float*)d_in[15];
    const float* l3W  = (const float*)d_in[16];
    const float* l3b  = (const float*)d_in[17];
    float* out = (float*)d_out;

    char* p = (char*)d_ws;
    auto alloc = [&](size_t bytes) {
        char* r = p;
        p += (bytes + 255) & ~size_t(255);
        return (void*)r;
    };
    int*   degp   = (int*)alloc((size_t)NB * NQ * NPG * 4);
    float* df_g   = (float*)alloc((size_t)NB * NPG * 4);
    float* di_g   = (float*)alloc((size_t)NB * NPG * 4);
    float* tp     = (float*)alloc((size_t)NB * NQ * NPG * 4);
    float* u_g    = (float*)alloc((size_t)NB * NPG * 4);
    float* sci_g  = (float*)alloc((size_t)NB * NPG * 4);
    float* scp    = (float*)alloc((size_t)NB * NQ * NPG * 4);
    int*   nmap_g = (int*)alloc((size_t)NB * NPG * 4);
    float* ulist  = (float*)alloc((size_t)N1 * 4);
    float* tg1    = (float*)alloc((size_t)N1 * 4);
    float* x1b    = (float*)alloc((size_t)NB * 256 * 4);
    int*   epair  = (int*)alloc((size_t)NB * NQ * QCAP * 4);
    int*   eqcnt  = (int*)alloc((size_t)NB * NQ * 4);
    int*   ldegp  = (int*)alloc((size_t)NB * NQ * K1V * 4);
    int*   srcs2  = (int*)alloc((size_t)NB * SCAP * 4);
    int*   rs2    = (int*)alloc((size_t)N1 * 4);
    int*   ic2    = (int*)alloc((size_t)N1 * 4);
    float* dfull2 = (float*)alloc((size_t)N1 * 4);
    float* dinv2  = (float*)alloc((size_t)N1 * 4);
    float* hw     = (float*)alloc((size_t)N1 * HID * 4);
    float* h2     = (float*)alloc((size_t)N1 * HID * 4);
    float* ds02   = (float*)alloc((size_t)N1 * 4);
    float* sc2i   = (float*)alloc((size_t)N1 * 4);

    k_deg8<<<NB * NQ, 256, 0, stream>>>(edst, degp);
    k_sweepA<<<NB * NQ, 256, 0, stream>>>(x, esrc, edst, degp, df_g, di_g, tp);
    k_sweepB<<<NB * NQ, 256, 0, stream>>>(x, esrc, edst, tp, df_g, di_g,
                                          W1, b1, sW1, sb1, u_g, sci_g, scp);
    k_select<<<NB, 1024, 0, stream>>>(sci_g, di_g, scp, u_g, W1, b1,
                                      ulist, tg1, x1b, nmap_g);
    k_compact8<<<NB * NQ, 256, 0, stream>>>(esrc, edst, nmap_g, epair, eqcnt, ldegp);
    k_csrmm<<<NB + N1 / 64, 256, 0, stream>>>(ldegp, eqcnt, epair, srcs2, rs2, ic2,
                                              dfull2, dinv2, ulist, tg1, W1, b1, W2, hw);
    k_pull2<<<N1 / 4, 256, 0, stream>>>(srcs2, rs2, ic2, dfull2, dinv2, hw,
                                        b2, sW2, sb2, h2, ds02, sc2i);
    k_tkhead<<<NB, 1024, 0, stream>>>(srcs2, rs2, ic2, dinv2, ds02, sc2i, h2,
                                      x1b, gi, l1W, l1b, l2W, l2b, l3W, l3b, out);
}

// Round 11
// 126.549 us; speedup vs baseline: 5.4631x; 1.0426x over previous
//
#include <hip/hip_runtime.h>
#include <math.h>

#define NB    64
#define NPG   2048      // nodes per graph
#define EPG   16384     // edges per graph
#define HID   128
#define K1V   512
#define K2V   128
#define N1    32768     // NB*K1V
#define MSK   (NPG - 1)
#define NQ    4         // edge segments per graph
#define ESEG  (EPG / NQ)   // 4096
#define SLOTS 24        // per-node CSR slot capacity (in-deg ~ Poisson(2))

typedef unsigned int u32;

static __device__ __forceinline__ float frelu(float v) { return v > 0.f ? v : 0.f; }

static __device__ __forceinline__ u32 f2key(float f) {
    u32 u = __float_as_uint(f);
    return u ^ ((u >> 31) ? 0xFFFFFFFFu : 0x80000000u);
}

static __device__ __forceinline__ u32 wave_iscan(u32 v, int lane) {
    #pragma unroll
    for (int off = 1; off < 64; off <<= 1) {
        u32 t = __shfl_up(v, off);
        if (lane >= off) v += t;
    }
    return v;
}

// Radix-select the K-th largest key among N LDS keys (T threads).
template <int N, int T>
static __device__ __forceinline__ void radix_top(const u32* __restrict__ key, int K,
                                                 u32* hist, u32* misc,
                                                 u32& tau, int& R) {
    const int tid = threadIdx.x;
    if (tid == 0) { misc[0] = 0u; misc[1] = (u32)K; }
    __syncthreads();
    #pragma unroll
    for (int p = 0; p < 4; p++) {
        const int shift = 24 - 8 * p;
        for (int i = tid; i < 256; i += T) hist[i] = 0u;
        __syncthreads();
        const u32 prefix = misc[0];
        const u32 need   = misc[1];
        for (int i = tid; i < N; i += T) {
            u32 k = key[i];
            bool ok = (p == 0) || ((k >> (shift + 8)) == prefix);
            if (ok) atomicAdd(&hist[(k >> shift) & 255u], 1u);
        }
        __syncthreads();
        if (tid < 64) {
            const int lane = tid;
            u32 c0 = hist[4 * lane + 0], c1 = hist[4 * lane + 1];
            u32 c2 = hist[4 * lane + 2], c3 = hist[4 * lane + 3];
            u32 local = c0 + c1 + c2 + c3;
            u32 inc = local;
            #pragma unroll
            for (int off = 1; off < 64; off <<= 1) {
                u32 v = __shfl_down(inc, off);
                if (lane + off < 64) inc += v;
            }
            u32 excl = inc - local;
            u32 ge3 = excl + c3, ge2 = ge3 + c2, ge1 = ge2 + c1, ge0 = ge1 + c0;
            int selb = -1; u32 gt = 0;
            if      (ge3 >= need && excl < need) { selb = 4 * lane + 3; gt = excl; }
            else if (ge2 >= need && ge3  < need) { selb = 4 * lane + 2; gt = ge3; }
            else if (ge1 >= need && ge2  < need) { selb = 4 * lane + 1; gt = ge2; }
            else if (ge0 >= need && ge1  < need) { selb = 4 * lane + 0; gt = ge1; }
            if (selb >= 0) { misc[0] = (prefix << 8) | (u32)selb; misc[1] = need - gt; }
        }
        __syncthreads();
    }
    tau = misc[0];
    R = (int)misc[1];
}

// ===== K1: fused deg-histogram + nodeA + t-sweep =====
// Each block: full-graph dst histogram in LDS -> df/di/dx, then its segment's
// t-scatter; q==0 block writes df_g/di_g.
__global__ __launch_bounds__(256) void k_sweepA(const float* __restrict__ x,
                                                const int* __restrict__ esrc,
                                                const int* __restrict__ edst,
                                                float* __restrict__ df_g,
                                                float* __restrict__ di_g,
                                                float* __restrict__ tp) {
    __shared__ int   cnt[NPG];
    __shared__ float lv[NPG];
    __shared__ float acc[NPG];
    const int bid = blockIdx.x, tid = threadIdx.x;
    const int g = bid >> 2, q = bid & 3;
    for (int i = tid; i < NPG; i += 256) { cnt[i] = 0; acc[i] = 0.f; }
    __syncthreads();
    const int4* dall = (const int4*)(edst + (size_t)g * EPG);
    for (int i = tid; i < EPG / 4; i += 256) {
        int4 dd = dall[i];
        atomicAdd(&cnt[dd.x & MSK], 1); atomicAdd(&cnt[dd.y & MSK], 1);
        atomicAdd(&cnt[dd.z & MSK], 1); atomicAdd(&cnt[dd.w & MSK], 1);
    }
    __syncthreads();
    for (int i = tid; i < NPG; i += 256) {
        float df = (float)cnt[i] + 1.0f;
        float di = rsqrtf(df);
        lv[i] = di * x[(size_t)g * NPG + i];
        if (q == 0) { df_g[(size_t)g * NPG + i] = df; di_g[(size_t)g * NPG + i] = di; }
    }
    __syncthreads();
    const int4* s4 = (const int4*)(esrc + g * EPG + q * ESEG);
    const int4* d4 = (const int4*)(edst + g * EPG + q * ESEG);
    for (int i = tid; i < ESEG / 4; i += 256) {
        int4 ss = s4[i]; int4 dd = d4[i];
        atomicAdd(&acc[dd.x & MSK], lv[ss.x & MSK]);
        atomicAdd(&acc[dd.y & MSK], lv[ss.y & MSK]);
        atomicAdd(&acc[dd.z & MSK], lv[ss.z & MSK]);
        atomicAdd(&acc[dd.w & MSK], lv[ss.w & MSK]);
    }
    __syncthreads();
    float4* op = (float4*)(tp + (size_t)bid * NPG);
    const float4* ap = (const float4*)acc;
    for (int i = tid; i < NPG / 4; i += 256) op[i] = ap[i];
}

// ===== K2: fused nodeB + score-sweep =====
__global__ __launch_bounds__(256) void k_sweepB(const float* __restrict__ x,
                                                const int* __restrict__ esrc,
                                                const int* __restrict__ edst,
                                                const float* __restrict__ tp,
                                                const float* __restrict__ df_g,
                                                const float* __restrict__ di_g,
                                                const float* __restrict__ W1,
                                                const float* __restrict__ b1,
                                                const float* __restrict__ sW1,
                                                const float* __restrict__ sb1,
                                                float* __restrict__ u_g,
                                                float* __restrict__ sci_g,
                                                float* __restrict__ scp) {
    __shared__ float lv[NPG];
    __shared__ float acc[NPG];
    __shared__ float lw[HID], lbb[HID], lsw[HID];
    const int bid = blockIdx.x, tid = threadIdx.x;
    const int g = bid >> 2, q = bid & 3;
    if (tid < HID) { lw[tid] = W1[tid]; lbb[tid] = b1[tid]; lsw[tid] = sW1[tid]; }
    __syncthreads();
    const float sb1v = sb1[0];
    for (int i = tid; i < NPG; i += 256) {
        float t = 0.f;
        #pragma unroll
        for (int q2 = 0; q2 < NQ; q2++) t += tp[(size_t)(g * NQ + q2) * NPG + i];
        float df = df_g[(size_t)g * NPG + i];
        float di = di_g[(size_t)g * NPG + i];
        float u = t * di + x[(size_t)g * NPG + i] / df;
        float s = 0.f;
        #pragma unroll 8
        for (int c = 0; c < HID; c++) s += frelu(fmaf(lw[c], u, lbb[c])) * lsw[c];
        lv[i] = di * s;
        acc[i] = 0.f;
        if (q == 0) {
            u_g[(size_t)g * NPG + i] = u;
            sci_g[(size_t)g * NPG + i] = s / df + sb1v;
        }
    }
    __syncthreads();
    const int4* s4 = (const int4*)(esrc + g * EPG + q * ESEG);
    const int4* d4 = (const int4*)(edst + g * EPG + q * ESEG);
    for (int i = tid; i < ESEG / 4; i += 256) {
        int4 ss = s4[i]; int4 dd = d4[i];
        atomicAdd(&acc[dd.x & MSK], lv[ss.x & MSK]);
        atomicAdd(&acc[dd.y & MSK], lv[ss.y & MSK]);
        atomicAdd(&acc[dd.z & MSK], lv[ss.z & MSK]);
        atomicAdd(&acc[dd.w & MSK], lv[ss.w & MSK]);
    }
    __syncthreads();
    float4* op = (float4*)(scp + (size_t)bid * NPG);
    const float4* ap = (const float4*)acc;
    for (int i = tid; i < NPG / 4; i += 256) op[i] = ap[i];
}

// ===== K3: per-graph score finalize, radix top-512, nmap, readout1; zeros gdeg =====
__global__ __launch_bounds__(1024) void k_select(
    const float* __restrict__ sci_g, const float* __restrict__ di_g,
    const float* __restrict__ scp, const float* __restrict__ u_g,
    const float* __restrict__ W1, const float* __restrict__ b1,
    float* __restrict__ ulist, float* __restrict__ tg1, float* __restrict__ x1b,
    int* __restrict__ nmap_g, int* __restrict__ gdeg)
{
    __shared__ float lsc[NPG];
    __shared__ u32   lkey[NPG];
    __shared__ int   ln[NPG];
    __shared__ float ul[K1V], tgl[K1V];
    __shared__ int   sellist[K1V];
    __shared__ u32   hist[256], misc[2], wsum[16];
    __shared__ int   scnt;
    __shared__ float lw[HID], lbb[HID];
    const int b = blockIdx.x, tid = threadIdx.x;
    const int lane = tid & 63, wv = tid >> 6;

    if (tid < K1V) gdeg[b * K1V + tid] = 0;
    for (int i = tid; i < NPG; i += 1024) {
        float a = 0.f;
        #pragma unroll
        for (int q = 0; q < NQ; q++) a += scp[(size_t)(b * NQ + q) * NPG + i];
        float sc = sci_g[(size_t)b * NPG + i] + di_g[(size_t)b * NPG + i] * a;
        lsc[i] = sc;
        lkey[i] = f2key(sc);
        ln[i] = -1;
    }
    if (tid < HID) { lw[tid] = W1[tid]; lbb[tid] = b1[tid]; }
    if (tid == 0) scnt = 0;
    __syncthreads();

    u32 tau; int R;
    radix_top<NPG, 1024>(lkey, K1V, hist, misc, tau, R);

    // stable tie rank (lowest index first)
    {
        int e0 = tid * 2, e1 = e0 + 1;
        u32 k0 = lkey[e0], k1 = lkey[e1];
        int q0 = (k0 == tau) ? 1 : 0, q1 = (k1 == tau) ? 1 : 0;
        u32 inc = wave_iscan((u32)(q0 + q1), lane);
        if (lane == 63) wsum[wv] = inc;
        __syncthreads();
        if (tid == 0) { u32 run = 0; for (int w2 = 0; w2 < 16; w2++) { u32 v = wsum[w2]; wsum[w2] = run; run += v; } }
        __syncthreads();
        u32 base = wsum[wv] + inc - (u32)(q0 + q1);
        bool sel0 = (k0 > tau) || (q0 && base < (u32)R);
        bool sel1 = (k1 > tau) || (q1 && (base + (u32)q0) < (u32)R);
        if (sel0) { int pos = atomicAdd(&scnt, 1); sellist[pos] = e0; }
        if (sel1) { int pos = atomicAdd(&scnt, 1); sellist[pos] = e1; }
        __syncthreads();
    }

    if (tid < K1V) {
        int node = sellist[tid];
        float uu = u_g[(size_t)b * NPG + node];
        float g = tanhf(lsc[node]);
        ul[tid] = uu; tgl[tid] = g;
        ulist[b * K1V + tid] = uu;
        tg1[b * K1V + tid] = g;
        ln[node] = tid;
    }
    __syncthreads();
    for (int i = tid; i < NPG; i += 1024) nmap_g[(size_t)b * NPG + i] = ln[i];

    // readout1: reuse lkey as two 1024-float partial arrays
    float* rp = (float*)lkey;
    {
        int grp = tid >> 7, c = tid & 127;
        float w = lw[c], bb = lbb[c];
        float mx = -INFINITY, sm = 0.f;
        for (int j = grp; j < K1V; j += 8) {
            float v = frelu(fmaf(w, ul[j], bb)) * tgl[j];
            mx = fmaxf(mx, v); sm += v;
        }
        __syncthreads();
        rp[tid] = mx; rp[1024 + tid] = sm;
        __syncthreads();
        if (tid < HID) {
            float m2 = -INFINITY, s2 = 0.f;
            #pragma unroll
            for (int g2 = 0; g2 < 8; g2++) {
                m2 = fmaxf(m2, rp[g2 * 128 + tid]);
                s2 += rp[1024 + g2 * 128 + tid];
            }
            x1b[b * 256 + tid] = m2;
            x1b[b * 256 + HID + tid] = s2 / (float)K1V;
        }
    }
}

// ===== K4: compact->slot-CSR (blocks 0..255) || matmul (blocks 256..767) =====
__global__ __launch_bounds__(256) void k_cpmm(
    const int* __restrict__ esrc, const int* __restrict__ edst,
    const int* __restrict__ nmap_g,
    int* __restrict__ gdeg, int* __restrict__ srcs2,
    const float* __restrict__ ulist, const float* __restrict__ tg1,
    const float* __restrict__ W1, const float* __restrict__ b1,
    const float* __restrict__ W2, float* __restrict__ hw)
{
    __shared__ union U {
        int lnm[NPG];
        struct { float lhT[HID * 64]; float lu[64]; float lg[64]; } mm;
    } sm;
    const int bid = blockIdx.x, tid = threadIdx.x;

    if (bid < NB * NQ) {
        const int g = bid >> 2, q = bid & 3;
        for (int i = tid; i < NPG; i += 256) sm.lnm[i] = nmap_g[(size_t)g * NPG + i];
        __syncthreads();
        const int4* s4 = (const int4*)(esrc + g * EPG + q * ESEG);
        const int4* d4 = (const int4*)(edst + g * EPG + q * ESEG);
        const int base = g * K1V;
        for (int i = tid; i < ESEG / 4; i += 256) {
            int4 ss = s4[i]; int4 dd = d4[i];
            int sa[4] = { ss.x & MSK, ss.y & MSK, ss.z & MSK, ss.w & MSK };
            int da[4] = { dd.x & MSK, dd.y & MSK, dd.z & MSK, dd.w & MSK };
            #pragma unroll
            for (int r = 0; r < 4; r++) {
                int s2 = sm.lnm[sa[r]], d2 = sm.lnm[da[r]];
                if (s2 >= 0 && d2 >= 0) {
                    int n = base + d2;
                    int slot = atomicAdd(&gdeg[n], 1);
                    if (slot < SLOTS) srcs2[(size_t)n * SLOTS + slot] = base + s2;
                }
            }
        }
    } else {
        const int row0 = (bid - NB * NQ) * 64;
        if (tid < 64) { sm.mm.lu[tid] = ulist[row0 + tid]; sm.mm.lg[tid] = tg1[row0 + tid]; }
        __syncthreads();
        for (int idx = tid; idx < HID * 64; idx += 256) {
            int k = idx >> 6, j = idx & 63;
            sm.mm.lhT[idx] = frelu(fmaf(W1[k], sm.mm.lu[j], b1[k])) * sm.mm.lg[j];
        }
        __syncthreads();
        const int cg2 = tid & 31, rg2 = tid >> 5;
        float acc[8][4];
        #pragma unroll
        for (int r = 0; r < 8; r++)
            #pragma unroll
            for (int c = 0; c < 4; c++) acc[r][c] = 0.f;
        const float4* lhT4 = (const float4*)sm.mm.lhT;
        #pragma unroll 4
        for (int k = 0; k < HID; k++) {
            float4 h0 = lhT4[k * 16 + rg2 * 2];
            float4 h1 = lhT4[k * 16 + rg2 * 2 + 1];
            float4 ww = *(const float4*)&W2[(size_t)k * HID + cg2 * 4];
            float hr[8] = { h0.x, h0.y, h0.z, h0.w, h1.x, h1.y, h1.z, h1.w };
            float wc[4] = { ww.x, ww.y, ww.z, ww.w };
            #pragma unroll
            for (int r = 0; r < 8; r++)
                #pragma unroll
                for (int c = 0; c < 4; c++)
                    acc[r][c] = fmaf(hr[r], wc[c], acc[r][c]);
        }
        #pragma unroll
        for (int r = 0; r < 8; r++) {
            float4 o; o.x = acc[r][0]; o.y = acc[r][1]; o.z = acc[r][2]; o.w = acc[r][3];
            *(float4*)&hw[(size_t)(row0 + rg2 * 8 + r) * HID + cg2 * 4] = o;
        }
    }
}

// ===== K5: stage-2 GCN via slot-CSR pull, fused bias/relu/score =====
__global__ __launch_bounds__(256) void k_pull2(
    const int* __restrict__ srcs2, const int* __restrict__ gdeg,
    const float* __restrict__ hw, const float* __restrict__ b2,
    const float* __restrict__ sW2, const float* __restrict__ sb2,
    float* __restrict__ h2, float* __restrict__ ds02, float* __restrict__ sc2i)
{
    int node = blockIdx.x * 4 + (threadIdx.x >> 6);
    int lane = threadIdx.x & 63;
    int dg = gdeg[node];
    int cnt = dg < SLOTS ? dg : SLOTS;
    float a0 = 0.f, a1 = 0.f;
    for (int j = 0; j < cnt; j++) {
        int s = srcs2[(size_t)node * SLOTS + j];
        float w = rsqrtf((float)gdeg[s] + 1.0f);
        a0 = fmaf(w, hw[(size_t)s * HID + lane], a0);
        a1 = fmaf(w, hw[(size_t)s * HID + 64 + lane], a1);
    }
    float df = (float)dg + 1.0f;
    float di = rsqrtf(df);
    float h0 = frelu(a0 * di + hw[(size_t)node * HID + lane] / df + b2[lane]);
    float h1 = frelu(a1 * di + hw[(size_t)node * HID + 64 + lane] / df + b2[lane + 64]);
    h2[(size_t)node * HID + lane] = h0;
    h2[(size_t)node * HID + 64 + lane] = h1;
    float dot = h0 * sW2[lane] + h1 * sW2[lane + 64];
    #pragma unroll
    for (int o = 32; o > 0; o >>= 1) dot += __shfl_down(dot, o);
    if (lane == 0) {
        ds02[node] = di * dot;
        sc2i[node] = dot / df + sb2[0];
    }
}

// ===== K6: topk2 + readout2 + head (1024 threads) =====
__global__ __launch_bounds__(1024) void k_tkhead(
    const int* __restrict__ srcs2, const int* __restrict__ gdeg,
    const float* __restrict__ ds02, const float* __restrict__ sc2i,
    const float* __restrict__ h2,
    const float* __restrict__ x1b, const float* __restrict__ gi,
    const float* __restrict__ l1W, const float* __restrict__ l1b,
    const float* __restrict__ l2W, const float* __restrict__ l2b,
    const float* __restrict__ l3W, const float* __restrict__ l3b,
    float* __restrict__ out)
{
    __shared__ float sv[K1V];
    __shared__ u32   skey[K1V];
    __shared__ u32   hist[256], misc[2], wsum[16];
    __shared__ int   plist[K2V];
    __shared__ float tl[K2V];
    __shared__ float rp[1024], rp2[1024];
    __shared__ float z[272];
    __shared__ float zp[8][128];
    __shared__ float z1[HID], z2[64], z3[32], red[2];
    __shared__ int   scnt;
    const int b = blockIdx.x, tid = threadIdx.x;
    const int lane = tid & 63, wv = tid >> 6;
    if (tid == 0) scnt = 0;

    // score finalize (one node per thread, tid<512)
    if (tid < K1V) {
        int n = b * K1V + tid;
        int dg = gdeg[n];
        int cnt = dg < SLOTS ? dg : SLOTS;
        float acc = 0.f;
        for (int j = 0; j < cnt; j++) acc += ds02[srcs2[(size_t)n * SLOTS + j]];
        float sc = sc2i[n] + rsqrtf((float)dg + 1.0f) * acc;
        sv[tid] = sc; skey[tid] = f2key(sc);
    }
    __syncthreads();
    u32 tau; int R;
    radix_top<K1V, 1024>(skey, K2V, hist, misc, tau, R);

    // tie rank: one element per thread
    {
        u32 k0 = skey[tid < K1V ? tid : 0];
        int q0 = (tid < K1V && k0 == tau) ? 1 : 0;
        u32 inc = wave_iscan((u32)q0, lane);
        if (lane == 63) wsum[wv] = inc;
        __syncthreads();
        if (tid == 0) { u32 run = 0; for (int w2 = 0; w2 < 16; w2++) { u32 v = wsum[w2]; wsum[w2] = run; run += v; } }
        __syncthreads();
        u32 base = wsum[wv] + inc - (u32)q0;
        bool sel = (tid < K1V) && ((k0 > tau) || (q0 && base < (u32)R));
        if (sel) { int pos = atomicAdd(&scnt, 1); plist[pos] = b * K1V + tid; tl[pos] = tanhf(sv[tid]); }
        __syncthreads();
    }

    // readout2: 8 groups x 128 channels
    {
        int grp = tid >> 7, c = tid & 127;
        float mx = -INFINITY, smv = 0.f;
        for (int j = grp; j < K2V; j += 8) {
            float v = h2[(size_t)plist[j] * HID + c] * tl[j];
            mx = fmaxf(mx, v); smv += v;
        }
        rp[tid] = mx; rp2[tid] = smv;
        __syncthreads();
        if (tid < 256) {
            int c2 = tid & 127, half = tid >> 7;
            if (half == 0) {
                float m = rp[c2];
                #pragma unroll
                for (int g2 = 1; g2 < 8; g2++) m = fmaxf(m, rp[g2 * 128 + c2]);
                z[c2] = x1b[b * 256 + c2] + m;
            } else {
                float s = rp2[c2];
                #pragma unroll
                for (int g2 = 1; g2 < 8; g2++) s += rp2[g2 * 128 + c2];
                z[128 + c2] = x1b[b * 256 + 128 + c2] + s / (float)K2V;
            }
        }
        if (tid < 10) z[256 + tid] = gi[b * 10 + tid];
        __syncthreads();
    }

    // head layer 1: 8 k-groups x 128 outputs, LDS reduce
    {
        int grp = tid >> 7, c = tid & 127;
        int k0 = grp * 34;
        int k1 = k0 + 34; if (k1 > 266) k1 = 266;
        float acc = 0.f;
        for (int k = k0; k < k1; k++) acc = fmaf(z[k], l1W[k * 128 + c], acc);
        zp[grp][c] = acc;
        __syncthreads();
        if (tid < 128) {
            float s = l1b[tid];
            #pragma unroll
            for (int g2 = 0; g2 < 8; g2++) s += zp[g2][tid];
            z1[tid] = frelu(s);
        }
        __syncthreads();
    }

    // head layer 2: 8 k-groups x 64 outputs, LDS reduce
    {
        if (tid < 512) {
            int grp = tid >> 6, c = tid & 63;
            int k0 = grp * 16;
            float acc = 0.f;
            #pragma unroll
            for (int k = k0; k < k0 + 16; k++) acc = fmaf(z1[k], l2W[k * 64 + c], acc);
            zp[grp][c] = acc;
        }
        __syncthreads();
        if (tid < 64) {
            float s = l2b[tid];
            #pragma unroll
            for (int g2 = 0; g2 < 8; g2++) s += zp[g2][tid];
            z2[tid] = frelu(s);
        }
        __syncthreads();
    }

    // head layer 3 + log_softmax
    if (tid < 32) {
        float a3 = l3b[tid];
        for (int k = 0; k < 64; k++) a3 = fmaf(z2[k], l3W[k * 32 + tid], a3);
        z3[tid] = a3;
    }
    __syncthreads();
    if (tid == 0) {
        float m = -INFINITY;
        for (int c2 = 0; c2 < 32; c2++) m = fmaxf(m, z3[c2]);
        float s = 0.f;
        for (int c2 = 0; c2 < 32; c2++) s += expf(z3[c2] - m);
        red[0] = m; red[1] = logf(s);
    }
    __syncthreads();
    if (tid < 32) out[b * 32 + tid] = z3[tid] - red[0] - red[1];
}

// ============ launch ============
extern "C" void kernel_launch(void* const* d_in, const int* in_sizes, int n_in,
                              void* d_out, int out_size, void* d_ws, size_t ws_size,
                              hipStream_t stream) {
    const float* x    = (const float*)d_in[0];
    const int*   esrc = (const int*)d_in[1];
    const int*   edst = (const int*)d_in[2];
    const float* gi   = (const float*)d_in[3];
    const float* W1   = (const float*)d_in[4];
    const float* b1   = (const float*)d_in[5];
    const float* sW1  = (const float*)d_in[6];
    const float* sb1  = (const float*)d_in[7];
    const float* W2   = (const float*)d_in[8];
    const float* b2   = (const float*)d_in[9];
    const float* sW2  = (const float*)d_in[10];
    const float* sb2  = (const float*)d_in[11];
    const float* l1W  = (const float*)d_in[12];
    const float* l1b  = (const float*)d_in[13];
    const float* l2W  = (const float*)d_in[14];
    const float* l2b  = (const float*)d_in[15];
    const float* l3W  = (const float*)d_in[16];
    const float* l3b  = (const float*)d_in[17];
    float* out = (float*)d_out;

    char* p = (char*)d_ws;
    auto alloc = [&](size_t bytes) {
        char* r = p;
        p += (bytes + 255) & ~size_t(255);
        return (void*)r;
    };
    float* df_g   = (float*)alloc((size_t)NB * NPG * 4);
    float* di_g   = (float*)alloc((size_t)NB * NPG * 4);
    float* tp     = (float*)alloc((size_t)NB * NQ * NPG * 4);
    float* u_g    = (float*)alloc((size_t)NB * NPG * 4);
    float* sci_g  = (float*)alloc((size_t)NB * NPG * 4);
    float* scp    = (float*)alloc((size_t)NB * NQ * NPG * 4);
    int*   nmap_g = (int*)alloc((size_t)NB * NPG * 4);
    float* ulist  = (float*)alloc((size_t)N1 * 4);
    float* tg1    = (float*)alloc((size_t)N1 * 4);
    float* x1b    = (float*)alloc((size_t)NB * 256 * 4);
    int*   gdeg   = (int*)alloc((size_t)N1 * 4);
    int*   srcs2  = (int*)alloc((size_t)N1 * SLOTS * 4);
    float* hw     = (float*)alloc((size_t)N1 * HID * 4);
    float* h2     = (float*)alloc((size_t)N1 * HID * 4);
    float* ds02   = (float*)alloc((size_t)N1 * 4);
    float* sc2i   = (float*)alloc((size_t)N1 * 4);

    k_sweepA<<<NB * NQ, 256, 0, stream>>>(x, esrc, edst, df_g, di_g, tp);
    k_sweepB<<<NB * NQ, 256, 0, stream>>>(x, esrc, edst, tp, df_g, di_g,
                                          W1, b1, sW1, sb1, u_g, sci_g, scp);
    k_select<<<NB, 1024, 0, stream>>>(sci_g, di_g, scp, u_g, W1, b1,
                                      ulist, tg1, x1b, nmap_g, gdeg);
    k_cpmm<<<NB * NQ + N1 / 64, 256, 0, stream>>>(esrc, edst, nmap_g, gdeg, srcs2,
                                                  ulist, tg1, W1, b1, W2, hw);
    k_pull2<<<N1 / 4, 256, 0, stream>>>(srcs2, gdeg, hw, b2, sW2, sb2, h2, ds02, sc2i);
    k_tkhead<<<NB, 1024, 0, stream>>>(srcs2, gdeg, ds02, sc2i, h2,
                                      x1b, gi, l1W, l1b, l2W, l2b, l3W, l3b, out);
}

// Round 12
// 115.410 us; speedup vs baseline: 5.9904x; 1.0965x over previous
//
#include <hip/hip_runtime.h>
#include <math.h>

#define NB    64
#define NPG   2048      // nodes per graph
#define EPG   16384     // edges per graph
#define HID   128
#define K1V   512
#define K2V   128
#define N1    32768     // NB*K1V
#define MSK   (NPG - 1)
#define NQ    4         // edge segments per graph
#define ESEG  (EPG / NQ)   // 4096
#define SLOTS 24        // per-node CSR slot capacity (in-deg ~ Poisson(2))

typedef unsigned int u32;

static __device__ __forceinline__ float frelu(float v) { return v > 0.f ? v : 0.f; }

static __device__ __forceinline__ u32 f2key(float f) {
    u32 u = __float_as_uint(f);
    return u ^ ((u >> 31) ? 0xFFFFFFFFu : 0x80000000u);
}

static __device__ __forceinline__ u32 wave_iscan(u32 v, int lane) {
    #pragma unroll
    for (int off = 1; off < 64; off <<= 1) {
        u32 t = __shfl_up(v, off);
        if (lane >= off) v += t;
    }
    return v;
}

// Radix-select the K-th largest key among N LDS keys (T threads).
template <int N, int T>
static __device__ __forceinline__ void radix_top(const u32* __restrict__ key, int K,
                                                 u32* hist, u32* misc,
                                                 u32& tau, int& R) {
    const int tid = threadIdx.x;
    if (tid == 0) { misc[0] = 0u; misc[1] = (u32)K; }
    __syncthreads();
    #pragma unroll
    for (int p = 0; p < 4; p++) {
        const int shift = 24 - 8 * p;
        for (int i = tid; i < 256; i += T) hist[i] = 0u;
        __syncthreads();
        const u32 prefix = misc[0];
        const u32 need   = misc[1];
        for (int i = tid; i < N; i += T) {
            u32 k = key[i];
            bool ok = (p == 0) || ((k >> (shift + 8)) == prefix);
            if (ok) atomicAdd(&hist[(k >> shift) & 255u], 1u);
        }
        __syncthreads();
        if (tid < 64) {
            const int lane = tid;
            u32 c0 = hist[4 * lane + 0], c1 = hist[4 * lane + 1];
            u32 c2 = hist[4 * lane + 2], c3 = hist[4 * lane + 3];
            u32 local = c0 + c1 + c2 + c3;
            u32 inc = local;
            #pragma unroll
            for (int off = 1; off < 64; off <<= 1) {
                u32 v = __shfl_down(inc, off);
                if (lane + off < 64) inc += v;
            }
            u32 excl = inc - local;
            u32 ge3 = excl + c3, ge2 = ge3 + c2, ge1 = ge2 + c1, ge0 = ge1 + c0;
            int selb = -1; u32 gt = 0;
            if      (ge3 >= need && excl < need) { selb = 4 * lane + 3; gt = excl; }
            else if (ge2 >= need && ge3  < need) { selb = 4 * lane + 2; gt = ge3; }
            else if (ge1 >= need && ge2  < need) { selb = 4 * lane + 1; gt = ge2; }
            else if (ge0 >= need && ge1  < need) { selb = 4 * lane + 0; gt = ge1; }
            if (selb >= 0) { misc[0] = (prefix << 8) | (u32)selb; misc[1] = need - gt; }
        }
        __syncthreads();
    }
    tau = misc[0];
    R = (int)misc[1];
}

// ===== K1: fused deg-histogram + nodeA + t-sweep (512 thr, 8 waves/CU) =====
__global__ __launch_bounds__(512) void k_sweepA(const float* __restrict__ x,
                                                const int* __restrict__ esrc,
                                                const int* __restrict__ edst,
                                                float* __restrict__ df_g,
                                                float* __restrict__ di_g,
                                                float* __restrict__ tp) {
    __shared__ int   cnt[NPG];
    __shared__ float lv[NPG];
    __shared__ float acc[NPG];
    const int bid = blockIdx.x, tid = threadIdx.x;
    const int g = bid >> 2, q = bid & 3;
    for (int i = tid; i < NPG; i += 512) { cnt[i] = 0; acc[i] = 0.f; }
    __syncthreads();
    const int4* dall = (const int4*)(edst + (size_t)g * EPG);
    for (int i = tid; i < EPG / 4; i += 512) {
        int4 dd = dall[i];
        atomicAdd(&cnt[dd.x & MSK], 1); atomicAdd(&cnt[dd.y & MSK], 1);
        atomicAdd(&cnt[dd.z & MSK], 1); atomicAdd(&cnt[dd.w & MSK], 1);
    }
    __syncthreads();
    for (int i = tid; i < NPG; i += 512) {
        float df = (float)cnt[i] + 1.0f;
        float di = rsqrtf(df);
        lv[i] = di * x[(size_t)g * NPG + i];
        if (q == 0) { df_g[(size_t)g * NPG + i] = df; di_g[(size_t)g * NPG + i] = di; }
    }
    __syncthreads();
    const int4* s4 = (const int4*)(esrc + g * EPG + q * ESEG);
    const int4* d4 = (const int4*)(edst + g * EPG + q * ESEG);
    for (int i = tid; i < ESEG / 4; i += 512) {
        int4 ss = s4[i]; int4 dd = d4[i];
        atomicAdd(&acc[dd.x & MSK], lv[ss.x & MSK]);
        atomicAdd(&acc[dd.y & MSK], lv[ss.y & MSK]);
        atomicAdd(&acc[dd.z & MSK], lv[ss.z & MSK]);
        atomicAdd(&acc[dd.w & MSK], lv[ss.w & MSK]);
    }
    __syncthreads();
    float4* op = (float4*)(tp + (size_t)bid * NPG);
    const float4* ap = (const float4*)acc;
    for (int i = tid; i < NPG / 4; i += 512) op[i] = ap[i];
}

// ===== K2: fused nodeB + score-sweep (512 thr, 8 waves/CU) =====
__global__ __launch_bounds__(512) void k_sweepB(const float* __restrict__ x,
                                                const int* __restrict__ esrc,
                                                const int* __restrict__ edst,
                                                const float* __restrict__ tp,
                                                const float* __restrict__ df_g,
                                                const float* __restrict__ di_g,
                                                const float* __restrict__ W1,
                                                const float* __restrict__ b1,
                                                const float* __restrict__ sW1,
                                                const float* __restrict__ sb1,
                                                float* __restrict__ u_g,
                                                float* __restrict__ sci_g,
                                                float* __restrict__ scp) {
    __shared__ float lv[NPG];
    __shared__ float acc[NPG];
    __shared__ float lw[HID], lbb[HID], lsw[HID];
    const int bid = blockIdx.x, tid = threadIdx.x;
    const int g = bid >> 2, q = bid & 3;
    if (tid < HID) { lw[tid] = W1[tid]; lbb[tid] = b1[tid]; lsw[tid] = sW1[tid]; }
    __syncthreads();
    const float sb1v = sb1[0];
    for (int i = tid; i < NPG; i += 512) {
        float t = 0.f;
        #pragma unroll
        for (int q2 = 0; q2 < NQ; q2++) t += tp[(size_t)(g * NQ + q2) * NPG + i];
        float df = df_g[(size_t)g * NPG + i];
        float di = di_g[(size_t)g * NPG + i];
        float u = t * di + x[(size_t)g * NPG + i] / df;
        float s = 0.f;
        #pragma unroll 8
        for (int c = 0; c < HID; c++) s += frelu(fmaf(lw[c], u, lbb[c])) * lsw[c];
        lv[i] = di * s;
        acc[i] = 0.f;
        if (q == 0) {
            u_g[(size_t)g * NPG + i] = u;
            sci_g[(size_t)g * NPG + i] = s / df + sb1v;
        }
    }
    __syncthreads();
    const int4* s4 = (const int4*)(esrc + g * EPG + q * ESEG);
    const int4* d4 = (const int4*)(edst + g * EPG + q * ESEG);
    for (int i = tid; i < ESEG / 4; i += 512) {
        int4 ss = s4[i]; int4 dd = d4[i];
        atomicAdd(&acc[dd.x & MSK], lv[ss.x & MSK]);
        atomicAdd(&acc[dd.y & MSK], lv[ss.y & MSK]);
        atomicAdd(&acc[dd.z & MSK], lv[ss.z & MSK]);
        atomicAdd(&acc[dd.w & MSK], lv[ss.w & MSK]);
    }
    __syncthreads();
    float4* op = (float4*)(scp + (size_t)bid * NPG);
    const float4* ap = (const float4*)acc;
    for (int i = tid; i < NPG / 4; i += 512) op[i] = ap[i];
}

// ===== K3: per-graph score finalize, radix top-512, nmap, readout1; zeros gdeg =====
__global__ __launch_bounds__(1024) void k_select(
    const float* __restrict__ sci_g, const float* __restrict__ di_g,
    const float* __restrict__ scp, const float* __restrict__ u_g,
    const float* __restrict__ W1, const float* __restrict__ b1,
    float* __restrict__ ulist, float* __restrict__ tg1, float* __restrict__ x1b,
    int* __restrict__ nmap_g, int* __restrict__ gdeg)
{
    __shared__ float lsc[NPG];
    __shared__ u32   lkey[NPG];
    __shared__ int   ln[NPG];
    __shared__ float ul[K1V], tgl[K1V];
    __shared__ int   sellist[K1V];
    __shared__ u32   hist[256], misc[2], wsum[16];
    __shared__ int   scnt;
    __shared__ float lw[HID], lbb[HID];
    const int b = blockIdx.x, tid = threadIdx.x;
    const int lane = tid & 63, wv = tid >> 6;

    if (tid < K1V) gdeg[b * K1V + tid] = 0;
    for (int i = tid; i < NPG; i += 1024) {
        float a = 0.f;
        #pragma unroll
        for (int q = 0; q < NQ; q++) a += scp[(size_t)(b * NQ + q) * NPG + i];
        float sc = sci_g[(size_t)b * NPG + i] + di_g[(size_t)b * NPG + i] * a;
        lsc[i] = sc;
        lkey[i] = f2key(sc);
        ln[i] = -1;
    }
    if (tid < HID) { lw[tid] = W1[tid]; lbb[tid] = b1[tid]; }
    if (tid == 0) scnt = 0;
    __syncthreads();

    u32 tau; int R;
    radix_top<NPG, 1024>(lkey, K1V, hist, misc, tau, R);

    // stable tie rank (lowest index first)
    {
        int e0 = tid * 2, e1 = e0 + 1;
        u32 k0 = lkey[e0], k1 = lkey[e1];
        int q0 = (k0 == tau) ? 1 : 0, q1 = (k1 == tau) ? 1 : 0;
        u32 inc = wave_iscan((u32)(q0 + q1), lane);
        if (lane == 63) wsum[wv] = inc;
        __syncthreads();
        if (tid == 0) { u32 run = 0; for (int w2 = 0; w2 < 16; w2++) { u32 v = wsum[w2]; wsum[w2] = run; run += v; } }
        __syncthreads();
        u32 base = wsum[wv] + inc - (u32)(q0 + q1);
        bool sel0 = (k0 > tau) || (q0 && base < (u32)R);
        bool sel1 = (k1 > tau) || (q1 && (base + (u32)q0) < (u32)R);
        if (sel0) { int pos = atomicAdd(&scnt, 1); sellist[pos] = e0; }
        if (sel1) { int pos = atomicAdd(&scnt, 1); sellist[pos] = e1; }
        __syncthreads();
    }

    if (tid < K1V) {
        int node = sellist[tid];
        float uu = u_g[(size_t)b * NPG + node];
        float g = tanhf(lsc[node]);
        ul[tid] = uu; tgl[tid] = g;
        ulist[b * K1V + tid] = uu;
        tg1[b * K1V + tid] = g;
        ln[node] = tid;
    }
    __syncthreads();
    for (int i = tid; i < NPG; i += 1024) nmap_g[(size_t)b * NPG + i] = ln[i];

    // readout1: reuse lkey as two 1024-float partial arrays
    float* rp = (float*)lkey;
    {
        int grp = tid >> 7, c = tid & 127;
        float w = lw[c], bb = lbb[c];
        float mx = -INFINITY, sm = 0.f;
        for (int j = grp; j < K1V; j += 8) {
            float v = frelu(fmaf(w, ul[j], bb)) * tgl[j];
            mx = fmaxf(mx, v); sm += v;
        }
        __syncthreads();
        rp[tid] = mx; rp[1024 + tid] = sm;
        __syncthreads();
        if (tid < HID) {
            float m2 = -INFINITY, s2 = 0.f;
            #pragma unroll
            for (int g2 = 0; g2 < 8; g2++) {
                m2 = fmaxf(m2, rp[g2 * 128 + tid]);
                s2 += rp[1024 + g2 * 128 + tid];
            }
            x1b[b * 256 + tid] = m2;
            x1b[b * 256 + HID + tid] = s2 / (float)K1V;
        }
    }
}

// ===== K4: compact->slot-CSR (blocks 0..255) || matmul (blocks 256..767) =====
__global__ __launch_bounds__(256) void k_cpmm(
    const int* __restrict__ esrc, const int* __restrict__ edst,
    const int* __restrict__ nmap_g,
    int* __restrict__ gdeg, int* __restrict__ srcs2,
    const float* __restrict__ ulist, const float* __restrict__ tg1,
    const float* __restrict__ W1, const float* __restrict__ b1,
    const float* __restrict__ W2, float* __restrict__ hw)
{
    __shared__ union U {
        int lnm[NPG];
        struct { float lhT[HID * 64]; float lu[64]; float lg[64]; } mm;
    } sm;
    const int bid = blockIdx.x, tid = threadIdx.x;

    if (bid < NB * NQ) {
        const int g = bid >> 2, q = bid & 3;
        for (int i = tid; i < NPG; i += 256) sm.lnm[i] = nmap_g[(size_t)g * NPG + i];
        __syncthreads();
        const int4* s4 = (const int4*)(esrc + g * EPG + q * ESEG);
        const int4* d4 = (const int4*)(edst + g * EPG + q * ESEG);
        const int base = g * K1V;
        for (int i = tid; i < ESEG / 4; i += 256) {
            int4 ss = s4[i]; int4 dd = d4[i];
            int sa[4] = { ss.x & MSK, ss.y & MSK, ss.z & MSK, ss.w & MSK };
            int da[4] = { dd.x & MSK, dd.y & MSK, dd.z & MSK, dd.w & MSK };
            #pragma unroll
            for (int r = 0; r < 4; r++) {
                int s2 = sm.lnm[sa[r]], d2 = sm.lnm[da[r]];
                if (s2 >= 0 && d2 >= 0) {
                    int n = base + d2;
                    int slot = atomicAdd(&gdeg[n], 1);
                    if (slot < SLOTS) srcs2[(size_t)n * SLOTS + slot] = base + s2;
                }
            }
        }
    } else {
        const int row0 = (bid - NB * NQ) * 64;
        if (tid < 64) { sm.mm.lu[tid] = ulist[row0 + tid]; sm.mm.lg[tid] = tg1[row0 + tid]; }
        __syncthreads();
        for (int idx = tid; idx < HID * 64; idx += 256) {
            int k = idx >> 6, j = idx & 63;
            sm.mm.lhT[idx] = frelu(fmaf(W1[k], sm.mm.lu[j], b1[k])) * sm.mm.lg[j];
        }
        __syncthreads();
        const int cg2 = tid & 31, rg2 = tid >> 5;
        float acc[8][4];
        #pragma unroll
        for (int r = 0; r < 8; r++)
            #pragma unroll
            for (int c = 0; c < 4; c++) acc[r][c] = 0.f;
        const float4* lhT4 = (const float4*)sm.mm.lhT;
        #pragma unroll 4
        for (int k = 0; k < HID; k++) {
            float4 h0 = lhT4[k * 16 + rg2 * 2];
            float4 h1 = lhT4[k * 16 + rg2 * 2 + 1];
            float4 ww = *(const float4*)&W2[(size_t)k * HID + cg2 * 4];
            float hr[8] = { h0.x, h0.y, h0.z, h0.w, h1.x, h1.y, h1.z, h1.w };
            float wc[4] = { ww.x, ww.y, ww.z, ww.w };
            #pragma unroll
            for (int r = 0; r < 8; r++)
                #pragma unroll
                for (int c = 0; c < 4; c++)
                    acc[r][c] = fmaf(hr[r], wc[c], acc[r][c]);
        }
        #pragma unroll
        for (int r = 0; r < 8; r++) {
            float4 o; o.x = acc[r][0]; o.y = acc[r][1]; o.z = acc[r][2]; o.w = acc[r][3];
            *(float4*)&hw[(size_t)(row0 + rg2 * 8 + r) * HID + cg2 * 4] = o;
        }
    }
}

// ===== K5: stage-2 GCN via slot-CSR pull, fused bias/relu/score =====
__global__ __launch_bounds__(256) void k_pull2(
    const int* __restrict__ srcs2, const int* __restrict__ gdeg,
    const float* __restrict__ hw, const float* __restrict__ b2,
    const float* __restrict__ sW2, const float* __restrict__ sb2,
    float* __restrict__ h2, float* __restrict__ ds02, float* __restrict__ sc2i)
{
    int node = blockIdx.x * 4 + (threadIdx.x >> 6);
    int lane = threadIdx.x & 63;
    int dg = gdeg[node];
    int cnt = dg < SLOTS ? dg : SLOTS;
    float a0 = 0.f, a1 = 0.f;
    for (int j = 0; j < cnt; j++) {
        int s = srcs2[(size_t)node * SLOTS + j];
        float w = rsqrtf((float)gdeg[s] + 1.0f);
        a0 = fmaf(w, hw[(size_t)s * HID + lane], a0);
        a1 = fmaf(w, hw[(size_t)s * HID + 64 + lane], a1);
    }
    float df = (float)dg + 1.0f;
    float di = rsqrtf(df);
    float h0 = frelu(a0 * di + hw[(size_t)node * HID + lane] / df + b2[lane]);
    float h1 = frelu(a1 * di + hw[(size_t)node * HID + 64 + lane] / df + b2[lane + 64]);
    h2[(size_t)node * HID + lane] = h0;
    h2[(size_t)node * HID + 64 + lane] = h1;
    float dot = h0 * sW2[lane] + h1 * sW2[lane + 64];
    #pragma unroll
    for (int o = 32; o > 0; o >>= 1) dot += __shfl_down(dot, o);
    if (lane == 0) {
        ds02[node] = di * dot;
        sc2i[node] = dot / df + sb2[0];
    }
}

// ===== K6: topk2 + readout2 + head (1024 threads) =====
__global__ __launch_bounds__(1024) void k_tkhead(
    const int* __restrict__ srcs2, const int* __restrict__ gdeg,
    const float* __restrict__ ds02, const float* __restrict__ sc2i,
    const float* __restrict__ h2,
    const float* __restrict__ x1b, const float* __restrict__ gi,
    const float* __restrict__ l1W, const float* __restrict__ l1b,
    const float* __restrict__ l2W, const float* __restrict__ l2b,
    const float* __restrict__ l3W, const float* __restrict__ l3b,
    float* __restrict__ out)
{
    __shared__ float sv[K1V];
    __shared__ u32   skey[K1V];
    __shared__ u32   hist[256], misc[2], wsum[16];
    __shared__ int   plist[K2V];
    __shared__ float tl[K2V];
    __shared__ float rp[1024], rp2[1024];
    __shared__ float z[272];
    __shared__ float zp[8][128];
    __shared__ float z1[HID], z2[64], z3[32], red[2];
    __shared__ int   scnt;
    const int b = blockIdx.x, tid = threadIdx.x;
    const int lane = tid & 63, wv = tid >> 6;
    if (tid == 0) scnt = 0;

    // score finalize (one node per thread, tid<512)
    if (tid < K1V) {
        int n = b * K1V + tid;
        int dg = gdeg[n];
        int cnt = dg < SLOTS ? dg : SLOTS;
        float acc = 0.f;
        for (int j = 0; j < cnt; j++) acc += ds02[srcs2[(size_t)n * SLOTS + j]];
        float sc = sc2i[n] + rsqrtf((float)dg + 1.0f) * acc;
        sv[tid] = sc; skey[tid] = f2key(sc);
    }
    __syncthreads();
    u32 tau; int R;
    radix_top<K1V, 1024>(skey, K2V, hist, misc, tau, R);

    // tie rank: one element per thread
    {
        u32 k0 = skey[tid < K1V ? tid : 0];
        int q0 = (tid < K1V && k0 == tau) ? 1 : 0;
        u32 inc = wave_iscan((u32)q0, lane);
        if (lane == 63) wsum[wv] = inc;
        __syncthreads();
        if (tid == 0) { u32 run = 0; for (int w2 = 0; w2 < 16; w2++) { u32 v = wsum[w2]; wsum[w2] = run; run += v; } }
        __syncthreads();
        u32 base = wsum[wv] + inc - (u32)q0;
        bool sel = (tid < K1V) && ((k0 > tau) || (q0 && base < (u32)R));
        if (sel) { int pos = atomicAdd(&scnt, 1); plist[pos] = b * K1V + tid; tl[pos] = tanhf(sv[tid]); }
        __syncthreads();
    }

    // readout2: 8 groups x 128 channels
    {
        int grp = tid >> 7, c = tid & 127;
        float mx = -INFINITY, smv = 0.f;
        for (int j = grp; j < K2V; j += 8) {
            float v = h2[(size_t)plist[j] * HID + c] * tl[j];
            mx = fmaxf(mx, v); smv += v;
        }
        rp[tid] = mx; rp2[tid] = smv;
        __syncthreads();
        if (tid < 256) {
            int c2 = tid & 127, half = tid >> 7;
            if (half == 0) {
                float m = rp[c2];
                #pragma unroll
                for (int g2 = 1; g2 < 8; g2++) m = fmaxf(m, rp[g2 * 128 + c2]);
                z[c2] = x1b[b * 256 + c2] + m;
            } else {
                float s = rp2[c2];
                #pragma unroll
                for (int g2 = 1; g2 < 8; g2++) s += rp2[g2 * 128 + c2];
                z[128 + c2] = x1b[b * 256 + 128 + c2] + s / (float)K2V;
            }
        }
        if (tid < 10) z[256 + tid] = gi[b * 10 + tid];
        __syncthreads();
    }

    // head layer 1: 8 k-groups x 128 outputs, LDS reduce
    {
        int grp = tid >> 7, c = tid & 127;
        int k0 = grp * 34;
        int k1 = k0 + 34; if (k1 > 266) k1 = 266;
        float acc = 0.f;
        for (int k = k0; k < k1; k++) acc = fmaf(z[k], l1W[k * 128 + c], acc);
        zp[grp][c] = acc;
        __syncthreads();
        if (tid < 128) {
            float s = l1b[tid];
            #pragma unroll
            for (int g2 = 0; g2 < 8; g2++) s += zp[g2][tid];
            z1[tid] = frelu(s);
        }
        __syncthreads();
    }

    // head layer 2: 8 k-groups x 64 outputs, LDS reduce
    {
        if (tid < 512) {
            int grp = tid >> 6, c = tid & 63;
            int k0 = grp * 16;
            float acc = 0.f;
            #pragma unroll
            for (int k = k0; k < k0 + 16; k++) acc = fmaf(z1[k], l2W[k * 64 + c], acc);
            zp[grp][c] = acc;
        }
        __syncthreads();
        if (tid < 64) {
            float s = l2b[tid];
            #pragma unroll
            for (int g2 = 0; g2 < 8; g2++) s += zp[g2][tid];
            z2[tid] = frelu(s);
        }
        __syncthreads();
    }

    // head layer 3 + log_softmax
    if (tid < 32) {
        float a3 = l3b[tid];
        for (int k = 0; k < 64; k++) a3 = fmaf(z2[k], l3W[k * 32 + tid], a3);
        z3[tid] = a3;
    }
    __syncthreads();
    if (tid == 0) {
        float m = -INFINITY;
        for (int c2 = 0; c2 < 32; c2++) m = fmaxf(m, z3[c2]);
        float s = 0.f;
        for (int c2 = 0; c2 < 32; c2++) s += expf(z3[c2] - m);
        red[0] = m; red[1] = logf(s);
    }
    __syncthreads();
    if (tid < 32) out[b * 32 + tid] = z3[tid] - red[0] - red[1];
}

// ============ launch ============
extern "C" void kernel_launch(void* const* d_in, const int* in_sizes, int n_in,
                              void* d_out, int out_size, void* d_ws, size_t ws_size,
                              hipStream_t stream) {
    const float* x    = (const float*)d_in[0];
    const int*   esrc = (const int*)d_in[1];
    const int*   edst = (const int*)d_in[2];
    const float* gi   = (const float*)d_in[3];
    const float* W1   = (const float*)d_in[4];
    const float* b1   = (const float*)d_in[5];
    const float* sW1  = (const float*)d_in[6];
    const float* sb1  = (const float*)d_in[7];
    const float* W2   = (const float*)d_in[8];
    const float* b2   = (const float*)d_in[9];
    const float* sW2  = (const float*)d_in[10];
    const float* sb2  = (const float*)d_in[11];
    const float* l1W  = (const float*)d_in[12];
    const float* l1b  = (const float*)d_in[13];
    const float* l2W  = (const float*)d_in[14];
    const float* l2b  = (const float*)d_in[15];
    const float* l3W  = (const float*)d_in[16];
    const float* l3b  = (const float*)d_in[17];
    float* out = (float*)d_out;

    char* p = (char*)d_ws;
    auto alloc = [&](size_t bytes) {
        char* r = p;
        p += (bytes + 255) & ~size_t(255);
        return (void*)r;
    };
    float* df_g   = (float*)alloc((size_t)NB * NPG * 4);
    float* di_g   = (float*)alloc((size_t)NB * NPG * 4);
    float* tp     = (float*)alloc((size_t)NB * NQ * NPG * 4);
    float* u_g    = (float*)alloc((size_t)NB * NPG * 4);
    float* sci_g  = (float*)alloc((size_t)NB * NPG * 4);
    float* scp    = (float*)alloc((size_t)NB * NQ * NPG * 4);
    int*   nmap_g = (int*)alloc((size_t)NB * NPG * 4);
    float* ulist  = (float*)alloc((size_t)N1 * 4);
    float* tg1    = (float*)alloc((size_t)N1 * 4);
    float* x1b    = (float*)alloc((size_t)NB * 256 * 4);
    int*   gdeg   = (int*)alloc((size_t)N1 * 4);
    int*   srcs2  = (int*)alloc((size_t)N1 * SLOTS * 4);
    float* hw     = (float*)alloc((size_t)N1 * HID * 4);
    float* h2     = (float*)alloc((size_t)N1 * HID * 4);
    float* ds02   = (float*)alloc((size_t)N1 * 4);
    float* sc2i   = (float*)alloc((size_t)N1 * 4);

    k_sweepA<<<NB * NQ, 512, 0, stream>>>(x, esrc, edst, df_g, di_g, tp);
    k_sweepB<<<NB * NQ, 512, 0, stream>>>(x, esrc, edst, tp, df_g, di_g,
                                          W1, b1, sW1, sb1, u_g, sci_g, scp);
    k_select<<<NB, 1024, 0, stream>>>(sci_g, di_g, scp, u_g, W1, b1,
                                      ulist, tg1, x1b, nmap_g, gdeg);
    k_cpmm<<<NB * NQ + N1 / 64, 256, 0, stream>>>(esrc, edst, nmap_g, gdeg, srcs2,
                                                  ulist, tg1, W1, b1, W2, hw);
    k_pull2<<<N1 / 4, 256, 0, stream>>>(srcs2, gdeg, hw, b2, sW2, sb2, h2, ds02, sc2i);
    k_tkhead<<<NB, 1024, 0, stream>>>(srcs2, gdeg, ds02, sc2i, h2,
                                      x1b, gi, l1W, l1b, l2W, l2b, l3W, l3b, out);
}

// Round 13
// 114.318 us; speedup vs baseline: 6.0476x; 1.0096x over previous
//
#include <hip/hip_runtime.h>
#include <math.h>

#define NB    64
#define NPG   2048      // nodes per graph
#define EPG   16384     // edges per graph
#define HID   128
#define K1V   512
#define K2V   128
#define N1    32768     // NB*K1V
#define MSK   (NPG - 1)
#define NQ    4         // edge segments per graph
#define ESEG  (EPG / NQ)   // 4096
#define SLOTS 24        // per-node CSR slot capacity (in-deg ~ Poisson(2))

typedef unsigned int u32;

static __device__ __forceinline__ float frelu(float v) { return v > 0.f ? v : 0.f; }

static __device__ __forceinline__ u32 f2key(float f) {
    u32 u = __float_as_uint(f);
    return u ^ ((u >> 31) ? 0xFFFFFFFFu : 0x80000000u);
}

static __device__ __forceinline__ u32 wave_iscan(u32 v, int lane) {
    #pragma unroll
    for (int off = 1; off < 64; off <<= 1) {
        u32 t = __shfl_up(v, off);
        if (lane >= off) v += t;
    }
    return v;
}

// Radix-select the K-th largest key among N LDS keys (T threads).
template <int N, int T>
static __device__ __forceinline__ void radix_top(const u32* __restrict__ key, int K,
                                                 u32* hist, u32* misc,
                                                 u32& tau, int& R) {
    const int tid = threadIdx.x;
    if (tid == 0) { misc[0] = 0u; misc[1] = (u32)K; }
    __syncthreads();
    #pragma unroll
    for (int p = 0; p < 4; p++) {
        const int shift = 24 - 8 * p;
        for (int i = tid; i < 256; i += T) hist[i] = 0u;
        __syncthreads();
        const u32 prefix = misc[0];
        const u32 need   = misc[1];
        for (int i = tid; i < N; i += T) {
            u32 k = key[i];
            bool ok = (p == 0) || ((k >> (shift + 8)) == prefix);
            if (ok) atomicAdd(&hist[(k >> shift) & 255u], 1u);
        }
        __syncthreads();
        if (tid < 64) {
            const int lane = tid;
            u32 c0 = hist[4 * lane + 0], c1 = hist[4 * lane + 1];
            u32 c2 = hist[4 * lane + 2], c3 = hist[4 * lane + 3];
            u32 local = c0 + c1 + c2 + c3;
            u32 inc = local;
            #pragma unroll
            for (int off = 1; off < 64; off <<= 1) {
                u32 v = __shfl_down(inc, off);
                if (lane + off < 64) inc += v;
            }
            u32 excl = inc - local;
            u32 ge3 = excl + c3, ge2 = ge3 + c2, ge1 = ge2 + c1, ge0 = ge1 + c0;
            int selb = -1; u32 gt = 0;
            if      (ge3 >= need && excl < need) { selb = 4 * lane + 3; gt = excl; }
            else if (ge2 >= need && ge3  < need) { selb = 4 * lane + 2; gt = ge3; }
            else if (ge1 >= need && ge2  < need) { selb = 4 * lane + 1; gt = ge2; }
            else if (ge0 >= need && ge1  < need) { selb = 4 * lane + 0; gt = ge1; }
            if (selb >= 0) { misc[0] = (prefix << 8) | (u32)selb; misc[1] = need - gt; }
        }
        __syncthreads();
    }
    tau = misc[0];
    R = (int)misc[1];
}

// ===== K1: fused deg-histogram + nodeA + t-sweep (1024 thr, 16 waves/CU) =====
__global__ __launch_bounds__(1024) void k_sweepA(const float* __restrict__ x,
                                                 const int* __restrict__ esrc,
                                                 const int* __restrict__ edst,
                                                 float* __restrict__ df_g,
                                                 float* __restrict__ di_g,
                                                 float* __restrict__ tp) {
    __shared__ int   cnt[NPG];
    __shared__ float lv[NPG];
    __shared__ float acc[NPG];
    const int bid = blockIdx.x, tid = threadIdx.x;
    const int g = bid >> 2, q = bid & 3;
    for (int i = tid; i < NPG; i += 1024) { cnt[i] = 0; acc[i] = 0.f; }
    __syncthreads();
    const int4* dall = (const int4*)(edst + (size_t)g * EPG);
    for (int i = tid; i < EPG / 4; i += 1024) {
        int4 dd = dall[i];
        atomicAdd(&cnt[dd.x & MSK], 1); atomicAdd(&cnt[dd.y & MSK], 1);
        atomicAdd(&cnt[dd.z & MSK], 1); atomicAdd(&cnt[dd.w & MSK], 1);
    }
    __syncthreads();
    for (int i = tid; i < NPG; i += 1024) {
        float df = (float)cnt[i] + 1.0f;
        float di = rsqrtf(df);
        lv[i] = di * x[(size_t)g * NPG + i];
        if (q == 0) { df_g[(size_t)g * NPG + i] = df; di_g[(size_t)g * NPG + i] = di; }
    }
    __syncthreads();
    const int4* s4 = (const int4*)(esrc + g * EPG + q * ESEG);
    const int4* d4 = (const int4*)(edst + g * EPG + q * ESEG);
    for (int i = tid; i < ESEG / 4; i += 1024) {
        int4 ss = s4[i]; int4 dd = d4[i];
        atomicAdd(&acc[dd.x & MSK], lv[ss.x & MSK]);
        atomicAdd(&acc[dd.y & MSK], lv[ss.y & MSK]);
        atomicAdd(&acc[dd.z & MSK], lv[ss.z & MSK]);
        atomicAdd(&acc[dd.w & MSK], lv[ss.w & MSK]);
    }
    __syncthreads();
    float4* op = (float4*)(tp + (size_t)bid * NPG);
    const float4* ap = (const float4*)acc;
    for (int i = tid; i < NPG / 4; i += 1024) op[i] = ap[i];
}

// ===== K2: fused nodeB + score-sweep (1024 thr, 16 waves/CU) =====
__global__ __launch_bounds__(1024) void k_sweepB(const float* __restrict__ x,
                                                 const int* __restrict__ esrc,
                                                 const int* __restrict__ edst,
                                                 const float* __restrict__ tp,
                                                 const float* __restrict__ df_g,
                                                 const float* __restrict__ di_g,
                                                 const float* __restrict__ W1,
                                                 const float* __restrict__ b1,
                                                 const float* __restrict__ sW1,
                                                 const float* __restrict__ sb1,
                                                 float* __restrict__ u_g,
                                                 float* __restrict__ sci_g,
                                                 float* __restrict__ scp) {
    __shared__ float lv[NPG];
    __shared__ float acc[NPG];
    __shared__ float lw[HID], lbb[HID], lsw[HID];
    const int bid = blockIdx.x, tid = threadIdx.x;
    const int g = bid >> 2, q = bid & 3;
    if (tid < HID) { lw[tid] = W1[tid]; lbb[tid] = b1[tid]; lsw[tid] = sW1[tid]; }
    __syncthreads();
    const float sb1v = sb1[0];
    for (int i = tid; i < NPG; i += 1024) {
        float t = 0.f;
        #pragma unroll
        for (int q2 = 0; q2 < NQ; q2++) t += tp[(size_t)(g * NQ + q2) * NPG + i];
        float df = df_g[(size_t)g * NPG + i];
        float di = di_g[(size_t)g * NPG + i];
        float u = t * di + x[(size_t)g * NPG + i] / df;
        float s = 0.f;
        #pragma unroll 8
        for (int c = 0; c < HID; c++) s += frelu(fmaf(lw[c], u, lbb[c])) * lsw[c];
        lv[i] = di * s;
        acc[i] = 0.f;
        if (q == 0) {
            u_g[(size_t)g * NPG + i] = u;
            sci_g[(size_t)g * NPG + i] = s / df + sb1v;
        }
    }
    __syncthreads();
    const int4* s4 = (const int4*)(esrc + g * EPG + q * ESEG);
    const int4* d4 = (const int4*)(edst + g * EPG + q * ESEG);
    for (int i = tid; i < ESEG / 4; i += 1024) {
        int4 ss = s4[i]; int4 dd = d4[i];
        atomicAdd(&acc[dd.x & MSK], lv[ss.x & MSK]);
        atomicAdd(&acc[dd.y & MSK], lv[ss.y & MSK]);
        atomicAdd(&acc[dd.z & MSK], lv[ss.z & MSK]);
        atomicAdd(&acc[dd.w & MSK], lv[ss.w & MSK]);
    }
    __syncthreads();
    float4* op = (float4*)(scp + (size_t)bid * NPG);
    const float4* ap = (const float4*)acc;
    for (int i = tid; i < NPG / 4; i += 1024) op[i] = ap[i];
}

// ===== K3: per-graph score finalize, radix top-512, nmap, readout1; zeros gdeg =====
__global__ __launch_bounds__(1024) void k_select(
    const float* __restrict__ sci_g, const float* __restrict__ di_g,
    const float* __restrict__ scp, const float* __restrict__ u_g,
    const float* __restrict__ W1, const float* __restrict__ b1,
    float* __restrict__ ulist, float* __restrict__ tg1, float* __restrict__ x1b,
    int* __restrict__ nmap_g, int* __restrict__ gdeg)
{
    __shared__ float lsc[NPG];
    __shared__ u32   lkey[NPG];
    __shared__ int   ln[NPG];
    __shared__ float ul[K1V], tgl[K1V];
    __shared__ int   sellist[K1V];
    __shared__ u32   hist[256], misc[2], wsum[16];
    __shared__ int   scnt;
    __shared__ float lw[HID], lbb[HID];
    const int b = blockIdx.x, tid = threadIdx.x;
    const int lane = tid & 63, wv = tid >> 6;

    if (tid < K1V) gdeg[b * K1V + tid] = 0;
    for (int i = tid; i < NPG; i += 1024) {
        float a = 0.f;
        #pragma unroll
        for (int q = 0; q < NQ; q++) a += scp[(size_t)(b * NQ + q) * NPG + i];
        float sc = sci_g[(size_t)b * NPG + i] + di_g[(size_t)b * NPG + i] * a;
        lsc[i] = sc;
        lkey[i] = f2key(sc);
        ln[i] = -1;
    }
    if (tid < HID) { lw[tid] = W1[tid]; lbb[tid] = b1[tid]; }
    if (tid == 0) scnt = 0;
    __syncthreads();

    u32 tau; int R;
    radix_top<NPG, 1024>(lkey, K1V, hist, misc, tau, R);

    // stable tie rank (lowest index first)
    {
        int e0 = tid * 2, e1 = e0 + 1;
        u32 k0 = lkey[e0], k1 = lkey[e1];
        int q0 = (k0 == tau) ? 1 : 0, q1 = (k1 == tau) ? 1 : 0;
        u32 inc = wave_iscan((u32)(q0 + q1), lane);
        if (lane == 63) wsum[wv] = inc;
        __syncthreads();
        if (tid == 0) { u32 run = 0; for (int w2 = 0; w2 < 16; w2++) { u32 v = wsum[w2]; wsum[w2] = run; run += v; } }
        __syncthreads();
        u32 base = wsum[wv] + inc - (u32)(q0 + q1);
        bool sel0 = (k0 > tau) || (q0 && base < (u32)R);
        bool sel1 = (k1 > tau) || (q1 && (base + (u32)q0) < (u32)R);
        if (sel0) { int pos = atomicAdd(&scnt, 1); sellist[pos] = e0; }
        if (sel1) { int pos = atomicAdd(&scnt, 1); sellist[pos] = e1; }
        __syncthreads();
    }

    if (tid < K1V) {
        int node = sellist[tid];
        float uu = u_g[(size_t)b * NPG + node];
        float g = tanhf(lsc[node]);
        ul[tid] = uu; tgl[tid] = g;
        ulist[b * K1V + tid] = uu;
        tg1[b * K1V + tid] = g;
        ln[node] = tid;
    }
    __syncthreads();
    for (int i = tid; i < NPG; i += 1024) nmap_g[(size_t)b * NPG + i] = ln[i];

    // readout1: reuse lkey as two 1024-float partial arrays
    float* rp = (float*)lkey;
    {
        int grp = tid >> 7, c = tid & 127;
        float w = lw[c], bb = lbb[c];
        float mx = -INFINITY, sm = 0.f;
        for (int j = grp; j < K1V; j += 8) {
            float v = frelu(fmaf(w, ul[j], bb)) * tgl[j];
            mx = fmaxf(mx, v); sm += v;
        }
        __syncthreads();
        rp[tid] = mx; rp[1024 + tid] = sm;
        __syncthreads();
        if (tid < HID) {
            float m2 = -INFINITY, s2 = 0.f;
            #pragma unroll
            for (int g2 = 0; g2 < 8; g2++) {
                m2 = fmaxf(m2, rp[g2 * 128 + tid]);
                s2 += rp[1024 + g2 * 128 + tid];
            }
            x1b[b * 256 + tid] = m2;
            x1b[b * 256 + HID + tid] = s2 / (float)K1V;
        }
    }
}

// ===== K4: compact->slot-CSR (blocks 0..255) || matmul (blocks 256..767), 512 thr =====
__global__ __launch_bounds__(512) void k_cpmm(
    const int* __restrict__ esrc, const int* __restrict__ edst,
    const int* __restrict__ nmap_g,
    int* __restrict__ gdeg, int* __restrict__ srcs2,
    const float* __restrict__ ulist, const float* __restrict__ tg1,
    const float* __restrict__ W1, const float* __restrict__ b1,
    const float* __restrict__ W2, float* __restrict__ hw)
{
    __shared__ union U {
        int lnm[NPG];
        struct { float lhT[HID * 64]; float lu[64]; float lg[64]; } mm;
    } sm;
    const int bid = blockIdx.x, tid = threadIdx.x;

    if (bid < NB * NQ) {
        const int g = bid >> 2, q = bid & 3;
        for (int i = tid; i < NPG; i += 512) sm.lnm[i] = nmap_g[(size_t)g * NPG + i];
        __syncthreads();
        const int4* s4 = (const int4*)(esrc + g * EPG + q * ESEG);
        const int4* d4 = (const int4*)(edst + g * EPG + q * ESEG);
        const int base = g * K1V;
        for (int i = tid; i < ESEG / 4; i += 512) {
            int4 ss = s4[i]; int4 dd = d4[i];
            int sa[4] = { ss.x & MSK, ss.y & MSK, ss.z & MSK, ss.w & MSK };
            int da[4] = { dd.x & MSK, dd.y & MSK, dd.z & MSK, dd.w & MSK };
            #pragma unroll
            for (int r = 0; r < 4; r++) {
                int s2 = sm.lnm[sa[r]], d2 = sm.lnm[da[r]];
                if (s2 >= 0 && d2 >= 0) {
                    int n = base + d2;
                    int slot = atomicAdd(&gdeg[n], 1);
                    if (slot < SLOTS) srcs2[(size_t)n * SLOTS + slot] = base + s2;
                }
            }
        }
    } else {
        // matmul: 64 rows/block, 512 threads = 16 row-groups x 32 col-groups,
        // 4x4 register tile per thread. Per-output k-order unchanged.
        const int row0 = (bid - NB * NQ) * 64;
        if (tid < 64) { sm.mm.lu[tid] = ulist[row0 + tid]; sm.mm.lg[tid] = tg1[row0 + tid]; }
        __syncthreads();
        for (int idx = tid; idx < HID * 64; idx += 512) {
            int k = idx >> 6, j = idx & 63;
            sm.mm.lhT[idx] = frelu(fmaf(W1[k], sm.mm.lu[j], b1[k])) * sm.mm.lg[j];
        }
        __syncthreads();
        const int cg2 = tid & 31, rg2 = tid >> 5;   // 32 col-groups, 16 row-groups
        float acc[4][4];
        #pragma unroll
        for (int r = 0; r < 4; r++)
            #pragma unroll
            for (int c = 0; c < 4; c++) acc[r][c] = 0.f;
        const float4* lhT4 = (const float4*)sm.mm.lhT;
        #pragma unroll 4
        for (int k = 0; k < HID; k++) {
            float4 h = lhT4[k * 16 + rg2];
            float4 ww = *(const float4*)&W2[(size_t)k * HID + cg2 * 4];
            float hr[4] = { h.x, h.y, h.z, h.w };
            float wc[4] = { ww.x, ww.y, ww.z, ww.w };
            #pragma unroll
            for (int r = 0; r < 4; r++)
                #pragma unroll
                for (int c = 0; c < 4; c++)
                    acc[r][c] = fmaf(hr[r], wc[c], acc[r][c]);
        }
        #pragma unroll
        for (int r = 0; r < 4; r++) {
            float4 o; o.x = acc[r][0]; o.y = acc[r][1]; o.z = acc[r][2]; o.w = acc[r][3];
            *(float4*)&hw[(size_t)(row0 + rg2 * 4 + r) * HID + cg2 * 4] = o;
        }
    }
}

// ===== K5: stage-2 GCN via slot-CSR pull, fused bias/relu/score =====
__global__ __launch_bounds__(256) void k_pull2(
    const int* __restrict__ srcs2, const int* __restrict__ gdeg,
    const float* __restrict__ hw, const float* __restrict__ b2,
    const float* __restrict__ sW2, const float* __restrict__ sb2,
    float* __restrict__ h2, float* __restrict__ ds02, float* __restrict__ sc2i)
{
    int node = blockIdx.x * 4 + (threadIdx.x >> 6);
    int lane = threadIdx.x & 63;
    int dg = gdeg[node];
    int cnt = dg < SLOTS ? dg : SLOTS;
    float a0 = 0.f, a1 = 0.f;
    for (int j = 0; j < cnt; j++) {
        int s = srcs2[(size_t)node * SLOTS + j];
        float w = rsqrtf((float)gdeg[s] + 1.0f);
        a0 = fmaf(w, hw[(size_t)s * HID + lane], a0);
        a1 = fmaf(w, hw[(size_t)s * HID + 64 + lane], a1);
    }
    float df = (float)dg + 1.0f;
    float di = rsqrtf(df);
    float h0 = frelu(a0 * di + hw[(size_t)node * HID + lane] / df + b2[lane]);
    float h1 = frelu(a1 * di + hw[(size_t)node * HID + 64 + lane] / df + b2[lane + 64]);
    h2[(size_t)node * HID + lane] = h0;
    h2[(size_t)node * HID + 64 + lane] = h1;
    float dot = h0 * sW2[lane] + h1 * sW2[lane + 64];
    #pragma unroll
    for (int o = 32; o > 0; o >>= 1) dot += __shfl_down(dot, o);
    if (lane == 0) {
        ds02[node] = di * dot;
        sc2i[node] = dot / df + sb2[0];
    }
}

// ===== K6: topk2 + readout2 + head (1024 threads) =====
__global__ __launch_bounds__(1024) void k_tkhead(
    const int* __restrict__ srcs2, const int* __restrict__ gdeg,
    const float* __restrict__ ds02, const float* __restrict__ sc2i,
    const float* __restrict__ h2,
    const float* __restrict__ x1b, const float* __restrict__ gi,
    const float* __restrict__ l1W, const float* __restrict__ l1b,
    const float* __restrict__ l2W, const float* __restrict__ l2b,
    const float* __restrict__ l3W, const float* __restrict__ l3b,
    float* __restrict__ out)
{
    __shared__ float sv[K1V];
    __shared__ u32   skey[K1V];
    __shared__ u32   hist[256], misc[2], wsum[16];
    __shared__ int   plist[K2V];
    __shared__ float tl[K2V];
    __shared__ float rp[1024], rp2[1024];
    __shared__ float z[272];
    __shared__ float zp[8][128];
    __shared__ float z1[HID], z2[64], z3[32], red[2];
    __shared__ int   scnt;
    const int b = blockIdx.x, tid = threadIdx.x;
    const int lane = tid & 63, wv = tid >> 6;
    if (tid == 0) scnt = 0;

    // score finalize (one node per thread, tid<512)
    if (tid < K1V) {
        int n = b * K1V + tid;
        int dg = gdeg[n];
        int cnt = dg < SLOTS ? dg : SLOTS;
        float acc = 0.f;
        for (int j = 0; j < cnt; j++) acc += ds02[srcs2[(size_t)n * SLOTS + j]];
        float sc = sc2i[n] + rsqrtf((float)dg + 1.0f) * acc;
        sv[tid] = sc; skey[tid] = f2key(sc);
    }
    __syncthreads();
    u32 tau; int R;
    radix_top<K1V, 1024>(skey, K2V, hist, misc, tau, R);

    // tie rank: one element per thread
    {
        u32 k0 = skey[tid < K1V ? tid : 0];
        int q0 = (tid < K1V && k0 == tau) ? 1 : 0;
        u32 inc = wave_iscan((u32)q0, lane);
        if (lane == 63) wsum[wv] = inc;
        __syncthreads();
        if (tid == 0) { u32 run = 0; for (int w2 = 0; w2 < 16; w2++) { u32 v = wsum[w2]; wsum[w2] = run; run += v; } }
        __syncthreads();
        u32 base = wsum[wv] + inc - (u32)q0;
        bool sel = (tid < K1V) && ((k0 > tau) || (q0 && base < (u32)R));
        if (sel) { int pos = atomicAdd(&scnt, 1); plist[pos] = b * K1V + tid; tl[pos] = tanhf(sv[tid]); }
        __syncthreads();
    }

    // readout2: 8 groups x 128 channels
    {
        int grp = tid >> 7, c = tid & 127;
        float mx = -INFINITY, smv = 0.f;
        for (int j = grp; j < K2V; j += 8) {
            float v = h2[(size_t)plist[j] * HID + c] * tl[j];
            mx = fmaxf(mx, v); smv += v;
        }
        rp[tid] = mx; rp2[tid] = smv;
        __syncthreads();
        if (tid < 256) {
            int c2 = tid & 127, half = tid >> 7;
            if (half == 0) {
                float m = rp[c2];
                #pragma unroll
                for (int g2 = 1; g2 < 8; g2++) m = fmaxf(m, rp[g2 * 128 + c2]);
                z[c2] = x1b[b * 256 + c2] + m;
            } else {
                float s = rp2[c2];
                #pragma unroll
                for (int g2 = 1; g2 < 8; g2++) s += rp2[g2 * 128 + c2];
                z[128 + c2] = x1b[b * 256 + 128 + c2] + s / (float)K2V;
            }
        }
        if (tid < 10) z[256 + tid] = gi[b * 10 + tid];
        __syncthreads();
    }

    // head layer 1: 8 k-groups x 128 outputs, LDS reduce
    {
        int grp = tid >> 7, c = tid & 127;
        int k0 = grp * 34;
        int k1 = k0 + 34; if (k1 > 266) k1 = 266;
        float acc = 0.f;
        for (int k = k0; k < k1; k++) acc = fmaf(z[k], l1W[k * 128 + c], acc);
        zp[grp][c] = acc;
        __syncthreads();
        if (tid < 128) {
            float s = l1b[tid];
            #pragma unroll
            for (int g2 = 0; g2 < 8; g2++) s += zp[g2][tid];
            z1[tid] = frelu(s);
        }
        __syncthreads();
    }

    // head layer 2: 8 k-groups x 64 outputs, LDS reduce
    {
        if (tid < 512) {
            int grp = tid >> 6, c = tid & 63;
            int k0 = grp * 16;
            float acc = 0.f;
            #pragma unroll
            for (int k = k0; k < k0 + 16; k++) acc = fmaf(z1[k], l2W[k * 64 + c], acc);
            zp[grp][c] = acc;
        }
        __syncthreads();
        if (tid < 64) {
            float s = l2b[tid];
            #pragma unroll
            for (int g2 = 0; g2 < 8; g2++) s += zp[g2][tid];
            z2[tid] = frelu(s);
        }
        __syncthreads();
    }

    // head layer 3 + log_softmax
    if (tid < 32) {
        float a3 = l3b[tid];
        for (int k = 0; k < 64; k++) a3 = fmaf(z2[k], l3W[k * 32 + tid], a3);
        z3[tid] = a3;
    }
    __syncthreads();
    if (tid == 0) {
        float m = -INFINITY;
        for (int c2 = 0; c2 < 32; c2++) m = fmaxf(m, z3[c2]);
        float s = 0.f;
        for (int c2 = 0; c2 < 32; c2++) s += expf(z3[c2] - m);
        red[0] = m; red[1] = logf(s);
    }
    __syncthreads();
    if (tid < 32) out[b * 32 + tid] = z3[tid] - red[0] - red[1];
}

// ============ launch ============
extern "C" void kernel_launch(void* const* d_in, const int* in_sizes, int n_in,
                              void* d_out, int out_size, void* d_ws, size_t ws_size,
                              hipStream_t stream) {
    const float* x    = (const float*)d_in[0];
    const int*   esrc = (const int*)d_in[1];
    const int*   edst = (const int*)d_in[2];
    const float* gi   = (const float*)d_in[3];
    const float* W1   = (const float*)d_in[4];
    const float* b1   = (const float*)d_in[5];
    const float* sW1  = (const float*)d_in[6];
    const float* sb1  = (const float*)d_in[7];
    const float* W2   = (const float*)d_in[8];
    const float* b2   = (const float*)d_in[9];
    const float* sW2  = (const float*)d_in[10];
    const float* sb2  = (const float*)d_in[11];
    const float* l1W  = (const float*)d_in[12];
    const float* l1b  = (const float*)d_in[13];
    const float* l2W  = (const float*)d_in[14];
    const float* l2b  = (const float*)d_in[15];
    const float* l3W  = (const float*)d_in[16];
    const float* l3b  = (const float*)d_in[17];
    float* out = (float*)d_out;

    char* p = (char*)d_ws;
    auto alloc = [&](size_t bytes) {
        char* r = p;
        p += (bytes + 255) & ~size_t(255);
        return (void*)r;
    };
    float* df_g   = (float*)alloc((size_t)NB * NPG * 4);
    float* di_g   = (float*)alloc((size_t)NB * NPG * 4);
    float* tp     = (float*)alloc((size_t)NB * NQ * NPG * 4);
    float* u_g    = (float*)alloc((size_t)NB * NPG * 4);
    float* sci_g  = (float*)alloc((size_t)NB * NPG * 4);
    float* scp    = (float*)alloc((size_t)NB * NQ * NPG * 4);
    int*   nmap_g = (int*)alloc((size_t)NB * NPG * 4);
    float* ulist  = (float*)alloc((size_t)N1 * 4);
    float* tg1    = (float*)alloc((size_t)N1 * 4);
    float* x1b    = (float*)alloc((size_t)NB * 256 * 4);
    int*   gdeg   = (int*)alloc((size_t)N1 * 4);
    int*   srcs2  = (int*)alloc((size_t)N1 * SLOTS * 4);
    float* hw     = (float*)alloc((size_t)N1 * HID * 4);
    float* h2     = (float*)alloc((size_t)N1 * HID * 4);
    float* ds02   = (float*)alloc((size_t)N1 * 4);
    float* sc2i   = (float*)alloc((size_t)N1 * 4);

    k_sweepA<<<NB * NQ, 1024, 0, stream>>>(x, esrc, edst, df_g, di_g, tp);
    k_sweepB<<<NB * NQ, 1024, 0, stream>>>(x, esrc, edst, tp, df_g, di_g,
                                           W1, b1, sW1, sb1, u_g, sci_g, scp);
    k_select<<<NB, 1024, 0, stream>>>(sci_g, di_g, scp, u_g, W1, b1,
                                      ulist, tg1, x1b, nmap_g, gdeg);
    k_cpmm<<<NB * NQ + N1 / 64, 512, 0, stream>>>(esrc, edst, nmap_g, gdeg, srcs2,
                                                  ulist, tg1, W1, b1, W2, hw);
    k_pull2<<<N1 / 4, 256, 0, stream>>>(srcs2, gdeg, hw, b2, sW2, sb2, h2, ds02, sc2i);
    k_tkhead<<<NB, 1024, 0, stream>>>(srcs2, gdeg, ds02, sc2i, h2,
                                      x1b, gi, l1W, l1b, l2W, l2b, l3W, l3b, out);
}

// Round 14
// 113.410 us; speedup vs baseline: 6.0960x; 1.0080x over previous
//
#include <hip/hip_runtime.h>
#include <math.h>

#define NB    64
#define NPG   2048      // nodes per graph
#define EPG   16384     // edges per graph
#define HID   128
#define K1V   512
#define K2V   128
#define N1    32768     // NB*K1V
#define MSK   (NPG - 1)
#define NQ    4         // edge segments per graph
#define ESEG  (EPG / NQ)   // 4096
#define SLOTS 24        // per-node CSR slot capacity (in-deg ~ Poisson(2))

typedef unsigned int u32;

static __device__ __forceinline__ float frelu(float v) { return v > 0.f ? v : 0.f; }

static __device__ __forceinline__ u32 f2key(float f) {
    u32 u = __float_as_uint(f);
    return u ^ ((u >> 31) ? 0xFFFFFFFFu : 0x80000000u);
}

static __device__ __forceinline__ u32 wave_iscan(u32 v, int lane) {
    #pragma unroll
    for (int off = 1; off < 64; off <<= 1) {
        u32 t = __shfl_up(v, off);
        if (lane >= off) v += t;
    }
    return v;
}

// Radix-select the K-th largest key among N LDS keys (T threads).
template <int N, int T>
static __device__ __forceinline__ void radix_top(const u32* __restrict__ key, int K,
                                                 u32* hist, u32* misc,
                                                 u32& tau, int& R) {
    const int tid = threadIdx.x;
    if (tid == 0) { misc[0] = 0u; misc[1] = (u32)K; }
    __syncthreads();
    #pragma unroll
    for (int p = 0; p < 4; p++) {
        const int shift = 24 - 8 * p;
        for (int i = tid; i < 256; i += T) hist[i] = 0u;
        __syncthreads();
        const u32 prefix = misc[0];
        const u32 need   = misc[1];
        for (int i = tid; i < N; i += T) {
            u32 k = key[i];
            bool ok = (p == 0) || ((k >> (shift + 8)) == prefix);
            if (ok) atomicAdd(&hist[(k >> shift) & 255u], 1u);
        }
        __syncthreads();
        if (tid < 64) {
            const int lane = tid;
            u32 c0 = hist[4 * lane + 0], c1 = hist[4 * lane + 1];
            u32 c2 = hist[4 * lane + 2], c3 = hist[4 * lane + 3];
            u32 local = c0 + c1 + c2 + c3;
            u32 inc = local;
            #pragma unroll
            for (int off = 1; off < 64; off <<= 1) {
                u32 v = __shfl_down(inc, off);
                if (lane + off < 64) inc += v;
            }
            u32 excl = inc - local;
            u32 ge3 = excl + c3, ge2 = ge3 + c2, ge1 = ge2 + c1, ge0 = ge1 + c0;
            int selb = -1; u32 gt = 0;
            if      (ge3 >= need && excl < need) { selb = 4 * lane + 3; gt = excl; }
            else if (ge2 >= need && ge3  < need) { selb = 4 * lane + 2; gt = ge3; }
            else if (ge1 >= need && ge2  < need) { selb = 4 * lane + 1; gt = ge2; }
            else if (ge0 >= need && ge1  < need) { selb = 4 * lane + 0; gt = ge1; }
            if (selb >= 0) { misc[0] = (prefix << 8) | (u32)selb; misc[1] = need - gt; }
        }
        __syncthreads();
    }
    tau = misc[0];
    R = (int)misc[1];
}

// ===== K1: fused deg-histogram + nodeA + t-sweep (1024 thr, XCD-affine) =====
// bid mapping: g = bid & 63, q = bid >> 6  -> all 4 blocks of graph g share an XCD.
__global__ __launch_bounds__(1024) void k_sweepA(const float* __restrict__ x,
                                                 const int* __restrict__ esrc,
                                                 const int* __restrict__ edst,
                                                 float* __restrict__ df_g,
                                                 float* __restrict__ di_g,
                                                 float* __restrict__ tp) {
    __shared__ int   cnt[NPG];
    __shared__ float lv[NPG];
    __shared__ float acc[NPG];
    const int bid = blockIdx.x, tid = threadIdx.x;
    const int g = bid & 63, q = bid >> 6;
    for (int i = tid; i < NPG; i += 1024) { cnt[i] = 0; acc[i] = 0.f; }
    __syncthreads();
    const int4* dall = (const int4*)(edst + (size_t)g * EPG);
    for (int i = tid; i < EPG / 4; i += 1024) {
        int4 dd = dall[i];
        atomicAdd(&cnt[dd.x & MSK], 1); atomicAdd(&cnt[dd.y & MSK], 1);
        atomicAdd(&cnt[dd.z & MSK], 1); atomicAdd(&cnt[dd.w & MSK], 1);
    }
    __syncthreads();
    for (int i = tid; i < NPG; i += 1024) {
        float df = (float)cnt[i] + 1.0f;
        float di = rsqrtf(df);
        lv[i] = di * x[(size_t)g * NPG + i];
        if (q == 0) { df_g[(size_t)g * NPG + i] = df; di_g[(size_t)g * NPG + i] = di; }
    }
    __syncthreads();
    const int4* s4 = (const int4*)(esrc + g * EPG + q * ESEG);
    const int4* d4 = (const int4*)(edst + g * EPG + q * ESEG);
    for (int i = tid; i < ESEG / 4; i += 1024) {
        int4 ss = s4[i]; int4 dd = d4[i];
        atomicAdd(&acc[dd.x & MSK], lv[ss.x & MSK]);
        atomicAdd(&acc[dd.y & MSK], lv[ss.y & MSK]);
        atomicAdd(&acc[dd.z & MSK], lv[ss.z & MSK]);
        atomicAdd(&acc[dd.w & MSK], lv[ss.w & MSK]);
    }
    __syncthreads();
    float4* op = (float4*)(tp + ((size_t)g * NQ + q) * NPG);
    const float4* ap = (const float4*)acc;
    for (int i = tid; i < NPG / 4; i += 1024) op[i] = ap[i];
}

// ===== K2: fused nodeB + score-sweep (1024 thr, XCD-affine) =====
__global__ __launch_bounds__(1024) void k_sweepB(const float* __restrict__ x,
                                                 const int* __restrict__ esrc,
                                                 const int* __restrict__ edst,
                                                 const float* __restrict__ tp,
                                                 const float* __restrict__ df_g,
                                                 const float* __restrict__ di_g,
                                                 const float* __restrict__ W1,
                                                 const float* __restrict__ b1,
                                                 const float* __restrict__ sW1,
                                                 const float* __restrict__ sb1,
                                                 float* __restrict__ u_g,
                                                 float* __restrict__ sci_g,
                                                 float* __restrict__ scp) {
    __shared__ float lv[NPG];
    __shared__ float acc[NPG];
    __shared__ float lw[HID], lbb[HID], lsw[HID];
    const int bid = blockIdx.x, tid = threadIdx.x;
    const int g = bid & 63, q = bid >> 6;
    if (tid < HID) { lw[tid] = W1[tid]; lbb[tid] = b1[tid]; lsw[tid] = sW1[tid]; }
    __syncthreads();
    const float sb1v = sb1[0];
    for (int i = tid; i < NPG; i += 1024) {
        float t = 0.f;
        #pragma unroll
        for (int q2 = 0; q2 < NQ; q2++) t += tp[((size_t)g * NQ + q2) * NPG + i];
        float df = df_g[(size_t)g * NPG + i];
        float di = di_g[(size_t)g * NPG + i];
        float u = t * di + x[(size_t)g * NPG + i] / df;
        float s = 0.f;
        #pragma unroll 8
        for (int c = 0; c < HID; c++) s += frelu(fmaf(lw[c], u, lbb[c])) * lsw[c];
        lv[i] = di * s;
        acc[i] = 0.f;
        if (q == 0) {
            u_g[(size_t)g * NPG + i] = u;
            sci_g[(size_t)g * NPG + i] = s / df + sb1v;
        }
    }
    __syncthreads();
    const int4* s4 = (const int4*)(esrc + g * EPG + q * ESEG);
    const int4* d4 = (const int4*)(edst + g * EPG + q * ESEG);
    for (int i = tid; i < ESEG / 4; i += 1024) {
        int4 ss = s4[i]; int4 dd = d4[i];
        atomicAdd(&acc[dd.x & MSK], lv[ss.x & MSK]);
        atomicAdd(&acc[dd.y & MSK], lv[ss.y & MSK]);
        atomicAdd(&acc[dd.z & MSK], lv[ss.z & MSK]);
        atomicAdd(&acc[dd.w & MSK], lv[ss.w & MSK]);
    }
    __syncthreads();
    float4* op = (float4*)(scp + ((size_t)g * NQ + q) * NPG);
    const float4* ap = (const float4*)acc;
    for (int i = tid; i < NPG / 4; i += 1024) op[i] = ap[i];
}

// ===== K3: per-graph score finalize, radix top-512, nmap, readout1; zeros gdeg =====
__global__ __launch_bounds__(1024) void k_select(
    const float* __restrict__ sci_g, const float* __restrict__ di_g,
    const float* __restrict__ scp, const float* __restrict__ u_g,
    const float* __restrict__ W1, const float* __restrict__ b1,
    float* __restrict__ ulist, float* __restrict__ tg1, float* __restrict__ x1b,
    int* __restrict__ nmap_g, int* __restrict__ gdeg)
{
    __shared__ float lsc[NPG];
    __shared__ u32   lkey[NPG];
    __shared__ int   ln[NPG];
    __shared__ float ul[K1V], tgl[K1V];
    __shared__ int   sellist[K1V];
    __shared__ u32   hist[256], misc[2], wsum[16];
    __shared__ int   scnt;
    __shared__ float lw[HID], lbb[HID];
    const int b = blockIdx.x, tid = threadIdx.x;
    const int lane = tid & 63, wv = tid >> 6;

    if (tid < K1V) gdeg[b * K1V + tid] = 0;
    for (int i = tid; i < NPG; i += 1024) {
        float a = 0.f;
        #pragma unroll
        for (int q = 0; q < NQ; q++) a += scp[((size_t)b * NQ + q) * NPG + i];
        float sc = sci_g[(size_t)b * NPG + i] + di_g[(size_t)b * NPG + i] * a;
        lsc[i] = sc;
        lkey[i] = f2key(sc);
        ln[i] = -1;
    }
    if (tid < HID) { lw[tid] = W1[tid]; lbb[tid] = b1[tid]; }
    if (tid == 0) scnt = 0;
    __syncthreads();

    u32 tau; int R;
    radix_top<NPG, 1024>(lkey, K1V, hist, misc, tau, R);

    // stable tie rank (lowest index first)
    {
        int e0 = tid * 2, e1 = e0 + 1;
        u32 k0 = lkey[e0], k1 = lkey[e1];
        int q0 = (k0 == tau) ? 1 : 0, q1 = (k1 == tau) ? 1 : 0;
        u32 inc = wave_iscan((u32)(q0 + q1), lane);
        if (lane == 63) wsum[wv] = inc;
        __syncthreads();
        if (tid == 0) { u32 run = 0; for (int w2 = 0; w2 < 16; w2++) { u32 v = wsum[w2]; wsum[w2] = run; run += v; } }
        __syncthreads();
        u32 base = wsum[wv] + inc - (u32)(q0 + q1);
        bool sel0 = (k0 > tau) || (q0 && base < (u32)R);
        bool sel1 = (k1 > tau) || (q1 && (base + (u32)q0) < (u32)R);
        if (sel0) { int pos = atomicAdd(&scnt, 1); sellist[pos] = e0; }
        if (sel1) { int pos = atomicAdd(&scnt, 1); sellist[pos] = e1; }
        __syncthreads();
    }

    if (tid < K1V) {
        int node = sellist[tid];
        float uu = u_g[(size_t)b * NPG + node];
        float g = tanhf(lsc[node]);
        ul[tid] = uu; tgl[tid] = g;
        ulist[b * K1V + tid] = uu;
        tg1[b * K1V + tid] = g;
        ln[node] = tid;
    }
    __syncthreads();
    for (int i = tid; i < NPG; i += 1024) nmap_g[(size_t)b * NPG + i] = ln[i];

    // readout1: reuse lkey as two 1024-float partial arrays
    float* rp = (float*)lkey;
    {
        int grp = tid >> 7, c = tid & 127;
        float w = lw[c], bb = lbb[c];
        float mx = -INFINITY, sm = 0.f;
        for (int j = grp; j < K1V; j += 8) {
            float v = frelu(fmaf(w, ul[j], bb)) * tgl[j];
            mx = fmaxf(mx, v); sm += v;
        }
        __syncthreads();
        rp[tid] = mx; rp[1024 + tid] = sm;
        __syncthreads();
        if (tid < HID) {
            float m2 = -INFINITY, s2 = 0.f;
            #pragma unroll
            for (int g2 = 0; g2 < 8; g2++) {
                m2 = fmaxf(m2, rp[g2 * 128 + tid]);
                s2 += rp[1024 + g2 * 128 + tid];
            }
            x1b[b * 256 + tid] = m2;
            x1b[b * 256 + HID + tid] = s2 / (float)K1V;
        }
    }
}

// ===== K4: compact->slot-CSR (blocks 0..255, XCD-affine) || matmul (256..767) =====
__global__ __launch_bounds__(512) void k_cpmm(
    const int* __restrict__ esrc, const int* __restrict__ edst,
    const int* __restrict__ nmap_g,
    int* __restrict__ gdeg, int* __restrict__ srcs2,
    const float* __restrict__ ulist, const float* __restrict__ tg1,
    const float* __restrict__ W1, const float* __restrict__ b1,
    const float* __restrict__ W2, float* __restrict__ hw)
{
    __shared__ union U {
        int lnm[NPG];
        struct { float lhT[HID * 64]; float lu[64]; float lg[64]; } mm;
    } sm;
    const int bid = blockIdx.x, tid = threadIdx.x;

    if (bid < NB * NQ) {
        const int g = bid & 63, q = bid >> 6;
        for (int i = tid; i < NPG; i += 512) sm.lnm[i] = nmap_g[(size_t)g * NPG + i];
        __syncthreads();
        const int4* s4 = (const int4*)(esrc + g * EPG + q * ESEG);
        const int4* d4 = (const int4*)(edst + g * EPG + q * ESEG);
        const int base = g * K1V;
        for (int i = tid; i < ESEG / 4; i += 512) {
            int4 ss = s4[i]; int4 dd = d4[i];
            int sa[4] = { ss.x & MSK, ss.y & MSK, ss.z & MSK, ss.w & MSK };
            int da[4] = { dd.x & MSK, dd.y & MSK, dd.z & MSK, dd.w & MSK };
            #pragma unroll
            for (int r = 0; r < 4; r++) {
                int s2 = sm.lnm[sa[r]], d2 = sm.lnm[da[r]];
                if (s2 >= 0 && d2 >= 0) {
                    int n = base + d2;
                    int slot = atomicAdd(&gdeg[n], 1);
                    if (slot < SLOTS) srcs2[(size_t)n * SLOTS + slot] = base + s2;
                }
            }
        }
    } else {
        // matmul: 64 rows/block, 512 threads = 16 row-groups x 32 col-groups.
        const int row0 = (bid - NB * NQ) * 64;
        if (tid < 64) { sm.mm.lu[tid] = ulist[row0 + tid]; sm.mm.lg[tid] = tg1[row0 + tid]; }
        __syncthreads();
        for (int idx = tid; idx < HID * 64; idx += 512) {
            int k = idx >> 6, j = idx & 63;
            sm.mm.lhT[idx] = frelu(fmaf(W1[k], sm.mm.lu[j], b1[k])) * sm.mm.lg[j];
        }
        __syncthreads();
        const int cg2 = tid & 31, rg2 = tid >> 5;
        float acc[4][4];
        #pragma unroll
        for (int r = 0; r < 4; r++)
            #pragma unroll
            for (int c = 0; c < 4; c++) acc[r][c] = 0.f;
        const float4* lhT4 = (const float4*)sm.mm.lhT;
        #pragma unroll 4
        for (int k = 0; k < HID; k++) {
            float4 h = lhT4[k * 16 + rg2];
            float4 ww = *(const float4*)&W2[(size_t)k * HID + cg2 * 4];
            float hr[4] = { h.x, h.y, h.z, h.w };
            float wc[4] = { ww.x, ww.y, ww.z, ww.w };
            #pragma unroll
            for (int r = 0; r < 4; r++)
                #pragma unroll
                for (int c = 0; c < 4; c++)
                    acc[r][c] = fmaf(hr[r], wc[c], acc[r][c]);
        }
        #pragma unroll
        for (int r = 0; r < 4; r++) {
            float4 o; o.x = acc[r][0]; o.y = acc[r][1]; o.z = acc[r][2]; o.w = acc[r][3];
            *(float4*)&hw[(size_t)(row0 + rg2 * 4 + r) * HID + cg2 * 4] = o;
        }
    }
}

// ===== K5: stage-2 GCN via slot-CSR pull, fused bias/relu/score =====
__global__ __launch_bounds__(256) void k_pull2(
    const int* __restrict__ srcs2, const int* __restrict__ gdeg,
    const float* __restrict__ hw, const float* __restrict__ b2,
    const float* __restrict__ sW2, const float* __restrict__ sb2,
    float* __restrict__ h2, float* __restrict__ ds02, float* __restrict__ sc2i)
{
    int node = blockIdx.x * 4 + (threadIdx.x >> 6);
    int lane = threadIdx.x & 63;
    int dg = gdeg[node];
    int cnt = dg < SLOTS ? dg : SLOTS;
    float a0 = 0.f, a1 = 0.f;
    for (int j = 0; j < cnt; j++) {
        int s = srcs2[(size_t)node * SLOTS + j];
        float w = rsqrtf((float)gdeg[s] + 1.0f);
        a0 = fmaf(w, hw[(size_t)s * HID + lane], a0);
        a1 = fmaf(w, hw[(size_t)s * HID + 64 + lane], a1);
    }
    float df = (float)dg + 1.0f;
    float di = rsqrtf(df);
    float h0 = frelu(a0 * di + hw[(size_t)node * HID + lane] / df + b2[lane]);
    float h1 = frelu(a1 * di + hw[(size_t)node * HID + 64 + lane] / df + b2[lane + 64]);
    h2[(size_t)node * HID + lane] = h0;
    h2[(size_t)node * HID + 64 + lane] = h1;
    float dot = h0 * sW2[lane] + h1 * sW2[lane + 64];
    #pragma unroll
    for (int o = 32; o > 0; o >>= 1) dot += __shfl_down(dot, o);
    if (lane == 0) {
        ds02[node] = di * dot;
        sc2i[node] = dot / df + sb2[0];
    }
}

// ===== K6: topk2 + readout2 + head (1024 threads) =====
__global__ __launch_bounds__(1024) void k_tkhead(
    const int* __restrict__ srcs2, const int* __restrict__ gdeg,
    const float* __restrict__ ds02, const float* __restrict__ sc2i,
    const float* __restrict__ h2,
    const float* __restrict__ x1b, const float* __restrict__ gi,
    const float* __restrict__ l1W, const float* __restrict__ l1b,
    const float* __restrict__ l2W, const float* __restrict__ l2b,
    const float* __restrict__ l3W, const float* __restrict__ l3b,
    float* __restrict__ out)
{
    __shared__ float sv[K1V];
    __shared__ u32   skey[K1V];
    __shared__ u32   hist[256], misc[2], wsum[16];
    __shared__ int   plist[K2V];
    __shared__ float tl[K2V];
    __shared__ float rp[1024], rp2[1024];
    __shared__ float z[272];
    __shared__ float zp[8][128];
    __shared__ float z1[HID], z2[64], z3[32], red[2];
    __shared__ int   scnt;
    const int b = blockIdx.x, tid = threadIdx.x;
    const int lane = tid & 63, wv = tid >> 6;
    if (tid == 0) scnt = 0;

    // score finalize (one node per thread, tid<512)
    if (tid < K1V) {
        int n = b * K1V + tid;
        int dg = gdeg[n];
        int cnt = dg < SLOTS ? dg : SLOTS;
        float acc = 0.f;
        for (int j = 0; j < cnt; j++) acc += ds02[srcs2[(size_t)n * SLOTS + j]];
        float sc = sc2i[n] + rsqrtf((float)dg + 1.0f) * acc;
        sv[tid] = sc; skey[tid] = f2key(sc);
    }
    __syncthreads();
    u32 tau; int R;
    radix_top<K1V, 1024>(skey, K2V, hist, misc, tau, R);

    // tie rank: one element per thread
    {
        u32 k0 = skey[tid < K1V ? tid : 0];
        int q0 = (tid < K1V && k0 == tau) ? 1 : 0;
        u32 inc = wave_iscan((u32)q0, lane);
        if (lane == 63) wsum[wv] = inc;
        __syncthreads();
        if (tid == 0) { u32 run = 0; for (int w2 = 0; w2 < 16; w2++) { u32 v = wsum[w2]; wsum[w2] = run; run += v; } }
        __syncthreads();
        u32 base = wsum[wv] + inc - (u32)q0;
        bool sel = (tid < K1V) && ((k0 > tau) || (q0 && base < (u32)R));
        if (sel) { int pos = atomicAdd(&scnt, 1); plist[pos] = b * K1V + tid; tl[pos] = tanhf(sv[tid]); }
        __syncthreads();
    }

    // readout2: 8 groups x 128 channels
    {
        int grp = tid >> 7, c = tid & 127;
        float mx = -INFINITY, smv = 0.f;
        for (int j = grp; j < K2V; j += 8) {
            float v = h2[(size_t)plist[j] * HID + c] * tl[j];
            mx = fmaxf(mx, v); smv += v;
        }
        rp[tid] = mx; rp2[tid] = smv;
        __syncthreads();
        if (tid < 256) {
            int c2 = tid & 127, half = tid >> 7;
            if (half == 0) {
                float m = rp[c2];
                #pragma unroll
                for (int g2 = 1; g2 < 8; g2++) m = fmaxf(m, rp[g2 * 128 + c2]);
                z[c2] = x1b[b * 256 + c2] + m;
            } else {
                float s = rp2[c2];
                #pragma unroll
                for (int g2 = 1; g2 < 8; g2++) s += rp2[g2 * 128 + c2];
                z[128 + c2] = x1b[b * 256 + 128 + c2] + s / (float)K2V;
            }
        }
        if (tid < 10) z[256 + tid] = gi[b * 10 + tid];
        __syncthreads();
    }

    // head layer 1: 8 k-groups x 128 outputs, LDS reduce
    {
        int grp = tid >> 7, c = tid & 127;
        int k0 = grp * 34;
        int k1 = k0 + 34; if (k1 > 266) k1 = 266;
        float acc = 0.f;
        for (int k = k0; k < k1; k++) acc = fmaf(z[k], l1W[k * 128 + c], acc);
        zp[grp][c] = acc;
        __syncthreads();
        if (tid < 128) {
            float s = l1b[tid];
            #pragma unroll
            for (int g2 = 0; g2 < 8; g2++) s += zp[g2][tid];
            z1[tid] = frelu(s);
        }
        __syncthreads();
    }

    // head layer 2: 8 k-groups x 64 outputs, LDS reduce
    {
        if (tid < 512) {
            int grp = tid >> 6, c = tid & 63;
            int k0 = grp * 16;
            float acc = 0.f;
            #pragma unroll
            for (int k = k0; k < k0 + 16; k++) acc = fmaf(z1[k], l2W[k * 64 + c], acc);
            zp[grp][c] = acc;
        }
        __syncthreads();
        if (tid < 64) {
            float s = l2b[tid];
            #pragma unroll
            for (int g2 = 0; g2 < 8; g2++) s += zp[g2][tid];
            z2[tid] = frelu(s);
        }
        __syncthreads();
    }

    // head layer 3 + log_softmax
    if (tid < 32) {
        float a3 = l3b[tid];
        for (int k = 0; k < 64; k++) a3 = fmaf(z2[k], l3W[k * 32 + tid], a3);
        z3[tid] = a3;
    }
    __syncthreads();
    if (tid == 0) {
        float m = -INFINITY;
        for (int c2 = 0; c2 < 32; c2++) m = fmaxf(m, z3[c2]);
        float s = 0.f;
        for (int c2 = 0; c2 < 32; c2++) s += expf(z3[c2] - m);
        red[0] = m; red[1] = logf(s);
    }
    __syncthreads();
    if (tid < 32) out[b * 32 + tid] = z3[tid] - red[0] - red[1];
}

// ============ launch ============
extern "C" void kernel_launch(void* const* d_in, const int* in_sizes, int n_in,
                              void* d_out, int out_size, void* d_ws, size_t ws_size,
                              hipStream_t stream) {
    const float* x    = (const float*)d_in[0];
    const int*   esrc = (const int*)d_in[1];
    const int*   edst = (const int*)d_in[2];
    const float* gi   = (const float*)d_in[3];
    const float* W1   = (const float*)d_in[4];
    const float* b1   = (const float*)d_in[5];
    const float* sW1  = (const float*)d_in[6];
    const float* sb1  = (const float*)d_in[7];
    const float* W2   = (const float*)d_in[8];
    const float* b2   = (const float*)d_in[9];
    const float* sW2  = (const float*)d_in[10];
    const float* sb2  = (const float*)d_in[11];
    const float* l1W  = (const float*)d_in[12];
    const float* l1b  = (const float*)d_in[13];
    const float* l2W  = (const float*)d_in[14];
    const float* l2b  = (const float*)d_in[15];
    const float* l3W  = (const float*)d_in[16];
    const float* l3b  = (const float*)d_in[17];
    float* out = (float*)d_out;

    char* p = (char*)d_ws;
    auto alloc = [&](size_t bytes) {
        char* r = p;
        p += (bytes + 255) & ~size_t(255);
        return (void*)r;
    };
    float* df_g   = (float*)alloc((size_t)NB * NPG * 4);
    float* di_g   = (float*)alloc((size_t)NB * NPG * 4);
    float* tp     = (float*)alloc((size_t)NB * NQ * NPG * 4);
    float* u_g    = (float*)alloc((size_t)NB * NPG * 4);
    float* sci_g  = (float*)alloc((size_t)NB * NPG * 4);
    float* scp    = (float*)alloc((size_t)NB * NQ * NPG * 4);
    int*   nmap_g = (int*)alloc((size_t)NB * NPG * 4);
    float* ulist  = (float*)alloc((size_t)N1 * 4);
    float* tg1    = (float*)alloc((size_t)N1 * 4);
    float* x1b    = (float*)alloc((size_t)NB * 256 * 4);
    int*   gdeg   = (int*)alloc((size_t)N1 * 4);
    int*   srcs2  = (int*)alloc((size_t)N1 * SLOTS * 4);
    float* hw     = (float*)alloc((size_t)N1 * HID * 4);
    float* h2     = (float*)alloc((size_t)N1 * HID * 4);
    float* ds02   = (float*)alloc((size_t)N1 * 4);
    float* sc2i   = (float*)alloc((size_t)N1 * 4);

    k_sweepA<<<NB * NQ, 1024, 0, stream>>>(x, esrc, edst, df_g, di_g, tp);
    k_sweepB<<<NB * NQ, 1024, 0, stream>>>(x, esrc, edst, tp, df_g, di_g,
                                           W1, b1, sW1, sb1, u_g, sci_g, scp);
    k_select<<<NB, 1024, 0, stream>>>(sci_g, di_g, scp, u_g, W1, b1,
                                      ulist, tg1, x1b, nmap_g, gdeg);
    k_cpmm<<<NB * NQ + N1 / 64, 512, 0, stream>>>(esrc, edst, nmap_g, gdeg, srcs2,
                                                  ulist, tg1, W1, b1, W2, hw);
    k_pull2<<<N1 / 4, 256, 0, stream>>>(srcs2, gdeg, hw, b2, sW2, sb2, h2, ds02, sc2i);
    k_tkhead<<<NB, 1024, 0, stream>>>(srcs2, gdeg, ds02, sc2i, h2,
                                      x1b, gi, l1W, l1b, l2W, l2b, l3W, l3b, out);
}

// Round 15
// 112.803 us; speedup vs baseline: 6.1288x; 1.0054x over previous
//
#include <hip/hip_runtime.h>
#include <math.h>

#define NB    64
#define NPG   2048      // nodes per graph
#define EPG   16384     // edges per graph
#define HID   128
#define K1V   512
#define K2V   128
#define N1    32768     // NB*K1V
#define MSK   (NPG - 1)
#define NQ    4         // edge segments per graph
#define ESEG  (EPG / NQ)   // 4096
#define SLOTS 24        // per-node CSR slot capacity (in-deg ~ Poisson(2))

typedef unsigned int u32;

static __device__ __forceinline__ float frelu(float v) { return v > 0.f ? v : 0.f; }

static __device__ __forceinline__ u32 f2key(float f) {
    u32 u = __float_as_uint(f);
    return u ^ ((u >> 31) ? 0xFFFFFFFFu : 0x80000000u);
}

static __device__ __forceinline__ u32 wave_iscan(u32 v, int lane) {
    #pragma unroll
    for (int off = 1; off < 64; off <<= 1) {
        u32 t = __shfl_up(v, off);
        if (lane >= off) v += t;
    }
    return v;
}

// Radix-select the K-th largest key among N LDS keys (T threads).
template <int N, int T>
static __device__ __forceinline__ void radix_top(const u32* __restrict__ key, int K,
                                                 u32* hist, u32* misc,
                                                 u32& tau, int& R) {
    const int tid = threadIdx.x;
    if (tid == 0) { misc[0] = 0u; misc[1] = (u32)K; }
    __syncthreads();
    #pragma unroll
    for (int p = 0; p < 4; p++) {
        const int shift = 24 - 8 * p;
        for (int i = tid; i < 256; i += T) hist[i] = 0u;
        __syncthreads();
        const u32 prefix = misc[0];
        const u32 need   = misc[1];
        for (int i = tid; i < N; i += T) {
            u32 k = key[i];
            bool ok = (p == 0) || ((k >> (shift + 8)) == prefix);
            if (ok) atomicAdd(&hist[(k >> shift) & 255u], 1u);
        }
        __syncthreads();
        if (tid < 64) {
            const int lane = tid;
            u32 c0 = hist[4 * lane + 0], c1 = hist[4 * lane + 1];
            u32 c2 = hist[4 * lane + 2], c3 = hist[4 * lane + 3];
            u32 local = c0 + c1 + c2 + c3;
            u32 inc = local;
            #pragma unroll
            for (int off = 1; off < 64; off <<= 1) {
                u32 v = __shfl_down(inc, off);
                if (lane + off < 64) inc += v;
            }
            u32 excl = inc - local;
            u32 ge3 = excl + c3, ge2 = ge3 + c2, ge1 = ge2 + c1, ge0 = ge1 + c0;
            int selb = -1; u32 gt = 0;
            if      (ge3 >= need && excl < need) { selb = 4 * lane + 3; gt = excl; }
            else if (ge2 >= need && ge3  < need) { selb = 4 * lane + 2; gt = ge3; }
            else if (ge1 >= need && ge2  < need) { selb = 4 * lane + 1; gt = ge2; }
            else if (ge0 >= need && ge1  < need) { selb = 4 * lane + 0; gt = ge1; }
            if (selb >= 0) { misc[0] = (prefix << 8) | (u32)selb; misc[1] = need - gt; }
        }
        __syncthreads();
    }
    tau = misc[0];
    R = (int)misc[1];
}

// ===== K1: fused deg-histogram + nodeA + t-sweep (1024 thr) =====
__global__ __launch_bounds__(1024) void k_sweepA(const float* __restrict__ x,
                                                 const int* __restrict__ esrc,
                                                 const int* __restrict__ edst,
                                                 float* __restrict__ df_g,
                                                 float* __restrict__ di_g,
                                                 float* __restrict__ tp) {
    __shared__ int   cnt[NPG];
    __shared__ float lv[NPG];
    __shared__ float acc[NPG];
    const int bid = blockIdx.x, tid = threadIdx.x;
    const int g = bid & 63, q = bid >> 6;
    for (int i = tid; i < NPG; i += 1024) { cnt[i] = 0; acc[i] = 0.f; }
    __syncthreads();
    const int4* dall = (const int4*)(edst + (size_t)g * EPG);
    for (int i = tid; i < EPG / 4; i += 1024) {
        int4 dd = dall[i];
        atomicAdd(&cnt[dd.x & MSK], 1); atomicAdd(&cnt[dd.y & MSK], 1);
        atomicAdd(&cnt[dd.z & MSK], 1); atomicAdd(&cnt[dd.w & MSK], 1);
    }
    __syncthreads();
    for (int i = tid; i < NPG; i += 1024) {
        float df = (float)cnt[i] + 1.0f;
        float di = rsqrtf(df);
        lv[i] = di * x[(size_t)g * NPG + i];
        if (q == 0) { df_g[(size_t)g * NPG + i] = df; di_g[(size_t)g * NPG + i] = di; }
    }
    __syncthreads();
    const int4* s4 = (const int4*)(esrc + g * EPG + q * ESEG);
    const int4* d4 = (const int4*)(edst + g * EPG + q * ESEG);
    for (int i = tid; i < ESEG / 4; i += 1024) {
        int4 ss = s4[i]; int4 dd = d4[i];
        atomicAdd(&acc[dd.x & MSK], lv[ss.x & MSK]);
        atomicAdd(&acc[dd.y & MSK], lv[ss.y & MSK]);
        atomicAdd(&acc[dd.z & MSK], lv[ss.z & MSK]);
        atomicAdd(&acc[dd.w & MSK], lv[ss.w & MSK]);
    }
    __syncthreads();
    float4* op = (float4*)(tp + ((size_t)g * NQ + q) * NPG);
    const float4* ap = (const float4*)acc;
    for (int i = tid; i < NPG / 4; i += 1024) op[i] = ap[i];
}

// ===== K2: fused nodeB + score-sweep (1024 thr) =====
__global__ __launch_bounds__(1024) void k_sweepB(const float* __restrict__ x,
                                                 const int* __restrict__ esrc,
                                                 const int* __restrict__ edst,
                                                 const float* __restrict__ tp,
                                                 const float* __restrict__ df_g,
                                                 const float* __restrict__ di_g,
                                                 const float* __restrict__ W1,
                                                 const float* __restrict__ b1,
                                                 const float* __restrict__ sW1,
                                                 const float* __restrict__ sb1,
                                                 float* __restrict__ u_g,
                                                 float* __restrict__ sci_g,
                                                 float* __restrict__ scp) {
    __shared__ float lv[NPG];
    __shared__ float acc[NPG];
    __shared__ float lw[HID], lbb[HID], lsw[HID];
    const int bid = blockIdx.x, tid = threadIdx.x;
    const int g = bid & 63, q = bid >> 6;
    if (tid < HID) { lw[tid] = W1[tid]; lbb[tid] = b1[tid]; lsw[tid] = sW1[tid]; }
    __syncthreads();
    const float sb1v = sb1[0];
    for (int i = tid; i < NPG; i += 1024) {
        float t = 0.f;
        #pragma unroll
        for (int q2 = 0; q2 < NQ; q2++) t += tp[((size_t)g * NQ + q2) * NPG + i];
        float df = df_g[(size_t)g * NPG + i];
        float di = di_g[(size_t)g * NPG + i];
        float u = t * di + x[(size_t)g * NPG + i] / df;
        float s = 0.f;
        #pragma unroll 8
        for (int c = 0; c < HID; c++) s += frelu(fmaf(lw[c], u, lbb[c])) * lsw[c];
        lv[i] = di * s;
        acc[i] = 0.f;
        if (q == 0) {
            u_g[(size_t)g * NPG + i] = u;
            sci_g[(size_t)g * NPG + i] = s / df + sb1v;
        }
    }
    __syncthreads();
    const int4* s4 = (const int4*)(esrc + g * EPG + q * ESEG);
    const int4* d4 = (const int4*)(edst + g * EPG + q * ESEG);
    for (int i = tid; i < ESEG / 4; i += 1024) {
        int4 ss = s4[i]; int4 dd = d4[i];
        atomicAdd(&acc[dd.x & MSK], lv[ss.x & MSK]);
        atomicAdd(&acc[dd.y & MSK], lv[ss.y & MSK]);
        atomicAdd(&acc[dd.z & MSK], lv[ss.z & MSK]);
        atomicAdd(&acc[dd.w & MSK], lv[ss.w & MSK]);
    }
    __syncthreads();
    float4* op = (float4*)(scp + ((size_t)g * NQ + q) * NPG);
    const float4* ap = (const float4*)acc;
    for (int i = tid; i < NPG / 4; i += 1024) op[i] = ap[i];
}

// ===== K3: score finalize, radix top-512, readout1, AND edge compaction =====
// nmap (ln) stays in LDS; slot-CSR built here with LDS cursors.
__global__ __launch_bounds__(1024) void k_select(
    const float* __restrict__ sci_g, const float* __restrict__ di_g,
    const float* __restrict__ scp, const float* __restrict__ u_g,
    const float* __restrict__ W1, const float* __restrict__ b1,
    const int* __restrict__ esrc, const int* __restrict__ edst,
    float* __restrict__ ulist, float* __restrict__ tg1, float* __restrict__ x1b,
    int* __restrict__ gdeg, int* __restrict__ srcs2)
{
    __shared__ float lsc[NPG];
    __shared__ u32   lkey[NPG];
    __shared__ int   ln[NPG];
    __shared__ float ul[K1V], tgl[K1V];
    __shared__ int   sellist[K1V];      // reused as ldeg cursors after selection
    __shared__ u32   hist[256], misc[2], wsum[16];
    __shared__ int   scnt;
    __shared__ float lw[HID], lbb[HID];
    const int b = blockIdx.x, tid = threadIdx.x;
    const int lane = tid & 63, wv = tid >> 6;

    for (int i = tid; i < NPG; i += 1024) {
        float a = 0.f;
        #pragma unroll
        for (int q = 0; q < NQ; q++) a += scp[((size_t)b * NQ + q) * NPG + i];
        float sc = sci_g[(size_t)b * NPG + i] + di_g[(size_t)b * NPG + i] * a;
        lsc[i] = sc;
        lkey[i] = f2key(sc);
        ln[i] = -1;
    }
    if (tid < HID) { lw[tid] = W1[tid]; lbb[tid] = b1[tid]; }
    if (tid == 0) scnt = 0;
    __syncthreads();

    u32 tau; int R;
    radix_top<NPG, 1024>(lkey, K1V, hist, misc, tau, R);

    // stable tie rank (lowest index first)
    {
        int e0 = tid * 2, e1 = e0 + 1;
        u32 k0 = lkey[e0], k1 = lkey[e1];
        int q0 = (k0 == tau) ? 1 : 0, q1 = (k1 == tau) ? 1 : 0;
        u32 inc = wave_iscan((u32)(q0 + q1), lane);
        if (lane == 63) wsum[wv] = inc;
        __syncthreads();
        if (tid == 0) { u32 run = 0; for (int w2 = 0; w2 < 16; w2++) { u32 v = wsum[w2]; wsum[w2] = run; run += v; } }
        __syncthreads();
        u32 base = wsum[wv] + inc - (u32)(q0 + q1);
        bool sel0 = (k0 > tau) || (q0 && base < (u32)R);
        bool sel1 = (k1 > tau) || (q1 && (base + (u32)q0) < (u32)R);
        if (sel0) { int pos = atomicAdd(&scnt, 1); sellist[pos] = e0; }
        if (sel1) { int pos = atomicAdd(&scnt, 1); sellist[pos] = e1; }
        __syncthreads();
    }

    if (tid < K1V) {
        int node = sellist[tid];
        float uu = u_g[(size_t)b * NPG + node];
        float g = tanhf(lsc[node]);
        ul[tid] = uu; tgl[tid] = g;
        ulist[b * K1V + tid] = uu;
        tg1[b * K1V + tid] = g;
        ln[node] = tid;
    }
    __syncthreads();

    // readout1: reuse lkey as two 1024-float partial arrays
    float* rp = (float*)lkey;
    {
        int grp = tid >> 7, c = tid & 127;
        float w = lw[c], bb = lbb[c];
        float mx = -INFINITY, sm = 0.f;
        for (int j = grp; j < K1V; j += 8) {
            float v = frelu(fmaf(w, ul[j], bb)) * tgl[j];
            mx = fmaxf(mx, v); sm += v;
        }
        __syncthreads();
        rp[tid] = mx; rp[1024 + tid] = sm;
        __syncthreads();
        if (tid < HID) {
            float m2 = -INFINITY, s2 = 0.f;
            #pragma unroll
            for (int g2 = 0; g2 < 8; g2++) {
                m2 = fmaxf(m2, rp[g2 * 128 + tid]);
                s2 += rp[1024 + g2 * 128 + tid];
            }
            x1b[b * 256 + tid] = m2;
            x1b[b * 256 + HID + tid] = s2 / (float)K1V;
        }
    }
    __syncthreads();

    // edge compaction -> slot-CSR (sellist reused as LDS slot cursors)
    int* ldeg2 = sellist;
    if (tid < K1V) ldeg2[tid] = 0;
    __syncthreads();
    {
        const int4* s4 = (const int4*)(esrc + (size_t)b * EPG);
        const int4* d4 = (const int4*)(edst + (size_t)b * EPG);
        const int base = b * K1V;
        for (int i = tid; i < EPG / 4; i += 1024) {
            int4 ss = s4[i]; int4 dd = d4[i];
            int sa[4] = { ss.x & MSK, ss.y & MSK, ss.z & MSK, ss.w & MSK };
            int da[4] = { dd.x & MSK, dd.y & MSK, dd.z & MSK, dd.w & MSK };
            #pragma unroll
            for (int r = 0; r < 4; r++) {
                int s2 = ln[sa[r]], d2 = ln[da[r]];
                if (s2 >= 0 && d2 >= 0) {
                    int slot = atomicAdd(&ldeg2[d2], 1);
                    if (slot < SLOTS) srcs2[(size_t)(base + d2) * SLOTS + slot] = base + s2;
                }
            }
        }
    }
    __syncthreads();
    if (tid < K1V) gdeg[b * K1V + tid] = ldeg2[tid];
}

// ===== K4: pure matmul hw = hp @ W2 (512 blocks x 512 thr) =====
__global__ __launch_bounds__(512) void k_mm(
    const float* __restrict__ ulist, const float* __restrict__ tg1,
    const float* __restrict__ W1, const float* __restrict__ b1,
    const float* __restrict__ W2, float* __restrict__ hw)
{
    __shared__ float lhT[HID * 64];
    __shared__ float lu[64], lg[64];
    const int bid = blockIdx.x, tid = threadIdx.x;
    const int row0 = bid * 64;
    if (tid < 64) { lu[tid] = ulist[row0 + tid]; lg[tid] = tg1[row0 + tid]; }
    __syncthreads();
    for (int idx = tid; idx < HID * 64; idx += 512) {
        int k = idx >> 6, j = idx & 63;
        lhT[idx] = frelu(fmaf(W1[k], lu[j], b1[k])) * lg[j];
    }
    __syncthreads();
    const int cg2 = tid & 31, rg2 = tid >> 5;
    float acc[4][4];
    #pragma unroll
    for (int r = 0; r < 4; r++)
        #pragma unroll
        for (int c = 0; c < 4; c++) acc[r][c] = 0.f;
    const float4* lhT4 = (const float4*)lhT;
    #pragma unroll 4
    for (int k = 0; k < HID; k++) {
        float4 h = lhT4[k * 16 + rg2];
        float4 ww = *(const float4*)&W2[(size_t)k * HID + cg2 * 4];
        float hr[4] = { h.x, h.y, h.z, h.w };
        float wc[4] = { ww.x, ww.y, ww.z, ww.w };
        #pragma unroll
        for (int r = 0; r < 4; r++)
            #pragma unroll
            for (int c = 0; c < 4; c++)
                acc[r][c] = fmaf(hr[r], wc[c], acc[r][c]);
    }
    #pragma unroll
    for (int r = 0; r < 4; r++) {
        float4 o; o.x = acc[r][0]; o.y = acc[r][1]; o.z = acc[r][2]; o.w = acc[r][3];
        *(float4*)&hw[(size_t)(row0 + rg2 * 4 + r) * HID + cg2 * 4] = o;
    }
}

// ===== K5: stage-2 GCN via slot-CSR pull, fused bias/relu/score =====
__global__ __launch_bounds__(256) void k_pull2(
    const int* __restrict__ srcs2, const int* __restrict__ gdeg,
    const float* __restrict__ hw, const float* __restrict__ b2,
    const float* __restrict__ sW2, const float* __restrict__ sb2,
    float* __restrict__ h2, float* __restrict__ ds02, float* __restrict__ sc2i)
{
    int node = blockIdx.x * 4 + (threadIdx.x >> 6);
    int lane = threadIdx.x & 63;
    int dg = gdeg[node];
    int cnt = dg < SLOTS ? dg : SLOTS;
    float a0 = 0.f, a1 = 0.f;
    for (int j = 0; j < cnt; j++) {
        int s = srcs2[(size_t)node * SLOTS + j];
        float w = rsqrtf((float)gdeg[s] + 1.0f);
        a0 = fmaf(w, hw[(size_t)s * HID + lane], a0);
        a1 = fmaf(w, hw[(size_t)s * HID + 64 + lane], a1);
    }
    float df = (float)dg + 1.0f;
    float di = rsqrtf(df);
    float h0 = frelu(a0 * di + hw[(size_t)node * HID + lane] / df + b2[lane]);
    float h1 = frelu(a1 * di + hw[(size_t)node * HID + 64 + lane] / df + b2[lane + 64]);
    h2[(size_t)node * HID + lane] = h0;
    h2[(size_t)node * HID + 64 + lane] = h1;
    float dot = h0 * sW2[lane] + h1 * sW2[lane + 64];
    #pragma unroll
    for (int o = 32; o > 0; o >>= 1) dot += __shfl_down(dot, o);
    if (lane == 0) {
        ds02[node] = di * dot;
        sc2i[node] = dot / df + sb2[0];
    }
}

// ===== K6: topk2 + readout2 + head (1024 threads) =====
__global__ __launch_bounds__(1024) void k_tkhead(
    const int* __restrict__ srcs2, const int* __restrict__ gdeg,
    const float* __restrict__ ds02, const float* __restrict__ sc2i,
    const float* __restrict__ h2,
    const float* __restrict__ x1b, const float* __restrict__ gi,
    const float* __restrict__ l1W, const float* __restrict__ l1b,
    const float* __restrict__ l2W, const float* __restrict__ l2b,
    const float* __restrict__ l3W, const float* __restrict__ l3b,
    float* __restrict__ out)
{
    __shared__ float sv[K1V];
    __shared__ u32   skey[K1V];
    __shared__ u32   hist[256], misc[2], wsum[16];
    __shared__ int   plist[K2V];
    __shared__ float tl[K2V];
    __shared__ float rp[1024], rp2[1024];
    __shared__ float z[272];
    __shared__ float zp[8][128];
    __shared__ float z1[HID], z2[64], z3[32], red[2];
    __shared__ int   scnt;
    const int b = blockIdx.x, tid = threadIdx.x;
    const int lane = tid & 63, wv = tid >> 6;
    if (tid == 0) scnt = 0;

    // score finalize (one node per thread, tid<512)
    if (tid < K1V) {
        int n = b * K1V + tid;
        int dg = gdeg[n];
        int cnt = dg < SLOTS ? dg : SLOTS;
        float acc = 0.f;
        for (int j = 0; j < cnt; j++) acc += ds02[srcs2[(size_t)n * SLOTS + j]];
        float sc = sc2i[n] + rsqrtf((float)dg + 1.0f) * acc;
        sv[tid] = sc; skey[tid] = f2key(sc);
    }
    __syncthreads();
    u32 tau; int R;
    radix_top<K1V, 1024>(skey, K2V, hist, misc, tau, R);

    // tie rank: one element per thread
    {
        u32 k0 = skey[tid < K1V ? tid : 0];
        int q0 = (tid < K1V && k0 == tau) ? 1 : 0;
        u32 inc = wave_iscan((u32)q0, lane);
        if (lane == 63) wsum[wv] = inc;
        __syncthreads();
        if (tid == 0) { u32 run = 0; for (int w2 = 0; w2 < 16; w2++) { u32 v = wsum[w2]; wsum[w2] = run; run += v; } }
        __syncthreads();
        u32 base = wsum[wv] + inc - (u32)q0;
        bool sel = (tid < K1V) && ((k0 > tau) || (q0 && base < (u32)R));
        if (sel) { int pos = atomicAdd(&scnt, 1); plist[pos] = b * K1V + tid; tl[pos] = tanhf(sv[tid]); }
        __syncthreads();
    }

    // readout2: 8 groups x 128 channels
    {
        int grp = tid >> 7, c = tid & 127;
        float mx = -INFINITY, smv = 0.f;
        for (int j = grp; j < K2V; j += 8) {
            float v = h2[(size_t)plist[j] * HID + c] * tl[j];
            mx = fmaxf(mx, v); smv += v;
        }
        rp[tid] = mx; rp2[tid] = smv;
        __syncthreads();
        if (tid < 256) {
            int c2 = tid & 127, half = tid >> 7;
            if (half == 0) {
                float m = rp[c2];
                #pragma unroll
                for (int g2 = 1; g2 < 8; g2++) m = fmaxf(m, rp[g2 * 128 + c2]);
                z[c2] = x1b[b * 256 + c2] + m;
            } else {
                float s = rp2[c2];
                #pragma unroll
                for (int g2 = 1; g2 < 8; g2++) s += rp2[g2 * 128 + c2];
                z[128 + c2] = x1b[b * 256 + 128 + c2] + s / (float)K2V;
            }
        }
        if (tid < 10) z[256 + tid] = gi[b * 10 + tid];
        __syncthreads();
    }

    // head layer 1: 8 k-groups x 128 outputs, LDS reduce
    {
        int grp = tid >> 7, c = tid & 127;
        int k0 = grp * 34;
        int k1 = k0 + 34; if (k1 > 266) k1 = 266;
        float acc = 0.f;
        for (int k = k0; k < k1; k++) acc = fmaf(z[k], l1W[k * 128 + c], acc);
        zp[grp][c] = acc;
        __syncthreads();
        if (tid < 128) {
            float s = l1b[tid];
            #pragma unroll
            for (int g2 = 0; g2 < 8; g2++) s += zp[g2][tid];
            z1[tid] = frelu(s);
        }
        __syncthreads();
    }

    // head layer 2: 8 k-groups x 64 outputs, LDS reduce
    {
        if (tid < 512) {
            int grp = tid >> 6, c = tid & 63;
            int k0 = grp * 16;
            float acc = 0.f;
            #pragma unroll
            for (int k = k0; k < k0 + 16; k++) acc = fmaf(z1[k], l2W[k * 64 + c], acc);
            zp[grp][c] = acc;
        }
        __syncthreads();
        if (tid < 64) {
            float s = l2b[tid];
            #pragma unroll
            for (int g2 = 0; g2 < 8; g2++) s += zp[g2][tid];
            z2[tid] = frelu(s);
        }
        __syncthreads();
    }

    // head layer 3 + log_softmax
    if (tid < 32) {
        float a3 = l3b[tid];
        for (int k = 0; k < 64; k++) a3 = fmaf(z2[k], l3W[k * 32 + tid], a3);
        z3[tid] = a3;
    }
    __syncthreads();
    if (tid == 0) {
        float m = -INFINITY;
        for (int c2 = 0; c2 < 32; c2++) m = fmaxf(m, z3[c2]);
        float s = 0.f;
        for (int c2 = 0; c2 < 32; c2++) s += expf(z3[c2] - m);
        red[0] = m; red[1] = logf(s);
    }
    __syncthreads();
    if (tid < 32) out[b * 32 + tid] = z3[tid] - red[0] - red[1];
}

// ============ launch ============
extern "C" void kernel_launch(void* const* d_in, const int* in_sizes, int n_in,
                              void* d_out, int out_size, void* d_ws, size_t ws_size,
                              hipStream_t stream) {
    const float* x    = (const float*)d_in[0];
    const int*   esrc = (const int*)d_in[1];
    const int*   edst = (const int*)d_in[2];
    const float* gi   = (const float*)d_in[3];
    const float* W1   = (const float*)d_in[4];
    const float* b1   = (const float*)d_in[5];
    const float* sW1  = (const float*)d_in[6];
    const float* sb1  = (const float*)d_in[7];
    const float* W2   = (const float*)d_in[8];
    const float* b2   = (const float*)d_in[9];
    const float* sW2  = (const float*)d_in[10];
    const float* sb2  = (const float*)d_in[11];
    const float* l1W  = (const float*)d_in[12];
    const float* l1b  = (const float*)d_in[13];
    const float* l2W  = (const float*)d_in[14];
    const float* l2b  = (const float*)d_in[15];
    const float* l3W  = (const float*)d_in[16];
    const float* l3b  = (const float*)d_in[17];
    float* out = (float*)d_out;

    char* p = (char*)d_ws;
    auto alloc = [&](size_t bytes) {
        char* r = p;
        p += (bytes + 255) & ~size_t(255);
        return (void*)r;
    };
    float* df_g   = (float*)alloc((size_t)NB * NPG * 4);
    float* di_g   = (float*)alloc((size_t)NB * NPG * 4);
    float* tp     = (float*)alloc((size_t)NB * NQ * NPG * 4);
    float* u_g    = (float*)alloc((size_t)NB * NPG * 4);
    float* sci_g  = (float*)alloc((size_t)NB * NPG * 4);
    float* scp    = (float*)alloc((size_t)NB * NQ * NPG * 4);
    float* ulist  = (float*)alloc((size_t)N1 * 4);
    float* tg1    = (float*)alloc((size_t)N1 * 4);
    float* x1b    = (float*)alloc((size_t)NB * 256 * 4);
    int*   gdeg   = (int*)alloc((size_t)N1 * 4);
    int*   srcs2  = (int*)alloc((size_t)N1 * SLOTS * 4);
    float* hw     = (float*)alloc((size_t)N1 * HID * 4);
    float* h2     = (float*)alloc((size_t)N1 * HID * 4);
    float* ds02   = (float*)alloc((size_t)N1 * 4);
    float* sc2i   = (float*)alloc((size_t)N1 * 4);

    k_sweepA<<<NB * NQ, 1024, 0, stream>>>(x, esrc, edst, df_g, di_g, tp);
    k_sweepB<<<NB * NQ, 1024, 0, stream>>>(x, esrc, edst, tp, df_g, di_g,
                                           W1, b1, sW1, sb1, u_g, sci_g, scp);
    k_select<<<NB, 1024, 0, stream>>>(sci_g, di_g, scp, u_g, W1, b1, esrc, edst,
                                      ulist, tg1, x1b, gdeg, srcs2);
    k_mm<<<N1 / 64, 512, 0, stream>>>(ulist, tg1, W1, b1, W2, hw);
    k_pull2<<<N1 / 4, 256, 0, stream>>>(srcs2, gdeg, hw, b2, sW2, sb2, h2, ds02, sc2i);
    k_tkhead<<<NB, 1024, 0, stream>>>(srcs2, gdeg, ds02, sc2i, h2,
                                      x1b, gi, l1W, l1b, l2W, l2b, l3W, l3b, out);
}